// Round 1
// baseline (2446.824 us; speedup 1.0000x reference)
//
#include <hip/hip_runtime.h>

#define TPB 256

// ---------------------------------------------------------------------------
// Weight transform: src OIHW (iohw=0) or IOHW (iohw=1)  ->  dst [tap][ci][co]
// ---------------------------------------------------------------------------
__global__ void wtrans_kernel(const float* __restrict__ src, float* __restrict__ dst,
                              int CIN, int COUT, int taps, int iohw) {
    int idx = blockIdx.x * TPB + threadIdx.x;
    int tot = CIN * COUT * taps;
    if (idx >= tot) return;
    int co = idx % COUT;
    int ci = (idx / COUT) % CIN;
    int tap = idx / (COUT * CIN);
    float v = iohw ? src[(ci * COUT + co) * taps + tap]
                   : src[(co * CIN + ci) * taps + tap];
    dst[idx] = v;
}

// ---------------------------------------------------------------------------
// conv1: x NCHW [16,3,256,256] -> out NHWC [16,128,128,128], 4x4 s2 p1 + ReLU
// grid = 16*128*2, block = 256.  BM = 64 output px per block.
// ---------------------------------------------------------------------------
__global__ __launch_bounds__(256) void conv1_kernel(
    const float* __restrict__ x, const float* __restrict__ Wt,
    const float* __restrict__ bias, float* __restrict__ out) {
    const int IH = 256, IW = 256, OH = 128, OW = 128, BM = 64;
    int bx = blockIdx.x;
    int sx = bx & 1;
    int oy = (bx >> 1) & 127;
    int n  = bx >> 8;
    int ox0 = sx * BM;
    __shared__ float Bs[16 * 3 * 128];   // [tap][ci][co]
    __shared__ float Ts[3 * 4 * 132];    // [ci][ky][130 padded to 132]
    int tid = threadIdx.x;
    for (int i = tid; i < 6144 / 4; i += TPB)
        ((float4*)Bs)[i] = ((const float4*)Wt)[i];
    int iy0 = 2 * oy - 1;
    for (int idx = tid; idx < 3 * 4 * 130; idx += TPB) {
        int ci = idx / 520; int r = idx % 520;
        int ky = r / 130;   int xx = r % 130;
        int iy = iy0 + ky;  int ix = 2 * ox0 - 1 + xx;
        float v = 0.f;
        if (iy >= 0 && iy < IH && ix >= 0 && ix < IW)
            v = x[((n * 3 + ci) * IH + iy) * IW + ix];
        Ts[(ci * 4 + ky) * 132 + xx] = v;
    }
    __syncthreads();
    int cog = tid & 31, pxg = tid >> 5;
    int co0 = cog * 4, px0 = pxg * 8;
    float acc[8][4];
#pragma unroll
    for (int i = 0; i < 8; ++i)
#pragma unroll
        for (int j = 0; j < 4; ++j) acc[i][j] = 0.f;
#pragma unroll 1
    for (int ky = 0; ky < 4; ++ky)
#pragma unroll 1
        for (int kx = 0; kx < 4; ++kx)
#pragma unroll
            for (int ci = 0; ci < 3; ++ci) {
                float4 b = *(const float4*)&Bs[((ky * 4 + kx) * 3 + ci) * 128 + co0];
                const float* trow = &Ts[(ci * 4 + ky) * 132 + kx];
#pragma unroll
                for (int q = 0; q < 8; ++q) {
                    float a = trow[2 * (px0 + q)];
                    acc[q][0] = fmaf(a, b.x, acc[q][0]);
                    acc[q][1] = fmaf(a, b.y, acc[q][1]);
                    acc[q][2] = fmaf(a, b.z, acc[q][2]);
                    acc[q][3] = fmaf(a, b.w, acc[q][3]);
                }
            }
    float4 bb = *(const float4*)&bias[co0];
#pragma unroll
    for (int q = 0; q < 8; ++q) {
        int ox = ox0 + px0 + q;
        float4 v;
        v.x = fmaxf(acc[q][0] + bb.x, 0.f);
        v.y = fmaxf(acc[q][1] + bb.y, 0.f);
        v.z = fmaxf(acc[q][2] + bb.z, 0.f);
        v.w = fmaxf(acc[q][3] + bb.w, 0.f);
        *(float4*)&out[(((long)n * OH + oy) * OW + ox) * 128 + co0] = v;
    }
}

// ---------------------------------------------------------------------------
// Generic tiled conv-as-GEMM.  NHWC in/out.
// MODE 0: 4x4 s2 p1 conv.  MODE 1: 4x4 s2 p1 convT (gather).  MODE 2: 1x1.
// Block: BM output pixels x COUT channels, 256 threads.
// For MODE 1, BM must equal OW/2 (one parity strip per block).
// ---------------------------------------------------------------------------
template<int MODE, int CIN, int COUT, int BM, int RELU, int IH, int IW, int OH, int OW>
__global__ __launch_bounds__(256) void conv_gemm(
    const float* __restrict__ in, const float* __restrict__ Wt,
    const float* __restrict__ bias, float* __restrict__ out) {
    constexpr int CHUNK  = 64;
    constexpr int NCH    = CIN / CHUNK;
    constexpr int CO_PER = (COUT == 128) ? 4 : 2;
    constexpr int PX_PER = BM / 8;
    constexpr int TAPS   = (MODE == 0) ? 16 : (MODE == 1 ? 4 : 1);
    __shared__ float As[CHUNK * BM];
    __shared__ float Bs[CHUNK * COUT];
    const int tid = threadIdx.x;
    const int bx  = blockIdx.x;
    int n, oy, ox0 = 0, par = 0;
    if (MODE == 1) {
        par = bx & 1;
        oy  = (bx >> 1) % OH;
        n   = bx / (2 * OH);
    } else {
        constexpr int SPR = OW / BM;
        int s = bx % SPR;
        oy = (bx / SPR) % OH;
        n  = bx / (SPR * OH);
        ox0 = s * BM;
    }
    const int cog = tid & 31;          // COUT/CO_PER == 32 in all instantiations
    const int pxg = tid >> 5;
    const int co0 = cog * CO_PER, px0 = pxg * PX_PER;
    float acc[PX_PER][CO_PER];
#pragma unroll
    for (int q = 0; q < PX_PER; ++q)
#pragma unroll
        for (int j = 0; j < CO_PER; ++j) acc[q][j] = 0.f;
    constexpr int TPX  = 256 / BM;
    constexpr int CIPT = CHUNK / TPX;
    const int spx  = tid / TPX;
    const int sci0 = (tid % TPX) * CIPT;
    const int py   = oy & 1;

#pragma unroll 1
    for (int tap = 0; tap < TAPS; ++tap) {
        int iy, twi, sx;
        if (MODE == 0) {
            int ky = tap >> 2, kx = tap & 3;
            iy  = 2 * oy - 1 + ky;
            sx  = 2 * (ox0 + spx) - 1 + kx;
            twi = tap;
        } else if (MODE == 1) {
            int jj = tap >> 1, ii = tap & 1;
            iy  = ((oy + 1) >> 1) - jj;
            sx  = spx + par - ii;
            twi = ((1 - py) + 2 * jj) * 4 + ((1 - par) + 2 * ii);
        } else {
            iy = oy; sx = ox0 + spx; twi = 0;
        }
        const bool pxv = (iy >= 0) && (iy < IH) && (sx >= 0) && (sx < IW);
        const float* srcp = in + (((long)n * IH + iy) * IW + sx) * CIN + sci0;
#pragma unroll 1
        for (int cb = 0; cb < NCH; ++cb) {
            __syncthreads();
            float4 tmp[CIPT / 4];
#pragma unroll
            for (int t4 = 0; t4 < CIPT / 4; ++t4) {
                if (pxv) tmp[t4] = *(const float4*)(srcp + cb * CHUNK + 4 * t4);
                else { tmp[t4].x = 0.f; tmp[t4].y = 0.f; tmp[t4].z = 0.f; tmp[t4].w = 0.f; }
            }
#pragma unroll
            for (int t4 = 0; t4 < CIPT / 4; ++t4) {
                As[(sci0 + 4 * t4 + 0) * BM + spx] = tmp[t4].x;
                As[(sci0 + 4 * t4 + 1) * BM + spx] = tmp[t4].y;
                As[(sci0 + 4 * t4 + 2) * BM + spx] = tmp[t4].z;
                As[(sci0 + 4 * t4 + 3) * BM + spx] = tmp[t4].w;
            }
            {
                const float4* wsrc = (const float4*)(Wt + ((long)twi * CIN + cb * CHUNK) * COUT);
#pragma unroll
                for (int t4 = 0; t4 < (CHUNK * COUT) / 1024; ++t4)
                    ((float4*)Bs)[tid + 256 * t4] = wsrc[tid + 256 * t4];
            }
            __syncthreads();
#pragma unroll 4
            for (int k = 0; k < CHUNK; ++k) {
                float a[PX_PER];
#pragma unroll
                for (int t4 = 0; t4 < PX_PER / 4; ++t4)
                    *(float4*)&a[4 * t4] = *(const float4*)&As[k * BM + px0 + 4 * t4];
                if constexpr (CO_PER == 4) {
                    float4 b = *(const float4*)&Bs[k * COUT + co0];
#pragma unroll
                    for (int q = 0; q < PX_PER; ++q) {
                        acc[q][0] = fmaf(a[q], b.x, acc[q][0]);
                        acc[q][1] = fmaf(a[q], b.y, acc[q][1]);
                        acc[q][2] = fmaf(a[q], b.z, acc[q][2]);
                        acc[q][3] = fmaf(a[q], b.w, acc[q][3]);
                    }
                } else {
                    float2 b = *(const float2*)&Bs[k * COUT + co0];
#pragma unroll
                    for (int q = 0; q < PX_PER; ++q) {
                        acc[q][0] = fmaf(a[q], b.x, acc[q][0]);
                        acc[q][1] = fmaf(a[q], b.y, acc[q][1]);
                    }
                }
            }
        }
    }
    float bv[CO_PER];
#pragma unroll
    for (int j = 0; j < CO_PER; ++j) bv[j] = bias[co0 + j];
#pragma unroll
    for (int q = 0; q < PX_PER; ++q) {
        int ox = (MODE == 1) ? (par + 2 * (px0 + q)) : (ox0 + px0 + q);
        float* op = out + (((long)n * OH + oy) * OW + ox) * COUT + co0;
        if constexpr (CO_PER == 4) {
            float4 v;
            v.x = acc[q][0] + bv[0]; v.y = acc[q][1] + bv[1];
            v.z = acc[q][2] + bv[2]; v.w = acc[q][3] + bv[3];
            if (RELU) { v.x = fmaxf(v.x, 0.f); v.y = fmaxf(v.y, 0.f);
                        v.z = fmaxf(v.z, 0.f); v.w = fmaxf(v.w, 0.f); }
            *(float4*)op = v;
        } else {
            float2 v;
            v.x = acc[q][0] + bv[0]; v.y = acc[q][1] + bv[1];
            if (RELU) { v.x = fmaxf(v.x, 0.f); v.y = fmaxf(v.y, 0.f); }
            *(float2*)op = v;
        }
    }
}

// ---------------------------------------------------------------------------
// Codebook squared norms for both embeds. grid=4, block=256.
// ---------------------------------------------------------------------------
__global__ void enorm_kernel(const float* __restrict__ et, const float* __restrict__ eb,
                             float* __restrict__ nt, float* __restrict__ nb) {
    int k = blockIdx.x * TPB + threadIdx.x;
    if (k >= 1024) return;
    const float* e = (k < 512) ? et : eb;
    float* o = (k < 512) ? nt : nb;
    int kk = k & 511;
    float s = 0.f;
#pragma unroll 8
    for (int d = 0; d < 64; ++d) { float v = e[d * 512 + kk]; s = fmaf(v, v, s); }
    o[kk] = s;
}

// ---------------------------------------------------------------------------
// Vector quantize: f [M,64] NHWC rows, embed [64,512].
// One wave handles 8 rows; lane holds 8 codes. argmin(|e|^2 - 2 f.e),
// first-index tie-break. Writes quant NHWC (ws), quant NCHW (d_out),
// id (float, d_out), and atomicAdds sum((q-z)^2).
// ---------------------------------------------------------------------------
__global__ __launch_bounds__(256) void quantize_kernel(
    const float* __restrict__ f, const float* __restrict__ embed,
    const float* __restrict__ enorm, float* __restrict__ qn,
    float* __restrict__ qc, float* __restrict__ ido, float* __restrict__ dsum,
    int M, int HW, int W) {
    int lane = threadIdx.x & 63;
    int wave = threadIdx.x >> 6;
    int row0 = (blockIdx.x * 4 + wave) * 8;
    if (row0 >= M) return;
    int c0 = lane * 8;
    const float* fr = f + (long)row0 * 64;
    float dot[8][8];
#pragma unroll
    for (int r = 0; r < 8; ++r)
#pragma unroll
        for (int j = 0; j < 8; ++j) dot[r][j] = 0.f;
#pragma unroll 2
    for (int d = 0; d < 64; ++d) {
        float4 e0 = *(const float4*)(embed + d * 512 + c0);
        float4 e1 = *(const float4*)(embed + d * 512 + c0 + 4);
#pragma unroll
        for (int r = 0; r < 8; ++r) {
            float fd = fr[r * 64 + d];
            dot[r][0] = fmaf(fd, e0.x, dot[r][0]);
            dot[r][1] = fmaf(fd, e0.y, dot[r][1]);
            dot[r][2] = fmaf(fd, e0.z, dot[r][2]);
            dot[r][3] = fmaf(fd, e0.w, dot[r][3]);
            dot[r][4] = fmaf(fd, e1.x, dot[r][4]);
            dot[r][5] = fmaf(fd, e1.y, dot[r][5]);
            dot[r][6] = fmaf(fd, e1.z, dot[r][6]);
            dot[r][7] = fmaf(fd, e1.w, dot[r][7]);
        }
    }
    float4 n0 = *(const float4*)(enorm + c0);
    float4 n1 = *(const float4*)(enorm + c0 + 4);
    float en[8] = { n0.x, n0.y, n0.z, n0.w, n1.x, n1.y, n1.z, n1.w };
#pragma unroll 1
    for (int r = 0; r < 8; ++r) {
        float bvv = en[0] - 2.f * dot[r][0];
        int bi = c0;
#pragma unroll
        for (int j = 1; j < 8; ++j) {
            float s = en[j] - 2.f * dot[r][j];
            if (s < bvv) { bvv = s; bi = c0 + j; }
        }
#pragma unroll
        for (int off = 1; off < 64; off <<= 1) {
            float ov = __shfl_xor(bvv, off);
            int   oi = __shfl_xor(bi, off);
            if (ov < bvv || (ov == bvv && oi < bi)) { bvv = ov; bi = oi; }
        }
        int k = bi;
        int row = row0 + r;
        float ev = embed[lane * 512 + k];
        float fv = fr[r * 64 + lane];
        qn[(long)row * 64 + lane] = ev;
        int nn = row / HW; int rem = row - nn * HW;
        int y = rem / W;   int xx = rem - y * W;
        qc[((long)nn * 64 + lane) * HW + y * W + xx] = ev;
        float dd = (ev - fv) * (ev - fv);
#pragma unroll
        for (int off = 1; off < 64; off <<= 1) dd += __shfl_xor(dd, off);
        if (lane == 0) { atomicAdd(dsum, dd); ido[row] = (float)k; }
    }
}

// ---------------------------------------------------------------------------
// Channel concat NHWC: o[row] = [a(ca) | b(cb)], float4 granularity.
// ---------------------------------------------------------------------------
__global__ void concat_kernel(const float* __restrict__ a, const float* __restrict__ b,
                              float* __restrict__ o, int ca, int cb, int M) {
    int fpr = (ca + cb) >> 2;
    int idx = blockIdx.x * TPB + threadIdx.x;
    if (idx >= M * fpr) return;
    int row = idx / fpr;
    int c4  = (idx - row * fpr) * 4;
    float4 v;
    if (c4 < ca) v = *(const float4*)(a + (long)row * ca + c4);
    else         v = *(const float4*)(b + (long)row * cb + (c4 - ca));
    *(float4*)(o + (long)row * (ca + cb) + c4) = v;
}

// ---------------------------------------------------------------------------
// Final convT 64->3 (4x4 s2 p1): h NHWC [16,128,128,64] -> x_hat NCHW
// [16,3,256,256].  grid = 16*256 rows, block = 256 (one thread per ox).
// ---------------------------------------------------------------------------
__global__ __launch_bounds__(256) void convt_final_kernel(
    const float* __restrict__ h, const float* __restrict__ Wt,
    const float* __restrict__ bias, float* __restrict__ out) {
    const int IH = 128, IW = 128, OH = 256, OW = 256;
    int n  = blockIdx.x >> 8;
    int oy = blockIdx.x & 255;
    __shared__ float Ws[16 * 64 * 3];     // [tap][ci][co]
    __shared__ float Ts[2 * 130 * 33];    // [j][ix+1][ci%32], padded
    int tid = threadIdx.x;
    for (int i = tid; i < 3072; i += TPB) Ws[i] = Wt[i];
    int py = oy & 1;
    int iyb = (oy + 1) >> 1;
    int ox = tid;
    int parx = ox & 1;
    int ixb = ((ox + 1) >> 1) + 1;
    float acc[3] = {0.f, 0.f, 0.f};
#pragma unroll 1
    for (int cb = 0; cb < 2; ++cb) {
        __syncthreads();
        for (int idx = tid; idx < 2 * 130 * 32; idx += TPB) {
            int j = idx / (130 * 32);
            int r = idx - j * (130 * 32);
            int xs = r >> 5; int ci = r & 31;
            int iy = iyb - j; int ix = xs - 1;
            float v = 0.f;
            if (iy >= 0 && iy < IH && ix >= 0 && ix < IW)
                v = h[(((long)n * IH + iy) * IW + ix) * 64 + cb * 32 + ci];
            Ts[(j * 130 + xs) * 33 + ci] = v;
        }
        __syncthreads();
#pragma unroll
        for (int j = 0; j < 2; ++j)
#pragma unroll
            for (int i = 0; i < 2; ++i) {
                int ky = (1 - py) + 2 * j;
                int kx = (1 - parx) + 2 * i;
                const float* wp = &Ws[((ky * 4 + kx) * 64 + cb * 32) * 3];
                const float* tp = &Ts[(j * 130 + (ixb - i)) * 33];
#pragma unroll 8
                for (int ci = 0; ci < 32; ++ci) {
                    float a = tp[ci];
                    acc[0] = fmaf(a, wp[ci * 3 + 0], acc[0]);
                    acc[1] = fmaf(a, wp[ci * 3 + 1], acc[1]);
                    acc[2] = fmaf(a, wp[ci * 3 + 2], acc[2]);
                }
            }
    }
    long obase = (((long)n * 3) * OH + oy) * OW + ox;
    out[obase]               = acc[0] + bias[0];
    out[obase + OH * OW]     = acc[1] + bias[1];
    out[obase + 2 * OH * OW] = acc[2] + bias[2];
}

// ---------------------------------------------------------------------------
__global__ void loss_kernel(const float* __restrict__ sums, float* __restrict__ out) {
    out[0] = sums[0] * (1.f / (16384.f * 64.f)) + sums[1] * (1.f / (65536.f * 64.f));
}

// ---------------------------------------------------------------------------
extern "C" void kernel_launch(void* const* d_in, const int* in_sizes, int n_in,
                              void* d_out, int out_size, void* d_ws, size_t ws_size,
                              hipStream_t stream) {
    const float* x   = (const float*)d_in[0];
    const float* wb1 = (const float*)d_in[1];  const float* bb1 = (const float*)d_in[2];
    const float* wb2 = (const float*)d_in[3];  const float* bb2 = (const float*)d_in[4];
    const float* wt1 = (const float*)d_in[5];  const float* bt1 = (const float*)d_in[6];
    const float* wqt = (const float*)d_in[7];  const float* bqt = (const float*)d_in[8];
    const float* embed_t = (const float*)d_in[9];
    const float* wdt = (const float*)d_in[10]; const float* bdt = (const float*)d_in[11];
    const float* wqb = (const float*)d_in[12]; const float* bqb = (const float*)d_in[13];
    const float* embed_b = (const float*)d_in[14];
    const float* wup = (const float*)d_in[15]; const float* bup = (const float*)d_in[16];
    const float* wd1 = (const float*)d_in[17]; const float* bd1 = (const float*)d_in[18];
    const float* wd2 = (const float*)d_in[19]; const float* bd2 = (const float*)d_in[20];
    float* out = (float*)d_out;
    float* ws  = (float*)d_ws;

    // d_out layout (floats): x_hat @0 (3145728) | quant_t @3145728 (1048576) |
    // quant_b @4194304 (4194304) | loss @8388608 (1) | id_t @8388609 (16384) |
    // id_b @8404993 (65536)
    float* O_XHAT = out;
    float* O_QT   = out + 3145728;
    float* O_QB   = out + 4194304;
    float* O_LOSS = out + 8388608;
    float* O_IDT  = out + 8388609;
    float* O_IDB  = out + 8404993;

    // ws layout (floats) — total 42,991,616 floats = 172 MB
    float* W_WB1 = ws + 0;        // 6144
    float* W_WB2 = ws + 8192;     // 262144
    float* W_WT1 = ws + 270336;   // 262144
    float* W_WQT = ws + 532480;   // 8192
    float* W_WDT = ws + 540672;   // 65536
    float* W_WQB = ws + 606208;   // 12288
    float* W_WUP = ws + 618496;   // 65536
    float* W_WD1 = ws + 684032;   // 131072
    float* W_WD2 = ws + 815104;   // 3072
    float* EN_T  = ws + 818176;   // 512
    float* EN_B  = ws + 818688;   // 512
    float* SUMS  = ws + 819200;   // 2
    float* T1    = ws + 1048576;          // enc_b NHWC [16,64,64,128]
    const long BIG = 9437184;
    float* T0   = ws + BIG;               // enc_b1 NHWC [16,128,128,128]
    float* T2   = ws + BIG;               // enc_t NHWC [16,32,32,128] (reuses T0)
    float* QT   = ws + BIG + 2097152;     // qt NHWC [16,32,32,64]
    float* QTN  = ws + BIG + 3145728;     // quant_t NHWC
    float* DECT = ws + BIG + 4194304;     // dec_t NHWC [16,64,64,64]
    float* ECAT = ws + BIG + 8388608;     // enc_cat NHWC [16,64,64,192]
    float* QB   = ws + BIG + 20971520;    // qb NHWC [16,64,64,64]
    float* QBN  = ws + BIG + 25165824;    // quant_b NHWC
    float* UPT  = ws + BIG + 4194304;     // up_t (reuses DECT)
    float* QCAT = ws + BIG + 8388608;     // quant_cat NHWC [16,64,64,128] (reuses ECAT)
    float* HBUF = ws + BIG + 16777216;    // h NHWC [16,128,128,64]

    // weight transforms
    auto wt_launch = [&](const float* src, float* dst, int cin, int cout, int taps, int iohw) {
        int tot = cin * cout * taps;
        wtrans_kernel<<<(tot + TPB - 1) / TPB, TPB, 0, stream>>>(src, dst, cin, cout, taps, iohw);
    };
    wt_launch(wb1, W_WB1, 3, 128, 16, 0);
    wt_launch(wb2, W_WB2, 128, 128, 16, 0);
    wt_launch(wt1, W_WT1, 128, 128, 16, 0);
    wt_launch(wqt, W_WQT, 128, 64, 1, 0);
    wt_launch(wdt, W_WDT, 64, 64, 16, 1);
    wt_launch(wqb, W_WQB, 192, 64, 1, 0);
    wt_launch(wup, W_WUP, 64, 64, 16, 1);
    wt_launch(wd1, W_WD1, 128, 64, 16, 1);
    wt_launch(wd2, W_WD2, 64, 3, 16, 1);
    enorm_kernel<<<4, TPB, 0, stream>>>(embed_t, embed_b, EN_T, EN_B);
    hipMemsetAsync((void*)SUMS, 0, 2 * sizeof(float), stream);

    // encode
    conv1_kernel<<<4096, TPB, 0, stream>>>(x, W_WB1, bb1, T0);
    conv_gemm<0, 128, 128, 64, 1, 128, 128, 64, 64><<<1024, TPB, 0, stream>>>(T0, W_WB2, bb2, T1);
    conv_gemm<0, 128, 128, 32, 1, 64, 64, 32, 32><<<512, TPB, 0, stream>>>(T1, W_WT1, bt1, T2);
    conv_gemm<2, 128, 64, 32, 0, 32, 32, 32, 32><<<512, TPB, 0, stream>>>(T2, W_WQT, bqt, QT);
    quantize_kernel<<<512, TPB, 0, stream>>>(QT, embed_t, EN_T, QTN, O_QT, O_IDT, SUMS,
                                             16384, 1024, 32);
    conv_gemm<1, 64, 64, 32, 0, 32, 32, 64, 64><<<2048, TPB, 0, stream>>>(QTN, W_WDT, bdt, DECT);
    concat_kernel<<<12288, TPB, 0, stream>>>(DECT, T1, ECAT, 64, 128, 65536);
    conv_gemm<2, 192, 64, 64, 0, 64, 64, 64, 64><<<1024, TPB, 0, stream>>>(ECAT, W_WQB, bqb, QB);
    quantize_kernel<<<2048, TPB, 0, stream>>>(QB, embed_b, EN_B, QBN, O_QB, O_IDB, SUMS + 1,
                                              65536, 4096, 64);
    // decode
    conv_gemm<1, 64, 64, 32, 0, 32, 32, 64, 64><<<2048, TPB, 0, stream>>>(QTN, W_WUP, bup, UPT);
    concat_kernel<<<8192, TPB, 0, stream>>>(UPT, QBN, QCAT, 64, 64, 65536);
    conv_gemm<1, 128, 64, 64, 1, 64, 64, 128, 128><<<4096, TPB, 0, stream>>>(QCAT, W_WD1, bd1, HBUF);
    convt_final_kernel<<<4096, TPB, 0, stream>>>(HBUF, W_WD2, bd2, O_XHAT);
    loss_kernel<<<1, 1, 0, stream>>>(SUMS, O_LOSS);

    (void)in_sizes; (void)n_in; (void)out_size; (void)ws_size;
}

// Round 2
// 1543.706 us; speedup vs baseline: 1.5850x; 1.5850x over previous
//
#include <hip/hip_runtime.h>

#define TPB 256

// ---------------------------------------------------------------------------
// Weight transform: src OIHW (iohw=0) or IOHW (iohw=1)  ->  dst [tap][ci][co]
// ---------------------------------------------------------------------------
__global__ void wtrans_kernel(const float* __restrict__ src, float* __restrict__ dst,
                              int CIN, int COUT, int taps, int iohw) {
    int idx = blockIdx.x * TPB + threadIdx.x;
    int tot = CIN * COUT * taps;
    if (idx >= tot) return;
    int co = idx % COUT;
    int ci = (idx / COUT) % CIN;
    int tap = idx / (COUT * CIN);
    float v = iohw ? src[(ci * COUT + co) * taps + tap]
                   : src[(co * CIN + ci) * taps + tap];
    dst[idx] = v;
}

// ---------------------------------------------------------------------------
// conv1: x NCHW [16,3,256,256] -> out NHWC [16,128,128,128], 4x4 s2 p1 + ReLU
// grid = 16*128*2, block = 256.  BM = 64 output px per block.
// ---------------------------------------------------------------------------
__global__ __launch_bounds__(256) void conv1_kernel(
    const float* __restrict__ x, const float* __restrict__ Wt,
    const float* __restrict__ bias, float* __restrict__ out) {
    const int IH = 256, IW = 256, OH = 128, OW = 128, BM = 64;
    int bx = blockIdx.x;
    int sx = bx & 1;
    int oy = (bx >> 1) & 127;
    int n  = bx >> 8;
    int ox0 = sx * BM;
    __shared__ float Bs[16 * 3 * 128];   // [tap][ci][co]
    __shared__ float Ts[3 * 4 * 132];    // [ci][ky][130 padded to 132]
    int tid = threadIdx.x;
    for (int i = tid; i < 6144 / 4; i += TPB)
        ((float4*)Bs)[i] = ((const float4*)Wt)[i];
    int iy0 = 2 * oy - 1;
    for (int idx = tid; idx < 3 * 4 * 130; idx += TPB) {
        int ci = idx / 520; int r = idx % 520;
        int ky = r / 130;   int xx = r % 130;
        int iy = iy0 + ky;  int ix = 2 * ox0 - 1 + xx;
        float v = 0.f;
        if (iy >= 0 && iy < IH && ix >= 0 && ix < IW)
            v = x[((n * 3 + ci) * IH + iy) * IW + ix];
        Ts[(ci * 4 + ky) * 132 + xx] = v;
    }
    __syncthreads();
    int cog = tid & 31, pxg = tid >> 5;
    int co0 = cog * 4, px0 = pxg * 8;
    float acc[8][4];
#pragma unroll
    for (int i = 0; i < 8; ++i)
#pragma unroll
        for (int j = 0; j < 4; ++j) acc[i][j] = 0.f;
#pragma unroll 1
    for (int ky = 0; ky < 4; ++ky)
#pragma unroll 1
        for (int kx = 0; kx < 4; ++kx)
#pragma unroll
            for (int ci = 0; ci < 3; ++ci) {
                float4 b = *(const float4*)&Bs[((ky * 4 + kx) * 3 + ci) * 128 + co0];
                const float* trow = &Ts[(ci * 4 + ky) * 132 + kx];
#pragma unroll
                for (int q = 0; q < 8; ++q) {
                    float a = trow[2 * (px0 + q)];
                    acc[q][0] = fmaf(a, b.x, acc[q][0]);
                    acc[q][1] = fmaf(a, b.y, acc[q][1]);
                    acc[q][2] = fmaf(a, b.z, acc[q][2]);
                    acc[q][3] = fmaf(a, b.w, acc[q][3]);
                }
            }
    float4 bb = *(const float4*)&bias[co0];
#pragma unroll
    for (int q = 0; q < 8; ++q) {
        int ox = ox0 + px0 + q;
        float4 v;
        v.x = fmaxf(acc[q][0] + bb.x, 0.f);
        v.y = fmaxf(acc[q][1] + bb.y, 0.f);
        v.z = fmaxf(acc[q][2] + bb.z, 0.f);
        v.w = fmaxf(acc[q][3] + bb.w, 0.f);
        *(float4*)&out[(((long)n * OH + oy) * OW + ox) * 128 + co0] = v;
    }
}

// ---------------------------------------------------------------------------
// Generic tiled conv-as-GEMM.  NHWC in/out.
// MODE 0: 4x4 s2 p1 conv.  MODE 1: 4x4 s2 p1 convT (gather).  MODE 2: 1x1.
// Block: BM output pixels x COUT channels, 256 threads.
// For MODE 1, BM must equal OW/2 (one parity strip per block).
// ---------------------------------------------------------------------------
template<int MODE, int CIN, int COUT, int BM, int RELU, int IH, int IW, int OH, int OW>
__global__ __launch_bounds__(256) void conv_gemm(
    const float* __restrict__ in, const float* __restrict__ Wt,
    const float* __restrict__ bias, float* __restrict__ out) {
    constexpr int CHUNK  = 64;
    constexpr int NCH    = CIN / CHUNK;
    constexpr int CO_PER = (COUT == 128) ? 4 : 2;
    constexpr int PX_PER = BM / 8;
    constexpr int TAPS   = (MODE == 0) ? 16 : (MODE == 1 ? 4 : 1);
    __shared__ float As[CHUNK * BM];
    __shared__ float Bs[CHUNK * COUT];
    const int tid = threadIdx.x;
    const int bx  = blockIdx.x;
    int n, oy, ox0 = 0, par = 0;
    if (MODE == 1) {
        par = bx & 1;
        oy  = (bx >> 1) % OH;
        n   = bx / (2 * OH);
    } else {
        constexpr int SPR = OW / BM;
        int s = bx % SPR;
        oy = (bx / SPR) % OH;
        n  = bx / (SPR * OH);
        ox0 = s * BM;
    }
    const int cog = tid & 31;          // COUT/CO_PER == 32 in all instantiations
    const int pxg = tid >> 5;
    const int co0 = cog * CO_PER, px0 = pxg * PX_PER;
    float acc[PX_PER][CO_PER];
#pragma unroll
    for (int q = 0; q < PX_PER; ++q)
#pragma unroll
        for (int j = 0; j < CO_PER; ++j) acc[q][j] = 0.f;
    constexpr int TPX  = 256 / BM;
    constexpr int CIPT = CHUNK / TPX;
    const int spx  = tid / TPX;
    const int sci0 = (tid % TPX) * CIPT;
    const int py   = oy & 1;

#pragma unroll 1
    for (int tap = 0; tap < TAPS; ++tap) {
        int iy, twi, sx;
        if (MODE == 0) {
            int ky = tap >> 2, kx = tap & 3;
            iy  = 2 * oy - 1 + ky;
            sx  = 2 * (ox0 + spx) - 1 + kx;
            twi = tap;
        } else if (MODE == 1) {
            int jj = tap >> 1, ii = tap & 1;
            iy  = ((oy + 1) >> 1) - jj;
            sx  = spx + par - ii;
            twi = ((1 - py) + 2 * jj) * 4 + ((1 - par) + 2 * ii);
        } else {
            iy = oy; sx = ox0 + spx; twi = 0;
        }
        const bool pxv = (iy >= 0) && (iy < IH) && (sx >= 0) && (sx < IW);
        const float* srcp = in + (((long)n * IH + iy) * IW + sx) * CIN + sci0;
#pragma unroll 1
        for (int cb = 0; cb < NCH; ++cb) {
            __syncthreads();
            float4 tmp[CIPT / 4];
#pragma unroll
            for (int t4 = 0; t4 < CIPT / 4; ++t4) {
                if (pxv) tmp[t4] = *(const float4*)(srcp + cb * CHUNK + 4 * t4);
                else { tmp[t4].x = 0.f; tmp[t4].y = 0.f; tmp[t4].z = 0.f; tmp[t4].w = 0.f; }
            }
#pragma unroll
            for (int t4 = 0; t4 < CIPT / 4; ++t4) {
                As[(sci0 + 4 * t4 + 0) * BM + spx] = tmp[t4].x;
                As[(sci0 + 4 * t4 + 1) * BM + spx] = tmp[t4].y;
                As[(sci0 + 4 * t4 + 2) * BM + spx] = tmp[t4].z;
                As[(sci0 + 4 * t4 + 3) * BM + spx] = tmp[t4].w;
            }
            {
                const float4* wsrc = (const float4*)(Wt + ((long)twi * CIN + cb * CHUNK) * COUT);
#pragma unroll
                for (int t4 = 0; t4 < (CHUNK * COUT) / 1024; ++t4)
                    ((float4*)Bs)[tid + 256 * t4] = wsrc[tid + 256 * t4];
            }
            __syncthreads();
#pragma unroll 4
            for (int k = 0; k < CHUNK; ++k) {
                float a[PX_PER];
#pragma unroll
                for (int t4 = 0; t4 < PX_PER / 4; ++t4)
                    *(float4*)&a[4 * t4] = *(const float4*)&As[k * BM + px0 + 4 * t4];
                if constexpr (CO_PER == 4) {
                    float4 b = *(const float4*)&Bs[k * COUT + co0];
#pragma unroll
                    for (int q = 0; q < PX_PER; ++q) {
                        acc[q][0] = fmaf(a[q], b.x, acc[q][0]);
                        acc[q][1] = fmaf(a[q], b.y, acc[q][1]);
                        acc[q][2] = fmaf(a[q], b.z, acc[q][2]);
                        acc[q][3] = fmaf(a[q], b.w, acc[q][3]);
                    }
                } else {
                    float2 b = *(const float2*)&Bs[k * COUT + co0];
#pragma unroll
                    for (int q = 0; q < PX_PER; ++q) {
                        acc[q][0] = fmaf(a[q], b.x, acc[q][0]);
                        acc[q][1] = fmaf(a[q], b.y, acc[q][1]);
                    }
                }
            }
        }
    }
    float bv[CO_PER];
#pragma unroll
    for (int j = 0; j < CO_PER; ++j) bv[j] = bias[co0 + j];
#pragma unroll
    for (int q = 0; q < PX_PER; ++q) {
        int ox = (MODE == 1) ? (par + 2 * (px0 + q)) : (ox0 + px0 + q);
        float* op = out + (((long)n * OH + oy) * OW + ox) * COUT + co0;
        if constexpr (CO_PER == 4) {
            float4 v;
            v.x = acc[q][0] + bv[0]; v.y = acc[q][1] + bv[1];
            v.z = acc[q][2] + bv[2]; v.w = acc[q][3] + bv[3];
            if (RELU) { v.x = fmaxf(v.x, 0.f); v.y = fmaxf(v.y, 0.f);
                        v.z = fmaxf(v.z, 0.f); v.w = fmaxf(v.w, 0.f); }
            *(float4*)op = v;
        } else {
            float2 v;
            v.x = acc[q][0] + bv[0]; v.y = acc[q][1] + bv[1];
            if (RELU) { v.x = fmaxf(v.x, 0.f); v.y = fmaxf(v.y, 0.f); }
            *(float2*)op = v;
        }
    }
}

// ---------------------------------------------------------------------------
// Codebook squared norms for both embeds. grid=4, block=256.
// ---------------------------------------------------------------------------
__global__ void enorm_kernel(const float* __restrict__ et, const float* __restrict__ eb,
                             float* __restrict__ nt, float* __restrict__ nb) {
    int k = blockIdx.x * TPB + threadIdx.x;
    if (k >= 1024) return;
    const float* e = (k < 512) ? et : eb;
    float* o = (k < 512) ? nt : nb;
    int kk = k & 511;
    float s = 0.f;
#pragma unroll 8
    for (int d = 0; d < 64; ++d) { float v = e[d * 512 + kk]; s = fmaf(v, v, s); }
    o[kk] = s;
}

// ---------------------------------------------------------------------------
// Vector quantize: f [M,64] NHWC rows, embed [64,512].
// Block = 256 threads = 4 waves; block handles 32 consecutive rows (8/wave).
// Lane holds 8 codes; argmin(|e|^2 - 2 f.e) via shfl butterfly with
// first-index tie-break.  Outputs:
//   qn  NHWC (coalesced 4B/lane)
//   qc  NCHW via LDS transpose -> 32-px (128 B) contiguous strips per channel
//   ido row index (lane 0)
//   dsum: ONE atomicAdd per block (reg accumulate -> shfl reduce -> LDS).
// Requires 32 | HW (true: 1024, 4096) so a block never crosses an image.
// ---------------------------------------------------------------------------
__global__ __launch_bounds__(256) void quantize_kernel(
    const float* __restrict__ f, const float* __restrict__ embed,
    const float* __restrict__ enorm, float* __restrict__ qn,
    float* __restrict__ qc, float* __restrict__ ido, float* __restrict__ dsum,
    int M, int HW) {
    __shared__ float S[32][65];
    __shared__ float wsum[4];
    int lane = threadIdx.x & 63;
    int wave = threadIdx.x >> 6;
    int R0 = blockIdx.x * 32;
    int row0 = R0 + wave * 8;
    int c0 = lane * 8;
    const float* fr = f + (long)row0 * 64;
    float dot[8][8];
#pragma unroll
    for (int r = 0; r < 8; ++r)
#pragma unroll
        for (int j = 0; j < 8; ++j) dot[r][j] = 0.f;
#pragma unroll 2
    for (int d = 0; d < 64; ++d) {
        float4 e0 = *(const float4*)(embed + d * 512 + c0);
        float4 e1 = *(const float4*)(embed + d * 512 + c0 + 4);
#pragma unroll
        for (int r = 0; r < 8; ++r) {
            float fd = fr[r * 64 + d];
            dot[r][0] = fmaf(fd, e0.x, dot[r][0]);
            dot[r][1] = fmaf(fd, e0.y, dot[r][1]);
            dot[r][2] = fmaf(fd, e0.z, dot[r][2]);
            dot[r][3] = fmaf(fd, e0.w, dot[r][3]);
            dot[r][4] = fmaf(fd, e1.x, dot[r][4]);
            dot[r][5] = fmaf(fd, e1.y, dot[r][5]);
            dot[r][6] = fmaf(fd, e1.z, dot[r][6]);
            dot[r][7] = fmaf(fd, e1.w, dot[r][7]);
        }
    }
    float4 n0 = *(const float4*)(enorm + c0);
    float4 n1 = *(const float4*)(enorm + c0 + 4);
    float en[8] = { n0.x, n0.y, n0.z, n0.w, n1.x, n1.y, n1.z, n1.w };
    float ddacc = 0.f;
#pragma unroll 1
    for (int r = 0; r < 8; ++r) {
        float bvv = en[0] - 2.f * dot[r][0];
        int bi = c0;
#pragma unroll
        for (int j = 1; j < 8; ++j) {
            float s = en[j] - 2.f * dot[r][j];
            if (s < bvv) { bvv = s; bi = c0 + j; }
        }
#pragma unroll
        for (int off = 1; off < 64; off <<= 1) {
            float ov = __shfl_xor(bvv, off);
            int   oi = __shfl_xor(bi, off);
            if (ov < bvv || (ov == bvv && oi < bi)) { bvv = ov; bi = oi; }
        }
        int k = bi;
        int row = row0 + r;
        float ev = embed[lane * 512 + k];
        float fv = fr[r * 64 + lane];
        qn[(long)row * 64 + lane] = ev;
        S[wave * 8 + r][lane] = ev;
        float dq = ev - fv;
        ddacc = fmaf(dq, dq, ddacc);
        if (lane == 0) ido[row] = (float)k;
    }
#pragma unroll
    for (int off = 1; off < 64; off <<= 1) ddacc += __shfl_xor(ddacc, off);
    if (lane == 0) wsum[wave] = ddacc;
    __syncthreads();
    if (threadIdx.x == 0)
        atomicAdd(dsum, wsum[0] + wsum[1] + wsum[2] + wsum[3]);
    // transposed NCHW store: 32 threads per channel strip, 128 B contiguous
    int nn = R0 / HW;
    int rem0 = R0 - nn * HW;
    int px = threadIdx.x & 31;
    int cg = threadIdx.x >> 5;   // 0..7
#pragma unroll
    for (int it = 0; it < 8; ++it) {
        int c = cg + 8 * it;
        qc[((long)nn * 64 + c) * HW + rem0 + px] = S[px][c];
    }
}

// ---------------------------------------------------------------------------
// Channel concat NHWC: o[row] = [a(ca) | b(cb)], float4 granularity.
// ---------------------------------------------------------------------------
__global__ void concat_kernel(const float* __restrict__ a, const float* __restrict__ b,
                              float* __restrict__ o, int ca, int cb, int M) {
    int fpr = (ca + cb) >> 2;
    int idx = blockIdx.x * TPB + threadIdx.x;
    if (idx >= M * fpr) return;
    int row = idx / fpr;
    int c4  = (idx - row * fpr) * 4;
    float4 v;
    if (c4 < ca) v = *(const float4*)(a + (long)row * ca + c4);
    else         v = *(const float4*)(b + (long)row * cb + (c4 - ca));
    *(float4*)(o + (long)row * (ca + cb) + c4) = v;
}

// ---------------------------------------------------------------------------
// Final convT 64->3 (4x4 s2 p1): h NHWC [16,128,128,64] -> x_hat NCHW
// [16,3,256,256].  grid = 16*256 rows, block = 256 (one thread per ox).
// ---------------------------------------------------------------------------
__global__ __launch_bounds__(256) void convt_final_kernel(
    const float* __restrict__ h, const float* __restrict__ Wt,
    const float* __restrict__ bias, float* __restrict__ out) {
    const int IH = 128, IW = 128, OH = 256, OW = 256;
    int n  = blockIdx.x >> 8;
    int oy = blockIdx.x & 255;
    __shared__ float Ws[16 * 64 * 3];     // [tap][ci][co]
    __shared__ float Ts[2 * 130 * 33];    // [j][ix+1][ci%32], padded
    int tid = threadIdx.x;
    for (int i = tid; i < 3072; i += TPB) Ws[i] = Wt[i];
    int py = oy & 1;
    int iyb = (oy + 1) >> 1;
    int ox = tid;
    int parx = ox & 1;
    int ixb = ((ox + 1) >> 1) + 1;
    float acc[3] = {0.f, 0.f, 0.f};
#pragma unroll 1
    for (int cb = 0; cb < 2; ++cb) {
        __syncthreads();
        for (int idx = tid; idx < 2 * 130 * 32; idx += TPB) {
            int j = idx / (130 * 32);
            int r = idx - j * (130 * 32);
            int xs = r >> 5; int ci = r & 31;
            int iy = iyb - j; int ix = xs - 1;
            float v = 0.f;
            if (iy >= 0 && iy < IH && ix >= 0 && ix < IW)
                v = h[(((long)n * IH + iy) * IW + ix) * 64 + cb * 32 + ci];
            Ts[(j * 130 + xs) * 33 + ci] = v;
        }
        __syncthreads();
#pragma unroll
        for (int j = 0; j < 2; ++j)
#pragma unroll
            for (int i = 0; i < 2; ++i) {
                int ky = (1 - py) + 2 * j;
                int kx = (1 - parx) + 2 * i;
                const float* wp = &Ws[((ky * 4 + kx) * 64 + cb * 32) * 3];
                const float* tp = &Ts[(j * 130 + (ixb - i)) * 33];
#pragma unroll 8
                for (int ci = 0; ci < 32; ++ci) {
                    float a = tp[ci];
                    acc[0] = fmaf(a, wp[ci * 3 + 0], acc[0]);
                    acc[1] = fmaf(a, wp[ci * 3 + 1], acc[1]);
                    acc[2] = fmaf(a, wp[ci * 3 + 2], acc[2]);
                }
            }
    }
    long obase = (((long)n * 3) * OH + oy) * OW + ox;
    out[obase]               = acc[0] + bias[0];
    out[obase + OH * OW]     = acc[1] + bias[1];
    out[obase + 2 * OH * OW] = acc[2] + bias[2];
}

// ---------------------------------------------------------------------------
__global__ void loss_kernel(const float* __restrict__ sums, float* __restrict__ out) {
    out[0] = sums[0] * (1.f / (16384.f * 64.f)) + sums[1] * (1.f / (65536.f * 64.f));
}

// ---------------------------------------------------------------------------
extern "C" void kernel_launch(void* const* d_in, const int* in_sizes, int n_in,
                              void* d_out, int out_size, void* d_ws, size_t ws_size,
                              hipStream_t stream) {
    const float* x   = (const float*)d_in[0];
    const float* wb1 = (const float*)d_in[1];  const float* bb1 = (const float*)d_in[2];
    const float* wb2 = (const float*)d_in[3];  const float* bb2 = (const float*)d_in[4];
    const float* wt1 = (const float*)d_in[5];  const float* bt1 = (const float*)d_in[6];
    const float* wqt = (const float*)d_in[7];  const float* bqt = (const float*)d_in[8];
    const float* embed_t = (const float*)d_in[9];
    const float* wdt = (const float*)d_in[10]; const float* bdt = (const float*)d_in[11];
    const float* wqb = (const float*)d_in[12]; const float* bqb = (const float*)d_in[13];
    const float* embed_b = (const float*)d_in[14];
    const float* wup = (const float*)d_in[15]; const float* bup = (const float*)d_in[16];
    const float* wd1 = (const float*)d_in[17]; const float* bd1 = (const float*)d_in[18];
    const float* wd2 = (const float*)d_in[19]; const float* bd2 = (const float*)d_in[20];
    float* out = (float*)d_out;
    float* ws  = (float*)d_ws;

    // d_out layout (floats): x_hat @0 (3145728) | quant_t @3145728 (1048576) |
    // quant_b @4194304 (4194304) | loss @8388608 (1) | id_t @8388609 (16384) |
    // id_b @8404993 (65536)
    float* O_XHAT = out;
    float* O_QT   = out + 3145728;
    float* O_QB   = out + 4194304;
    float* O_LOSS = out + 8388608;
    float* O_IDT  = out + 8388609;
    float* O_IDB  = out + 8404993;

    // ws layout (floats)
    float* W_WB1 = ws + 0;        // 6144
    float* W_WB2 = ws + 8192;     // 262144
    float* W_WT1 = ws + 270336;   // 262144
    float* W_WQT = ws + 532480;   // 8192
    float* W_WDT = ws + 540672;   // 65536
    float* W_WQB = ws + 606208;   // 12288
    float* W_WUP = ws + 618496;   // 65536
    float* W_WD1 = ws + 684032;   // 131072
    float* W_WD2 = ws + 815104;   // 3072
    float* EN_T  = ws + 818176;   // 512
    float* EN_B  = ws + 818688;   // 512
    float* SUMS  = ws + 819200;   // 2
    float* T1    = ws + 1048576;          // enc_b NHWC [16,64,64,128]
    const long BIG = 9437184;
    float* T0   = ws + BIG;               // enc_b1 NHWC [16,128,128,128]
    float* T2   = ws + BIG;               // enc_t NHWC [16,32,32,128] (reuses T0)
    float* QT   = ws + BIG + 2097152;     // qt NHWC [16,32,32,64]
    float* QTN  = ws + BIG + 3145728;     // quant_t NHWC
    float* DECT = ws + BIG + 4194304;     // dec_t NHWC [16,64,64,64]
    float* ECAT = ws + BIG + 8388608;     // enc_cat NHWC [16,64,64,192]
    float* QB   = ws + BIG + 20971520;    // qb NHWC [16,64,64,64]
    float* QBN  = ws + BIG + 25165824;    // quant_b NHWC
    float* UPT  = ws + BIG + 4194304;     // up_t (reuses DECT)
    float* QCAT = ws + BIG + 8388608;     // quant_cat NHWC [16,64,64,128] (reuses ECAT)
    float* HBUF = ws + BIG + 16777216;    // h NHWC [16,128,128,64]

    // weight transforms
    auto wt_launch = [&](const float* src, float* dst, int cin, int cout, int taps, int iohw) {
        int tot = cin * cout * taps;
        wtrans_kernel<<<(tot + TPB - 1) / TPB, TPB, 0, stream>>>(src, dst, cin, cout, taps, iohw);
    };
    wt_launch(wb1, W_WB1, 3, 128, 16, 0);
    wt_launch(wb2, W_WB2, 128, 128, 16, 0);
    wt_launch(wt1, W_WT1, 128, 128, 16, 0);
    wt_launch(wqt, W_WQT, 128, 64, 1, 0);
    wt_launch(wdt, W_WDT, 64, 64, 16, 1);
    wt_launch(wqb, W_WQB, 192, 64, 1, 0);
    wt_launch(wup, W_WUP, 64, 64, 16, 1);
    wt_launch(wd1, W_WD1, 128, 64, 16, 1);
    wt_launch(wd2, W_WD2, 64, 3, 16, 1);
    enorm_kernel<<<4, TPB, 0, stream>>>(embed_t, embed_b, EN_T, EN_B);
    hipMemsetAsync((void*)SUMS, 0, 2 * sizeof(float), stream);

    // encode
    conv1_kernel<<<4096, TPB, 0, stream>>>(x, W_WB1, bb1, T0);
    conv_gemm<0, 128, 128, 64, 1, 128, 128, 64, 64><<<1024, TPB, 0, stream>>>(T0, W_WB2, bb2, T1);
    conv_gemm<0, 128, 128, 32, 1, 64, 64, 32, 32><<<512, TPB, 0, stream>>>(T1, W_WT1, bt1, T2);
    conv_gemm<2, 128, 64, 32, 0, 32, 32, 32, 32><<<512, TPB, 0, stream>>>(T2, W_WQT, bqt, QT);
    quantize_kernel<<<512, TPB, 0, stream>>>(QT, embed_t, EN_T, QTN, O_QT, O_IDT, SUMS,
                                             16384, 1024);
    conv_gemm<1, 64, 64, 32, 0, 32, 32, 64, 64><<<2048, TPB, 0, stream>>>(QTN, W_WDT, bdt, DECT);
    concat_kernel<<<12288, TPB, 0, stream>>>(DECT, T1, ECAT, 64, 128, 65536);
    conv_gemm<2, 192, 64, 64, 0, 64, 64, 64, 64><<<1024, TPB, 0, stream>>>(ECAT, W_WQB, bqb, QB);
    quantize_kernel<<<2048, TPB, 0, stream>>>(QB, embed_b, EN_B, QBN, O_QB, O_IDB, SUMS + 1,
                                              65536, 4096);
    // decode
    conv_gemm<1, 64, 64, 32, 0, 32, 32, 64, 64><<<2048, TPB, 0, stream>>>(QTN, W_WUP, bup, UPT);
    concat_kernel<<<8192, TPB, 0, stream>>>(UPT, QBN, QCAT, 64, 64, 65536);
    conv_gemm<1, 128, 64, 64, 1, 64, 64, 128, 128><<<4096, TPB, 0, stream>>>(QCAT, W_WD1, bd1, HBUF);
    convt_final_kernel<<<4096, TPB, 0, stream>>>(HBUF, W_WD2, bd2, O_XHAT);
    loss_kernel<<<1, 1, 0, stream>>>(SUMS, O_LOSS);

    (void)in_sizes; (void)n_in; (void)out_size; (void)ws_size;
}

// Round 4
// 1003.128 us; speedup vs baseline: 2.4392x; 1.5389x over previous
//
#include <hip/hip_runtime.h>

#define TPB 256

typedef __attribute__((ext_vector_type(4))) float f32x4;
typedef __attribute__((ext_vector_type(8))) short bf16x8;

// ---------------------------------------------------------------------------
// Weight transform fp32: src OIHW (iohw=0) or IOHW (iohw=1) -> [tap][ci][co]
// ---------------------------------------------------------------------------
__global__ void wtrans_kernel(const float* __restrict__ src, float* __restrict__ dst,
                              int CIN, int COUT, int taps, int iohw) {
    int idx = blockIdx.x * TPB + threadIdx.x;
    int tot = CIN * COUT * taps;
    if (idx >= tot) return;
    int co = idx % COUT;
    int ci = (idx / COUT) % CIN;
    int tap = idx / (COUT * CIN);
    float v = iohw ? src[(ci * COUT + co) * taps + tap]
                   : src[(co * CIN + ci) * taps + tap];
    dst[idx] = v;
}

// ---------------------------------------------------------------------------
// RNE fp32 -> bf16 (finite inputs), returns 16-bit pattern in low bits.
// ---------------------------------------------------------------------------
__device__ __forceinline__ unsigned bf16_rne(float v) {
    unsigned u = __float_as_uint(v);
    return (u + 0x7FFFu + ((u >> 16) & 1u)) >> 16;
}

// ---------------------------------------------------------------------------
// Weight transform bf16-split: src OIHW/IOHW fp32 -> hi plane [tap][co][ci],
// lo plane at +PL.  hi = RNE-bf16(v), lo = RNE-bf16(v - hi).
// ---------------------------------------------------------------------------
__global__ void wtrans_bf16_kernel(const float* __restrict__ src, short* __restrict__ dst,
                                   int CIN, int COUT, int taps, int iohw, int PL) {
    int idx = blockIdx.x * TPB + threadIdx.x;
    int tot = CIN * COUT * taps;
    if (idx >= tot) return;
    int ci = idx % CIN;
    int co = (idx / CIN) % COUT;
    int tap = idx / (CIN * COUT);
    float v = iohw ? src[(ci * COUT + co) * taps + tap]
                   : src[(co * CIN + ci) * taps + tap];
    unsigned h = bf16_rne(v);
    float rem = v - __uint_as_float(h << 16);
    unsigned l = bf16_rne(rem);
    dst[idx] = (short)h;
    dst[idx + PL] = (short)l;
}

// ---------------------------------------------------------------------------
// fp32 pair -> packed bf16x2 helpers (RNE, integer path)
// ---------------------------------------------------------------------------
__device__ __forceinline__ void cvt_split2(float a, float b, unsigned& hw, unsigned& lw) {
    unsigned ha = bf16_rne(a), hb = bf16_rne(b);
    float ra = a - __uint_as_float(ha << 16);
    float rb = b - __uint_as_float(hb << 16);
    hw = ha | (hb << 16);
    lw = bf16_rne(ra) | (bf16_rne(rb) << 16);
}
__device__ __forceinline__ unsigned cvt_pk(float a, float b) {
    return bf16_rne(a) | (bf16_rne(b) << 16);
}

// ---------------------------------------------------------------------------
// MFMA implicit-GEMM conv.  NHWC fp32 in/out, bf16(-split) compute.
// MODE 0: 4x4 s2 p1 conv (16 taps).  MODE 1: 4x4 s2 p1 convT via 4 parity
// classes (4 taps each; block handles one class).
// Tile: 128 px (R rows of CW) x COUT.  256 threads = 4 waves.
// SPLIT=1: a=ah+al, b=bh+bl; D += ah*bh + al*bh + ah*bl (fp32-faithful).
// Weights Wb: bf16 planes [hi|lo][tap][co][ci].
// LDS rows stride 40 shorts (BK=32 + 8 pad): uniform bank coverage for both
// staging writes and frag reads.
// ---------------------------------------------------------------------------
template<int MODE, int CIN, int COUT, int SPLIT, int RELU,
         int IH, int IW, int OH, int OW, int R>
__global__ __launch_bounds__(256) void mfma_conv(
    const float* __restrict__ in, const short* __restrict__ Wb,
    const float* __restrict__ bias, float* __restrict__ outp) {
    constexpr int TAPS = (MODE == 0) ? 16 : 4;
    constexpr int CW = (MODE == 0) ? OW : OW / 2;   // tile-row width
    constexpr int CH = (MODE == 0) ? OH : OH / 2;   // tile-grid height
    constexpr int NCH = CIN / 32;
    constexpr int MTc = (COUT == 128) ? 4 : 2;
    constexpr long PL = (long)TAPS * COUT * CIN;

    __shared__ short Ah[128 * 40];
    __shared__ short Al[SPLIT ? 128 * 40 : 8];
    __shared__ short Bh[COUT * 40];
    __shared__ short Bl[SPLIT ? COUT * 40 : 8];

    int bx = blockIdx.x;
    int ry = 0, rx = 0;
    if (MODE == 1) { int c = bx & 3; ry = c >> 1; rx = c & 1; bx >>= 2; }
    const int y0 = (bx % (CH / R)) * R;
    const int n  = bx / (CH / R);

    const int tid = threadIdx.x;
    // A staging ids
    const int p  = tid >> 1;
    const int ak = (tid & 1) * 16;
    const int rr = p / CW, xx = p % CW;
    // B staging ids
    constexpr int BPT = (COUT * 32) / 256;   // shorts per thread: 16 or 8
    constexpr int TPRB = 32 / BPT;
    const int bco = tid / TPRB;
    const int bk  = (tid % TPRB) * BPT;
    // wave ids
    const int lane = tid & 63, wv = tid >> 6;
    const int quad = lane >> 4, l16 = lane & 15;
    const int mbase = (COUT == 128) ? (wv & 1) * 64 : wv * 32;
    const int nbase = (COUT == 128) ? (wv >> 1) * 64 : 0;

    f32x4 acc[MTc][4];
#pragma unroll
    for (int mt = 0; mt < MTc; ++mt)
#pragma unroll
        for (int nt = 0; nt < 4; ++nt) acc[mt][nt] = f32x4{0.f, 0.f, 0.f, 0.f};

#pragma unroll 1
    for (int tap = 0; tap < TAPS; ++tap) {
        int iy, ix, wt;
        if (MODE == 0) {
            int ky = tap >> 2, kx = tap & 3;
            iy = 2 * (y0 + rr) - 1 + ky;
            ix = 2 * xx - 1 + kx;
            wt = tap;
        } else {
            int jj = tap >> 1, ii = tap & 1;
            iy = (y0 + rr) + ry - jj;
            ix = xx + rx - ii;
            wt = ((1 - ry) + 2 * jj) * 4 + ((1 - rx) + 2 * ii);
        }
        const bool av = (iy >= 0) && (iy < IH) && (ix >= 0) && (ix < IW);
        const long abase = ((long)(n * IH + iy) * IW + ix) * CIN + ak;
        const short* wrh = Wb + ((long)wt * COUT + bco) * CIN + bk;

#pragma unroll 1
        for (int cb = 0; cb < NCH; ++cb) {
            __syncthreads();
            // ---- stage A (16 floats -> hi/lo bf16) ----
            float4 f[4];
            if (av) {
                const float* sp = in + abase + cb * 32;
#pragma unroll
                for (int i = 0; i < 4; ++i) f[i] = *(const float4*)(sp + 4 * i);
            } else {
#pragma unroll
                for (int i = 0; i < 4; ++i) { f[i].x = 0.f; f[i].y = 0.f; f[i].z = 0.f; f[i].w = 0.f; }
            }
            if constexpr (SPLIT) {
                unsigned hw[8], lw[8];
#pragma unroll
                for (int i = 0; i < 4; ++i) {
                    cvt_split2(f[i].x, f[i].y, hw[2 * i], lw[2 * i]);
                    cvt_split2(f[i].z, f[i].w, hw[2 * i + 1], lw[2 * i + 1]);
                }
                *(uint4*)&Ah[p * 40 + ak]     = make_uint4(hw[0], hw[1], hw[2], hw[3]);
                *(uint4*)&Ah[p * 40 + ak + 8] = make_uint4(hw[4], hw[5], hw[6], hw[7]);
                *(uint4*)&Al[p * 40 + ak]     = make_uint4(lw[0], lw[1], lw[2], lw[3]);
                *(uint4*)&Al[p * 40 + ak + 8] = make_uint4(lw[4], lw[5], lw[6], lw[7]);
            } else {
                unsigned hw[8];
#pragma unroll
                for (int i = 0; i < 4; ++i) {
                    hw[2 * i]     = cvt_pk(f[i].x, f[i].y);
                    hw[2 * i + 1] = cvt_pk(f[i].z, f[i].w);
                }
                *(uint4*)&Ah[p * 40 + ak]     = make_uint4(hw[0], hw[1], hw[2], hw[3]);
                *(uint4*)&Ah[p * 40 + ak + 8] = make_uint4(hw[4], hw[5], hw[6], hw[7]);
            }
            // ---- stage B (already bf16 in global) ----
#pragma unroll
            for (int i = 0; i < BPT / 8; ++i) {
                *(uint4*)&Bh[bco * 40 + bk + 8 * i] = *(const uint4*)(wrh + cb * 32 + 8 * i);
                if constexpr (SPLIT)
                    *(uint4*)&Bl[bco * 40 + bk + 8 * i] = *(const uint4*)(wrh + PL + cb * 32 + 8 * i);
            }
            __syncthreads();
            // ---- MFMA ----
            bf16x8 ahf[MTc], alf[SPLIT ? MTc : 1];
#pragma unroll
            for (int mt = 0; mt < MTc; ++mt) {
                ahf[mt] = *(const bf16x8*)&Ah[(mbase + mt * 16 + l16) * 40 + quad * 8];
                if constexpr (SPLIT)
                    alf[mt] = *(const bf16x8*)&Al[(mbase + mt * 16 + l16) * 40 + quad * 8];
            }
#pragma unroll
            for (int nt = 0; nt < 4; ++nt) {
                bf16x8 bhf = *(const bf16x8*)&Bh[(nbase + nt * 16 + l16) * 40 + quad * 8];
#pragma unroll
                for (int mt = 0; mt < MTc; ++mt)
                    acc[mt][nt] = __builtin_amdgcn_mfma_f32_16x16x32_bf16(ahf[mt], bhf, acc[mt][nt], 0, 0, 0);
                if constexpr (SPLIT) {
                    bf16x8 blf = *(const bf16x8*)&Bl[(nbase + nt * 16 + l16) * 40 + quad * 8];
#pragma unroll
                    for (int mt = 0; mt < MTc; ++mt) {
                        acc[mt][nt] = __builtin_amdgcn_mfma_f32_16x16x32_bf16(alf[mt], bhf, acc[mt][nt], 0, 0, 0);
                        acc[mt][nt] = __builtin_amdgcn_mfma_f32_16x16x32_bf16(ahf[mt], blf, acc[mt][nt], 0, 0, 0);
                    }
                }
            }
        }
    }
    // ---- epilogue ----
#pragma unroll
    for (int mt = 0; mt < MTc; ++mt)
#pragma unroll
        for (int nt = 0; nt < 4; ++nt) {
            int co = nbase + nt * 16 + l16;
            float bv = bias[co];
#pragma unroll
            for (int r = 0; r < 4; ++r) {
                int pl = mbase + mt * 16 + quad * 4 + r;
                int rr2 = pl / CW, x2 = pl % CW;
                int oy, ox;
                if (MODE == 0) { oy = y0 + rr2; ox = x2; }
                else           { oy = 2 * (y0 + rr2) + ry; ox = 2 * x2 + rx; }
                float vv = acc[mt][nt][r] + bv;
                if (RELU) vv = fmaxf(vv, 0.f);
                outp[((long)(n * OH + oy) * OW + ox) * COUT + co] = vv;
            }
        }
}

// ---------------------------------------------------------------------------
// conv1: x NCHW [16,3,256,256] -> out NHWC [16,128,128,128], 4x4 s2 p1 + ReLU
// ---------------------------------------------------------------------------
__global__ __launch_bounds__(256) void conv1_kernel(
    const float* __restrict__ x, const float* __restrict__ Wt,
    const float* __restrict__ bias, float* __restrict__ out) {
    const int IH = 256, IW = 256, OH = 128, OW = 128, BM = 64;
    int bx = blockIdx.x;
    int sx = bx & 1;
    int oy = (bx >> 1) & 127;
    int n  = bx >> 8;
    int ox0 = sx * BM;
    __shared__ float Bs[16 * 3 * 128];
    __shared__ float Ts[3 * 4 * 132];
    int tid = threadIdx.x;
    for (int i = tid; i < 6144 / 4; i += TPB)
        ((float4*)Bs)[i] = ((const float4*)Wt)[i];
    int iy0 = 2 * oy - 1;
    for (int idx = tid; idx < 3 * 4 * 130; idx += TPB) {
        int ci = idx / 520; int r = idx % 520;
        int ky = r / 130;   int xx = r % 130;
        int iy = iy0 + ky;  int ix = 2 * ox0 - 1 + xx;
        float v = 0.f;
        if (iy >= 0 && iy < IH && ix >= 0 && ix < IW)
            v = x[((n * 3 + ci) * IH + iy) * IW + ix];
        Ts[(ci * 4 + ky) * 132 + xx] = v;
    }
    __syncthreads();
    int cog = tid & 31, pxg = tid >> 5;
    int co0 = cog * 4, px0 = pxg * 8;
    float acc[8][4];
#pragma unroll
    for (int i = 0; i < 8; ++i)
#pragma unroll
        for (int j = 0; j < 4; ++j) acc[i][j] = 0.f;
#pragma unroll 1
    for (int ky = 0; ky < 4; ++ky)
#pragma unroll 1
        for (int kx = 0; kx < 4; ++kx)
#pragma unroll
            for (int ci = 0; ci < 3; ++ci) {
                float4 b = *(const float4*)&Bs[((ky * 4 + kx) * 3 + ci) * 128 + co0];
                const float* trow = &Ts[(ci * 4 + ky) * 132 + kx];
#pragma unroll
                for (int q = 0; q < 8; ++q) {
                    float a = trow[2 * (px0 + q)];
                    acc[q][0] = fmaf(a, b.x, acc[q][0]);
                    acc[q][1] = fmaf(a, b.y, acc[q][1]);
                    acc[q][2] = fmaf(a, b.z, acc[q][2]);
                    acc[q][3] = fmaf(a, b.w, acc[q][3]);
                }
            }
    float4 bb = *(const float4*)&bias[co0];
#pragma unroll
    for (int q = 0; q < 8; ++q) {
        int ox = ox0 + px0 + q;
        float4 v;
        v.x = fmaxf(acc[q][0] + bb.x, 0.f);
        v.y = fmaxf(acc[q][1] + bb.y, 0.f);
        v.z = fmaxf(acc[q][2] + bb.z, 0.f);
        v.w = fmaxf(acc[q][3] + bb.w, 0.f);
        *(float4*)&out[(((long)n * OH + oy) * OW + ox) * 128 + co0] = v;
    }
}

// ---------------------------------------------------------------------------
// Generic fp32 tiled conv-as-GEMM (kept for wqt / wqb / wdt).
// MODE 1: convT gather (parity strips).  MODE 2: 1x1.
// ---------------------------------------------------------------------------
template<int MODE, int CIN, int COUT, int BM, int RELU, int IH, int IW, int OH, int OW>
__global__ __launch_bounds__(256) void conv_gemm(
    const float* __restrict__ in, const float* __restrict__ Wt,
    const float* __restrict__ bias, float* __restrict__ out) {
    constexpr int CHUNK  = 64;
    constexpr int NCH    = CIN / CHUNK;
    constexpr int CO_PER = (COUT == 128) ? 4 : 2;
    constexpr int PX_PER = BM / 8;
    constexpr int TAPS   = (MODE == 0) ? 16 : (MODE == 1 ? 4 : 1);
    __shared__ float As[CHUNK * BM];
    __shared__ float Bs[CHUNK * COUT];
    const int tid = threadIdx.x;
    const int bx  = blockIdx.x;
    int n, oy, ox0 = 0, par = 0;
    if (MODE == 1) {
        par = bx & 1;
        oy  = (bx >> 1) % OH;
        n   = bx / (2 * OH);
    } else {
        constexpr int SPR = OW / BM;
        int s = bx % SPR;
        oy = (bx / SPR) % OH;
        n  = bx / (SPR * OH);
        ox0 = s * BM;
    }
    const int cog = tid & 31;
    const int pxg = tid >> 5;
    const int co0 = cog * CO_PER, px0 = pxg * PX_PER;
    float acc[PX_PER][CO_PER];
#pragma unroll
    for (int q = 0; q < PX_PER; ++q)
#pragma unroll
        for (int j = 0; j < CO_PER; ++j) acc[q][j] = 0.f;
    constexpr int TPX  = 256 / BM;
    constexpr int CIPT = CHUNK / TPX;
    const int spx  = tid / TPX;
    const int sci0 = (tid % TPX) * CIPT;
    const int py   = oy & 1;

#pragma unroll 1
    for (int tap = 0; tap < TAPS; ++tap) {
        int iy, twi, sx;
        if (MODE == 0) {
            int ky = tap >> 2, kx = tap & 3;
            iy  = 2 * oy - 1 + ky;
            sx  = 2 * (ox0 + spx) - 1 + kx;
            twi = tap;
        } else if (MODE == 1) {
            int jj = tap >> 1, ii = tap & 1;
            iy  = ((oy + 1) >> 1) - jj;
            sx  = spx + par - ii;
            twi = ((1 - py) + 2 * jj) * 4 + ((1 - par) + 2 * ii);
        } else {
            iy = oy; sx = ox0 + spx; twi = 0;
        }
        const bool pxv = (iy >= 0) && (iy < IH) && (sx >= 0) && (sx < IW);
        const float* srcp = in + (((long)n * IH + iy) * IW + sx) * CIN + sci0;
#pragma unroll 1
        for (int cb = 0; cb < NCH; ++cb) {
            __syncthreads();
            float4 tmp[CIPT / 4];
#pragma unroll
            for (int t4 = 0; t4 < CIPT / 4; ++t4) {
                if (pxv) tmp[t4] = *(const float4*)(srcp + cb * CHUNK + 4 * t4);
                else { tmp[t4].x = 0.f; tmp[t4].y = 0.f; tmp[t4].z = 0.f; tmp[t4].w = 0.f; }
            }
#pragma unroll
            for (int t4 = 0; t4 < CIPT / 4; ++t4) {
                As[(sci0 + 4 * t4 + 0) * BM + spx] = tmp[t4].x;
                As[(sci0 + 4 * t4 + 1) * BM + spx] = tmp[t4].y;
                As[(sci0 + 4 * t4 + 2) * BM + spx] = tmp[t4].z;
                As[(sci0 + 4 * t4 + 3) * BM + spx] = tmp[t4].w;
            }
            {
                const float4* wsrc = (const float4*)(Wt + ((long)twi * CIN + cb * CHUNK) * COUT);
#pragma unroll
                for (int t4 = 0; t4 < (CHUNK * COUT) / 1024; ++t4)
                    ((float4*)Bs)[tid + 256 * t4] = wsrc[tid + 256 * t4];
            }
            __syncthreads();
#pragma unroll 4
            for (int k = 0; k < CHUNK; ++k) {
                float a[PX_PER];
#pragma unroll
                for (int t4 = 0; t4 < PX_PER / 4; ++t4)
                    *(float4*)&a[4 * t4] = *(const float4*)&As[k * BM + px0 + 4 * t4];
                if constexpr (CO_PER == 4) {
                    float4 b = *(const float4*)&Bs[k * COUT + co0];
#pragma unroll
                    for (int q = 0; q < PX_PER; ++q) {
                        acc[q][0] = fmaf(a[q], b.x, acc[q][0]);
                        acc[q][1] = fmaf(a[q], b.y, acc[q][1]);
                        acc[q][2] = fmaf(a[q], b.z, acc[q][2]);
                        acc[q][3] = fmaf(a[q], b.w, acc[q][3]);
                    }
                } else {
                    float2 b = *(const float2*)&Bs[k * COUT + co0];
#pragma unroll
                    for (int q = 0; q < PX_PER; ++q) {
                        acc[q][0] = fmaf(a[q], b.x, acc[q][0]);
                        acc[q][1] = fmaf(a[q], b.y, acc[q][1]);
                    }
                }
            }
        }
    }
    float bv[CO_PER];
#pragma unroll
    for (int j = 0; j < CO_PER; ++j) bv[j] = bias[co0 + j];
#pragma unroll
    for (int q = 0; q < PX_PER; ++q) {
        int ox = (MODE == 1) ? (par + 2 * (px0 + q)) : (ox0 + px0 + q);
        float* op = out + (((long)n * OH + oy) * OW + ox) * COUT + co0;
        if constexpr (CO_PER == 4) {
            float4 v;
            v.x = acc[q][0] + bv[0]; v.y = acc[q][1] + bv[1];
            v.z = acc[q][2] + bv[2]; v.w = acc[q][3] + bv[3];
            if (RELU) { v.x = fmaxf(v.x, 0.f); v.y = fmaxf(v.y, 0.f);
                        v.z = fmaxf(v.z, 0.f); v.w = fmaxf(v.w, 0.f); }
            *(float4*)op = v;
        } else {
            float2 v;
            v.x = acc[q][0] + bv[0]; v.y = acc[q][1] + bv[1];
            if (RELU) { v.x = fmaxf(v.x, 0.f); v.y = fmaxf(v.y, 0.f); }
            *(float2*)op = v;
        }
    }
}

// ---------------------------------------------------------------------------
__global__ void enorm_kernel(const float* __restrict__ et, const float* __restrict__ eb,
                             float* __restrict__ nt, float* __restrict__ nb) {
    int k = blockIdx.x * TPB + threadIdx.x;
    if (k >= 1024) return;
    const float* e = (k < 512) ? et : eb;
    float* o = (k < 512) ? nt : nb;
    int kk = k & 511;
    float s = 0.f;
#pragma unroll 8
    for (int d = 0; d < 64; ++d) { float v = e[d * 512 + kk]; s = fmaf(v, v, s); }
    o[kk] = s;
}

// ---------------------------------------------------------------------------
// Vector quantize (see round-2 comments).  One atomicAdd per block; NCHW out
// via LDS transpose in 32-px strips.
// ---------------------------------------------------------------------------
__global__ __launch_bounds__(256) void quantize_kernel(
    const float* __restrict__ f, const float* __restrict__ embed,
    const float* __restrict__ enorm, float* __restrict__ qn,
    float* __restrict__ qc, float* __restrict__ ido, float* __restrict__ dsum,
    int M, int HW) {
    __shared__ float S[32][65];
    __shared__ float wsum[4];
    int lane = threadIdx.x & 63;
    int wave = threadIdx.x >> 6;
    int R0 = blockIdx.x * 32;
    int row0 = R0 + wave * 8;
    int c0 = lane * 8;
    const float* fr = f + (long)row0 * 64;
    float dot[8][8];
#pragma unroll
    for (int r = 0; r < 8; ++r)
#pragma unroll
        for (int j = 0; j < 8; ++j) dot[r][j] = 0.f;
#pragma unroll 2
    for (int d = 0; d < 64; ++d) {
        float4 e0 = *(const float4*)(embed + d * 512 + c0);
        float4 e1 = *(const float4*)(embed + d * 512 + c0 + 4);
#pragma unroll
        for (int r = 0; r < 8; ++r) {
            float fd = fr[r * 64 + d];
            dot[r][0] = fmaf(fd, e0.x, dot[r][0]);
            dot[r][1] = fmaf(fd, e0.y, dot[r][1]);
            dot[r][2] = fmaf(fd, e0.z, dot[r][2]);
            dot[r][3] = fmaf(fd, e0.w, dot[r][3]);
            dot[r][4] = fmaf(fd, e1.x, dot[r][4]);
            dot[r][5] = fmaf(fd, e1.y, dot[r][5]);
            dot[r][6] = fmaf(fd, e1.z, dot[r][6]);
            dot[r][7] = fmaf(fd, e1.w, dot[r][7]);
        }
    }
    float4 n0 = *(const float4*)(enorm + c0);
    float4 n1 = *(const float4*)(enorm + c0 + 4);
    float en[8] = { n0.x, n0.y, n0.z, n0.w, n1.x, n1.y, n1.z, n1.w };
    float ddacc = 0.f;
#pragma unroll 1
    for (int r = 0; r < 8; ++r) {
        float bvv = en[0] - 2.f * dot[r][0];
        int bi = c0;
#pragma unroll
        for (int j = 1; j < 8; ++j) {
            float s = en[j] - 2.f * dot[r][j];
            if (s < bvv) { bvv = s; bi = c0 + j; }
        }
#pragma unroll
        for (int off = 1; off < 64; off <<= 1) {
            float ov = __shfl_xor(bvv, off);
            int   oi = __shfl_xor(bi, off);
            if (ov < bvv || (ov == bvv && oi < bi)) { bvv = ov; bi = oi; }
        }
        int k = bi;
        int row = row0 + r;
        float ev = embed[lane * 512 + k];
        float fv = fr[r * 64 + lane];
        qn[(long)row * 64 + lane] = ev;
        S[wave * 8 + r][lane] = ev;
        float dq = ev - fv;
        ddacc = fmaf(dq, dq, ddacc);
        if (lane == 0) ido[row] = (float)k;
    }
#pragma unroll
    for (int off = 1; off < 64; off <<= 1) ddacc += __shfl_xor(ddacc, off);
    if (lane == 0) wsum[wave] = ddacc;
    __syncthreads();
    if (threadIdx.x == 0)
        atomicAdd(dsum, wsum[0] + wsum[1] + wsum[2] + wsum[3]);
    int nn = R0 / HW;
    int rem0 = R0 - nn * HW;
    int px = threadIdx.x & 31;
    int cg = threadIdx.x >> 5;
#pragma unroll
    for (int it = 0; it < 8; ++it) {
        int c = cg + 8 * it;
        qc[((long)nn * 64 + c) * HW + rem0 + px] = S[px][c];
    }
}

// ---------------------------------------------------------------------------
__global__ void concat_kernel(const float* __restrict__ a, const float* __restrict__ b,
                              float* __restrict__ o, int ca, int cb, int M) {
    int fpr = (ca + cb) >> 2;
    int idx = blockIdx.x * TPB + threadIdx.x;
    if (idx >= M * fpr) return;
    int row = idx / fpr;
    int c4  = (idx - row * fpr) * 4;
    float4 v;
    if (c4 < ca) v = *(const float4*)(a + (long)row * ca + c4);
    else         v = *(const float4*)(b + (long)row * cb + (c4 - ca));
    *(float4*)(o + (long)row * (ca + cb) + c4) = v;
}

// ---------------------------------------------------------------------------
// Final convT 64->3: h NHWC [16,128,128,64] -> x_hat NCHW [16,3,256,256]
// ---------------------------------------------------------------------------
__global__ __launch_bounds__(256) void convt_final_kernel(
    const float* __restrict__ h, const float* __restrict__ Wt,
    const float* __restrict__ bias, float* __restrict__ out) {
    const int IH = 128, IW = 128, OH = 256, OW = 256;
    int n  = blockIdx.x >> 8;
    int oy = blockIdx.x & 255;
    __shared__ float Ws[16 * 64 * 3];
    __shared__ float Ts[2 * 130 * 33];
    int tid = threadIdx.x;
    for (int i = tid; i < 3072; i += TPB) Ws[i] = Wt[i];
    int py = oy & 1;
    int iyb = (oy + 1) >> 1;
    int ox = tid;
    int parx = ox & 1;
    int ixb = ((ox + 1) >> 1) + 1;
    float acc[3] = {0.f, 0.f, 0.f};
#pragma unroll 1
    for (int cb = 0; cb < 2; ++cb) {
        __syncthreads();
        for (int idx = tid; idx < 2 * 130 * 32; idx += TPB) {
            int j = idx / (130 * 32);
            int r = idx - j * (130 * 32);
            int xs = r >> 5; int ci = r & 31;
            int iy = iyb - j; int ix = xs - 1;
            float v = 0.f;
            if (iy >= 0 && iy < IH && ix >= 0 && ix < IW)
                v = h[(((long)n * IH + iy) * IW + ix) * 64 + cb * 32 + ci];
            Ts[(j * 130 + xs) * 33 + ci] = v;
        }
        __syncthreads();
#pragma unroll
        for (int j = 0; j < 2; ++j)
#pragma unroll
            for (int i = 0; i < 2; ++i) {
                int ky = (1 - py) + 2 * j;
                int kx = (1 - parx) + 2 * i;
                const float* wp = &Ws[((ky * 4 + kx) * 64 + cb * 32) * 3];
                const float* tp = &Ts[(j * 130 + (ixb - i)) * 33];
#pragma unroll 8
                for (int ci = 0; ci < 32; ++ci) {
                    float a = tp[ci];
                    acc[0] = fmaf(a, wp[ci * 3 + 0], acc[0]);
                    acc[1] = fmaf(a, wp[ci * 3 + 1], acc[1]);
                    acc[2] = fmaf(a, wp[ci * 3 + 2], acc[2]);
                }
            }
    }
    long obase = (((long)n * 3) * OH + oy) * OW + ox;
    out[obase]               = acc[0] + bias[0];
    out[obase + OH * OW]     = acc[1] + bias[1];
    out[obase + 2 * OH * OW] = acc[2] + bias[2];
}

// ---------------------------------------------------------------------------
__global__ void loss_kernel(const float* __restrict__ sums, float* __restrict__ out) {
    out[0] = sums[0] * (1.f / (16384.f * 64.f)) + sums[1] * (1.f / (65536.f * 64.f));
}

// ---------------------------------------------------------------------------
extern "C" void kernel_launch(void* const* d_in, const int* in_sizes, int n_in,
                              void* d_out, int out_size, void* d_ws, size_t ws_size,
                              hipStream_t stream) {
    const float* x   = (const float*)d_in[0];
    const float* wb1 = (const float*)d_in[1];  const float* bb1 = (const float*)d_in[2];
    const float* wb2 = (const float*)d_in[3];  const float* bb2 = (const float*)d_in[4];
    const float* wt1 = (const float*)d_in[5];  const float* bt1 = (const float*)d_in[6];
    const float* wqt = (const float*)d_in[7];  const float* bqt = (const float*)d_in[8];
    const float* embed_t = (const float*)d_in[9];
    const float* wdt = (const float*)d_in[10]; const float* bdt = (const float*)d_in[11];
    const float* wqb = (const float*)d_in[12]; const float* bqb = (const float*)d_in[13];
    const float* embed_b = (const float*)d_in[14];
    const float* wup = (const float*)d_in[15]; const float* bup = (const float*)d_in[16];
    const float* wd1 = (const float*)d_in[17]; const float* bd1 = (const float*)d_in[18];
    const float* wd2 = (const float*)d_in[19]; const float* bd2 = (const float*)d_in[20];
    float* out = (float*)d_out;
    float* ws  = (float*)d_ws;

    float* O_XHAT = out;
    float* O_QT   = out + 3145728;
    float* O_QB   = out + 4194304;
    float* O_LOSS = out + 8388608;
    float* O_IDT  = out + 8388609;
    float* O_IDB  = out + 8404993;

    // ws layout (floats) — peak ≈ 43.72M floats ≈ 175 MB
    float* W_WB1 = ws + 0;        // 6144   (fp32, conv1)
    float* W_WQT = ws + 532480;   // 8192   (fp32 1x1)
    float* W_WDT = ws + 540672;   // 65536  (fp32 convT, id-critical)
    float* W_WQB = ws + 606208;   // 12288  (fp32 1x1)
    float* W_WD2 = ws + 815104;   // 3072   (fp32 final convT)
    float* EN_T  = ws + 818176;   // 512
    float* EN_B  = ws + 818688;   // 512
    float* SUMS  = ws + 819200;   // 2
    float* T1    = ws + 1048576;          // enc_b NHWC [16,64,64,128] fp32
    const long BIG = 9437184;
    float* T0   = ws + BIG;               // enc_b1 NHWC [16,128,128,128] fp32
    float* T2   = ws + BIG;               // enc_t NHWC (reuses T0 after conv2)
    float* QT   = ws + BIG + 2097152;
    float* QTN  = ws + BIG + 3145728;
    float* DECT = ws + BIG + 4194304;
    float* ECAT = ws + BIG + 8388608;
    float* QB   = ws + BIG + 20971520;
    float* QBN  = ws + BIG + 25165824;
    float* UPT  = ws + BIG + 4194304;     // reuses DECT
    float* QCAT = ws + BIG + 8388608;     // reuses ECAT
    float* HBUF = ws + BIG + 16777216;
    // bf16 split weight planes (shorts), after T0's end @ 42,991,616 floats
    short* WB_BF2 = (short*)(ws + 42991616);  // [2][16][128][128] = 524288 sh
    short* WB_BT1 = (short*)(ws + 43253760);  // [2][16][128][128]
    short* WB_BD1 = (short*)(ws + 43515904);  // [2][16][64][128]  = 262144 sh
    short* WB_BUP = (short*)(ws + 43646976);  // [2][16][64][64]   = 131072 sh

    auto wt_launch = [&](const float* src, float* dst, int cin, int cout, int taps, int iohw) {
        int tot = cin * cout * taps;
        wtrans_kernel<<<(tot + TPB - 1) / TPB, TPB, 0, stream>>>(src, dst, cin, cout, taps, iohw);
    };
    auto wtb_launch = [&](const float* src, short* dst, int cin, int cout, int taps, int iohw) {
        int tot = cin * cout * taps;
        wtrans_bf16_kernel<<<(tot + TPB - 1) / TPB, TPB, 0, stream>>>(src, dst, cin, cout, taps, iohw, tot);
    };
    wt_launch(wb1, W_WB1, 3, 128, 16, 0);
    wt_launch(wqt, W_WQT, 128, 64, 1, 0);
    wt_launch(wdt, W_WDT, 64, 64, 16, 1);
    wt_launch(wqb, W_WQB, 192, 64, 1, 0);
    wt_launch(wd2, W_WD2, 64, 3, 16, 1);
    wtb_launch(wb2, WB_BF2, 128, 128, 16, 0);
    wtb_launch(wt1, WB_BT1, 128, 128, 16, 0);
    wtb_launch(wd1, WB_BD1, 128, 64, 16, 1);
    wtb_launch(wup, WB_BUP, 64, 64, 16, 1);
    enorm_kernel<<<4, TPB, 0, stream>>>(embed_t, embed_b, EN_T, EN_B);
    hipError_t e0 = hipMemsetAsync((void*)SUMS, 0, 2 * sizeof(float), stream);
    (void)e0;

    // ----- encode -----
    conv1_kernel<<<4096, TPB, 0, stream>>>(x, W_WB1, bb1, T0);
    // conv2: split-bf16 MFMA, 128->128, 128^2 -> 64^2
    mfma_conv<0, 128, 128, 1, 1, 128, 128, 64, 64, 2><<<512, TPB, 0, stream>>>(T0, WB_BF2, bb2, T1);
    // conv3: split-bf16 MFMA, 128->128, 64^2 -> 32^2
    mfma_conv<0, 128, 128, 1, 1, 64, 64, 32, 32, 4><<<128, TPB, 0, stream>>>(T1, WB_BT1, bt1, T2);
    conv_gemm<2, 128, 64, 32, 0, 32, 32, 32, 32><<<512, TPB, 0, stream>>>(T2, W_WQT, bqt, QT);
    quantize_kernel<<<512, TPB, 0, stream>>>(QT, embed_t, EN_T, QTN, O_QT, O_IDT, SUMS,
                                             16384, 1024);
    conv_gemm<1, 64, 64, 32, 0, 32, 32, 64, 64><<<2048, TPB, 0, stream>>>(QTN, W_WDT, bdt, DECT);
    concat_kernel<<<12288, TPB, 0, stream>>>(DECT, T1, ECAT, 64, 128, 65536);
    conv_gemm<2, 192, 64, 64, 0, 64, 64, 64, 64><<<1024, TPB, 0, stream>>>(ECAT, W_WQB, bqb, QB);
    quantize_kernel<<<2048, TPB, 0, stream>>>(QB, embed_b, EN_B, QBN, O_QB, O_IDB, SUMS + 1,
                                              65536, 4096);
    // ----- decode -----
    // up_t: plain-bf16 MFMA convT 64->64, 32^2 -> 64^2
    mfma_conv<1, 64, 64, 0, 0, 32, 32, 64, 64, 4><<<512, TPB, 0, stream>>>(QTN, WB_BUP, bup, UPT);
    concat_kernel<<<8192, TPB, 0, stream>>>(UPT, QBN, QCAT, 64, 64, 65536);
    // dec1: plain-bf16 MFMA convT 128->64, 64^2 -> 128^2 + ReLU
    mfma_conv<1, 128, 64, 0, 1, 64, 64, 128, 128, 2><<<2048, TPB, 0, stream>>>(QCAT, WB_BD1, bd1, HBUF);
    convt_final_kernel<<<4096, TPB, 0, stream>>>(HBUF, W_WD2, bd2, O_XHAT);
    loss_kernel<<<1, 1, 0, stream>>>(SUMS, O_LOSS);

    (void)in_sizes; (void)n_in; (void)out_size; (void)ws_size;
}

// Round 5
// 893.465 us; speedup vs baseline: 2.7386x; 1.1227x over previous
//
#include <hip/hip_runtime.h>

#define TPB 256

typedef __attribute__((ext_vector_type(4))) float f32x4;
typedef __attribute__((ext_vector_type(8))) short bf16x8;

// ---------------------------------------------------------------------------
// Weight transform fp32: src OIHW (iohw=0) or IOHW (iohw=1) -> [tap][ci][co]
// ---------------------------------------------------------------------------
__global__ void wtrans_kernel(const float* __restrict__ src, float* __restrict__ dst,
                              int CIN, int COUT, int taps, int iohw) {
    int idx = blockIdx.x * TPB + threadIdx.x;
    int tot = CIN * COUT * taps;
    if (idx >= tot) return;
    int co = idx % COUT;
    int ci = (idx / COUT) % CIN;
    int tap = idx / (COUT * CIN);
    float v = iohw ? src[(ci * COUT + co) * taps + tap]
                   : src[(co * CIN + ci) * taps + tap];
    dst[idx] = v;
}

// ---------------------------------------------------------------------------
// RNE fp32 -> bf16 (finite inputs), returns 16-bit pattern in low bits.
// ---------------------------------------------------------------------------
__device__ __forceinline__ unsigned bf16_rne(float v) {
    unsigned u = __float_as_uint(v);
    return (u + 0x7FFFu + ((u >> 16) & 1u)) >> 16;
}

// ---------------------------------------------------------------------------
// Weight transform bf16-split: src OIHW/IOHW fp32 -> hi plane [tap][co][ci],
// lo plane at +PL.  hi = RNE-bf16(v), lo = RNE-bf16(v - hi).
// ---------------------------------------------------------------------------
__global__ void wtrans_bf16_kernel(const float* __restrict__ src, short* __restrict__ dst,
                                   int CIN, int COUT, int taps, int iohw, int PL) {
    int idx = blockIdx.x * TPB + threadIdx.x;
    int tot = CIN * COUT * taps;
    if (idx >= tot) return;
    int ci = idx % CIN;
    int co = (idx / CIN) % COUT;
    int tap = idx / (CIN * COUT);
    float v = iohw ? src[(ci * COUT + co) * taps + tap]
                   : src[(co * CIN + ci) * taps + tap];
    unsigned h = bf16_rne(v);
    float rem = v - __uint_as_float(h << 16);
    unsigned l = bf16_rne(rem);
    dst[idx] = (short)h;
    dst[idx + PL] = (short)l;
}

// ---------------------------------------------------------------------------
// wd2 weights -> bf16 [cls(4)][tap(4)][co(16 pad from 3)][ci(64)]
// cls = py*2+px, tap = jj*2+ii, ky = (1-py)+2jj, kx = (1-px)+2ii.
// src wd2: [Cin=64][Cout=3][4][4]
// ---------------------------------------------------------------------------
__global__ void wtrans_wd2_kernel(const float* __restrict__ src, short* __restrict__ dst) {
    int idx = blockIdx.x * TPB + threadIdx.x;
    if (idx >= 16384) return;
    int ci  = idx & 63;
    int co  = (idx >> 6) & 15;
    int tap = (idx >> 10) & 3;
    int cls = idx >> 12;
    int py = cls >> 1, px = cls & 1;
    int jj = tap >> 1, ii = tap & 1;
    int ky = (1 - py) + 2 * jj;
    int kx = (1 - px) + 2 * ii;
    float v = (co < 3) ? src[(ci * 3 + co) * 16 + ky * 4 + kx] : 0.f;
    dst[idx] = (short)bf16_rne(v);
}

// ---------------------------------------------------------------------------
// fp32 pair -> packed bf16x2 helpers (RNE, integer path)
// ---------------------------------------------------------------------------
__device__ __forceinline__ void cvt_split2(float a, float b, unsigned& hw, unsigned& lw) {
    unsigned ha = bf16_rne(a), hb = bf16_rne(b);
    float ra = a - __uint_as_float(ha << 16);
    float rb = b - __uint_as_float(hb << 16);
    hw = ha | (hb << 16);
    lw = bf16_rne(ra) | (bf16_rne(rb) << 16);
}
__device__ __forceinline__ unsigned cvt_pk(float a, float b) {
    return bf16_rne(a) | (bf16_rne(b) << 16);
}

// ---------------------------------------------------------------------------
// MFMA implicit-GEMM conv.  NHWC fp32 in/out, bf16(-split) compute.
// MODE 0: 4x4 s2 p1 conv (16 taps).  MODE 1: 4x4 s2 p1 convT via 4 parity
// classes (4 taps each; block handles one class).
// Tile: 128 px (R rows of CW) x COUT.  256 threads = 4 waves.
// SPLIT=1: a=ah+al, b=bh+bl; D += ah*bh + al*bh + ah*bl (fp32-faithful).
// Weights Wb: bf16 planes [hi|lo][tap][co][ci].
// ---------------------------------------------------------------------------
template<int MODE, int CIN, int COUT, int SPLIT, int RELU,
         int IH, int IW, int OH, int OW, int R>
__global__ __launch_bounds__(256) void mfma_conv(
    const float* __restrict__ in, const short* __restrict__ Wb,
    const float* __restrict__ bias, float* __restrict__ outp) {
    constexpr int TAPS = (MODE == 0) ? 16 : 4;
    constexpr int CW = (MODE == 0) ? OW : OW / 2;   // tile-row width
    constexpr int CH = (MODE == 0) ? OH : OH / 2;   // tile-grid height
    constexpr int NCH = CIN / 32;
    constexpr int MTc = (COUT == 128) ? 4 : 2;
    constexpr long PL = (long)TAPS * COUT * CIN;

    __shared__ short Ah[128 * 40];
    __shared__ short Al[SPLIT ? 128 * 40 : 8];
    __shared__ short Bh[COUT * 40];
    __shared__ short Bl[SPLIT ? COUT * 40 : 8];

    int bx = blockIdx.x;
    int ry = 0, rx = 0;
    if (MODE == 1) { int c = bx & 3; ry = c >> 1; rx = c & 1; bx >>= 2; }
    const int y0 = (bx % (CH / R)) * R;
    const int n  = bx / (CH / R);

    const int tid = threadIdx.x;
    // A staging ids
    const int p  = tid >> 1;
    const int ak = (tid & 1) * 16;
    const int rr = p / CW, xx = p % CW;
    // B staging ids
    constexpr int BPT = (COUT * 32) / 256;   // shorts per thread: 16 or 8
    constexpr int TPRB = 32 / BPT;
    const int bco = tid / TPRB;
    const int bk  = (tid % TPRB) * BPT;
    // wave ids
    const int lane = tid & 63, wv = tid >> 6;
    const int quad = lane >> 4, l16 = lane & 15;
    const int mbase = (COUT == 128) ? (wv & 1) * 64 : wv * 32;
    const int nbase = (COUT == 128) ? (wv >> 1) * 64 : 0;

    f32x4 acc[MTc][4];
#pragma unroll
    for (int mt = 0; mt < MTc; ++mt)
#pragma unroll
        for (int nt = 0; nt < 4; ++nt) acc[mt][nt] = f32x4{0.f, 0.f, 0.f, 0.f};

#pragma unroll 1
    for (int tap = 0; tap < TAPS; ++tap) {
        int iy, ix, wt;
        if (MODE == 0) {
            int ky = tap >> 2, kx = tap & 3;
            iy = 2 * (y0 + rr) - 1 + ky;
            ix = 2 * xx - 1 + kx;
            wt = tap;
        } else {
            int jj = tap >> 1, ii = tap & 1;
            iy = (y0 + rr) + ry - jj;
            ix = xx + rx - ii;
            wt = ((1 - ry) + 2 * jj) * 4 + ((1 - rx) + 2 * ii);
        }
        const bool av = (iy >= 0) && (iy < IH) && (ix >= 0) && (ix < IW);
        const long abase = ((long)(n * IH + iy) * IW + ix) * CIN + ak;
        const short* wrh = Wb + ((long)wt * COUT + bco) * CIN + bk;

#pragma unroll 1
        for (int cb = 0; cb < NCH; ++cb) {
            __syncthreads();
            // ---- stage A (16 floats -> hi/lo bf16) ----
            float4 f[4];
            if (av) {
                const float* sp = in + abase + cb * 32;
#pragma unroll
                for (int i = 0; i < 4; ++i) f[i] = *(const float4*)(sp + 4 * i);
            } else {
#pragma unroll
                for (int i = 0; i < 4; ++i) { f[i].x = 0.f; f[i].y = 0.f; f[i].z = 0.f; f[i].w = 0.f; }
            }
            if constexpr (SPLIT) {
                unsigned hw[8], lw[8];
#pragma unroll
                for (int i = 0; i < 4; ++i) {
                    cvt_split2(f[i].x, f[i].y, hw[2 * i], lw[2 * i]);
                    cvt_split2(f[i].z, f[i].w, hw[2 * i + 1], lw[2 * i + 1]);
                }
                *(uint4*)&Ah[p * 40 + ak]     = make_uint4(hw[0], hw[1], hw[2], hw[3]);
                *(uint4*)&Ah[p * 40 + ak + 8] = make_uint4(hw[4], hw[5], hw[6], hw[7]);
                *(uint4*)&Al[p * 40 + ak]     = make_uint4(lw[0], lw[1], lw[2], lw[3]);
                *(uint4*)&Al[p * 40 + ak + 8] = make_uint4(lw[4], lw[5], lw[6], lw[7]);
            } else {
                unsigned hw[8];
#pragma unroll
                for (int i = 0; i < 4; ++i) {
                    hw[2 * i]     = cvt_pk(f[i].x, f[i].y);
                    hw[2 * i + 1] = cvt_pk(f[i].z, f[i].w);
                }
                *(uint4*)&Ah[p * 40 + ak]     = make_uint4(hw[0], hw[1], hw[2], hw[3]);
                *(uint4*)&Ah[p * 40 + ak + 8] = make_uint4(hw[4], hw[5], hw[6], hw[7]);
            }
            // ---- stage B (already bf16 in global) ----
#pragma unroll
            for (int i = 0; i < BPT / 8; ++i) {
                *(uint4*)&Bh[bco * 40 + bk + 8 * i] = *(const uint4*)(wrh + cb * 32 + 8 * i);
                if constexpr (SPLIT)
                    *(uint4*)&Bl[bco * 40 + bk + 8 * i] = *(const uint4*)(wrh + PL + cb * 32 + 8 * i);
            }
            __syncthreads();
            // ---- MFMA ----
            bf16x8 ahf[MTc], alf[SPLIT ? MTc : 1];
#pragma unroll
            for (int mt = 0; mt < MTc; ++mt) {
                ahf[mt] = *(const bf16x8*)&Ah[(mbase + mt * 16 + l16) * 40 + quad * 8];
                if constexpr (SPLIT)
                    alf[mt] = *(const bf16x8*)&Al[(mbase + mt * 16 + l16) * 40 + quad * 8];
            }
#pragma unroll
            for (int nt = 0; nt < 4; ++nt) {
                bf16x8 bhf = *(const bf16x8*)&Bh[(nbase + nt * 16 + l16) * 40 + quad * 8];
#pragma unroll
                for (int mt = 0; mt < MTc; ++mt)
                    acc[mt][nt] = __builtin_amdgcn_mfma_f32_16x16x32_bf16(ahf[mt], bhf, acc[mt][nt], 0, 0, 0);
                if constexpr (SPLIT) {
                    bf16x8 blf = *(const bf16x8*)&Bl[(nbase + nt * 16 + l16) * 40 + quad * 8];
#pragma unroll
                    for (int mt = 0; mt < MTc; ++mt) {
                        acc[mt][nt] = __builtin_amdgcn_mfma_f32_16x16x32_bf16(alf[mt], bhf, acc[mt][nt], 0, 0, 0);
                        acc[mt][nt] = __builtin_amdgcn_mfma_f32_16x16x32_bf16(ahf[mt], blf, acc[mt][nt], 0, 0, 0);
                    }
                }
            }
        }
    }
    // ---- epilogue ----
#pragma unroll
    for (int mt = 0; mt < MTc; ++mt)
#pragma unroll
        for (int nt = 0; nt < 4; ++nt) {
            int co = nbase + nt * 16 + l16;
            float bv = bias[co];
#pragma unroll
            for (int r = 0; r < 4; ++r) {
                int pl = mbase + mt * 16 + quad * 4 + r;
                int rr2 = pl / CW, x2 = pl % CW;
                int oy, ox;
                if (MODE == 0) { oy = y0 + rr2; ox = x2; }
                else           { oy = 2 * (y0 + rr2) + ry; ox = 2 * x2 + rx; }
                float vv = acc[mt][nt][r] + bv;
                if (RELU) vv = fmaxf(vv, 0.f);
                outp[((long)(n * OH + oy) * OW + ox) * COUT + co] = vv;
            }
        }
}

// ---------------------------------------------------------------------------
// wd2 convT 64->3 via MFMA, N padded 3->16, all 4 parity classes per block.
// h NHWC [16,128,128,64] -> x_hat NCHW [16,3,256,256] (+bias).
// Block = (n, y): output rows oy=2y,2y+1, full width.  Stages h rows
// y-1..y+1 x 130 cols x 64ci as bf16 ONCE; 4 classes x 4 taps x 2 K-chunks.
// Weights Wc: [cls][tap][co16][ci64] bf16 (see wtrans_wd2_kernel).
// LDS row stride 72 shorts (36 words = 4 mod 32 -> uniform bank lattice).
// ---------------------------------------------------------------------------
__global__ __launch_bounds__(256) void convt_final_mfma(
    const float* __restrict__ h, const short* __restrict__ Wc,
    const float* __restrict__ bias, float* __restrict__ out) {
    const int HW = 128;                      // h spatial
    __shared__ short HB[3 * 130 * 72];       // [hr*130+xc][ci64 + 8 pad]
    __shared__ float Sout[6 * 260];          // [py*3+co][256 + 4 pad]

    const int tid = threadIdx.x;
    const int y = blockIdx.x & 127;
    const int n = blockIdx.x >> 7;
    const int lane = tid & 63, wv = tid >> 6;
    const int quad = lane >> 4, l16 = lane & 15;

    // ---- stage h rows y-1..y+1, cols -1..128, bf16 ----
    for (int u = tid; u < 780; u += TPB) {
        int row = u >> 1, half = u & 1;
        int hr = row / 130, xc = row % 130;
        int hy = y - 1 + hr, hx = xc - 1;
        unsigned w[8];
        if (hy >= 0 && hy < HW && hx >= 0 && hx < HW) {
            const float* sp = h + ((long)(n * HW + hy) * HW + hx) * 64 + half * 32;
#pragma unroll
            for (int i = 0; i < 4; ++i) {
                float4 f4 = *(const float4*)(sp + 8 * i);
                float4 g4 = *(const float4*)(sp + 8 * i + 4);
                w[2 * i]     = cvt_pk(f4.x, f4.y) ;
                w[2 * i]     = cvt_pk(f4.x, f4.y);
                w[2 * i + 1] = cvt_pk(f4.z, f4.w);
                // repack: we want ci order 0..7 -> two uints each pair
                w[2 * i + 1] = cvt_pk(f4.z, f4.w);
                (void)g4;
            }
            // NOTE: loop above only handled 16 of 32 ci; redo cleanly:
#pragma unroll
            for (int i = 0; i < 8; ++i) {
                float2 p2 = *(const float2*)(sp + 4 * i);
                float2 q2 = *(const float2*)(sp + 4 * i + 2);
                w[i] = cvt_pk(p2.x, p2.y);
                // store pairs sequentially: positions 4i..4i+3 shorts
                // w[i] holds shorts 4i,4i+1? No: each uint = 2 shorts.
                (void)q2;
            }
            // Final clean version: 32 ci = 16 uints? No - 32 shorts = 8 uint4/..
            // Simply: 32 floats -> 16 uints is wrong; 32 bf16 = 16 uints? 32
            // shorts = 16 uints. We emit 8 uints here (16 ci) - need 16.
        }
        // --- rewritten below ---
        {
            unsigned ww[16];
            bool ok = (hy >= 0 && hy < HW && hx >= 0 && hx < HW);
            const float* sp = h + ((long)(n * HW + hy) * HW + hx) * 64 + half * 32;
#pragma unroll
            for (int i = 0; i < 16; ++i) {
                float a = 0.f, b = 0.f;
                if (ok) { float2 p2 = *(const float2*)(sp + 2 * i); a = p2.x; b = p2.y; }
                ww[i] = cvt_pk(a, b);
            }
            short* dp = &HB[row * 72 + half * 32];
#pragma unroll
            for (int i = 0; i < 4; ++i)
                *(uint4*)(dp + 8 * i) = make_uint4(ww[4 * i], ww[4 * i + 1], ww[4 * i + 2], ww[4 * i + 3]);
        }
    }
    __syncthreads();

    // ---- 4 parity classes ----
#pragma unroll 1
    for (int cls = 0; cls < 4; ++cls) {
        const int py = cls >> 1, px = cls & 1;
        // B fragments in registers: [tap][cb]
        bf16x8 Bf[4][2];
#pragma unroll
        for (int tap = 0; tap < 4; ++tap)
#pragma unroll
            for (int cb = 0; cb < 2; ++cb)
                Bf[tap][cb] = *(const bf16x8*)&Wc[((cls * 4 + tap) * 16 + l16) * 64 + cb * 32 + quad * 8];

        f32x4 acc2[2] = { f32x4{0.f,0.f,0.f,0.f}, f32x4{0.f,0.f,0.f,0.f} };
#pragma unroll
        for (int mt = 0; mt < 2; ++mt) {
            const int xp0 = wv * 32 + mt * 16;
#pragma unroll
            for (int tap = 0; tap < 4; ++tap) {
                const int jj = tap >> 1, ii = tap & 1;
                const int hr = py - jj + 1;                     // 0..2
                const int rbase = (hr * 130 + xp0 + l16 + px - ii + 1) * 72;
#pragma unroll
                for (int cb = 0; cb < 2; ++cb) {
                    bf16x8 Af = *(const bf16x8*)&HB[rbase + cb * 32 + quad * 8];
                    acc2[mt] = __builtin_amdgcn_mfma_f32_16x16x32_bf16(Af, Bf[tap][cb], acc2[mt], 0, 0, 0);
                }
            }
        }
        // scatter C into Sout (only co<3 lanes)
        if (l16 < 3) {
#pragma unroll
            for (int mt = 0; mt < 2; ++mt)
#pragma unroll
                for (int r = 0; r < 4; ++r) {
                    int xp = wv * 32 + mt * 16 + quad * 4 + r;
                    Sout[(py * 3 + l16) * 260 + 2 * xp + px] = acc2[mt][r];
                }
        }
    }
    __syncthreads();

    // ---- write x_hat NCHW, coalesced float4 ----
    for (int u = tid; u < 384; u += TPB) {
        int idx = u * 4;
        int rowi = idx >> 8;          // 0..5 = py*3+co
        int xq   = idx & 255;
        int py = rowi / 3, co = rowi % 3;
        float bv = bias[co];
        float4 v = *(const float4*)&Sout[rowi * 260 + xq];
        v.x += bv; v.y += bv; v.z += bv; v.w += bv;
        *(float4*)&out[(((long)(n * 3 + co) * 256) + 2 * y + py) * 256 + xq] = v;
    }
}

// ---------------------------------------------------------------------------
// conv1: x NCHW [16,3,256,256] -> out NHWC [16,128,128,128], 4x4 s2 p1 + ReLU
// ---------------------------------------------------------------------------
__global__ __launch_bounds__(256) void conv1_kernel(
    const float* __restrict__ x, const float* __restrict__ Wt,
    const float* __restrict__ bias, float* __restrict__ out) {
    const int IH = 256, IW = 256, OH = 128, OW = 128, BM = 64;
    int bx = blockIdx.x;
    int sx = bx & 1;
    int oy = (bx >> 1) & 127;
    int n  = bx >> 8;
    int ox0 = sx * BM;
    __shared__ float Bs[16 * 3 * 128];
    __shared__ float Ts[3 * 4 * 132];
    int tid = threadIdx.x;
    for (int i = tid; i < 6144 / 4; i += TPB)
        ((float4*)Bs)[i] = ((const float4*)Wt)[i];
    int iy0 = 2 * oy - 1;
    for (int idx = tid; idx < 3 * 4 * 130; idx += TPB) {
        int ci = idx / 520; int r = idx % 520;
        int ky = r / 130;   int xx = r % 130;
        int iy = iy0 + ky;  int ix = 2 * ox0 - 1 + xx;
        float v = 0.f;
        if (iy >= 0 && iy < IH && ix >= 0 && ix < IW)
            v = x[((n * 3 + ci) * IH + iy) * IW + ix];
        Ts[(ci * 4 + ky) * 132 + xx] = v;
    }
    __syncthreads();
    int cog = tid & 31, pxg = tid >> 5;
    int co0 = cog * 4, px0 = pxg * 8;
    float acc[8][4];
#pragma unroll
    for (int i = 0; i < 8; ++i)
#pragma unroll
        for (int j = 0; j < 4; ++j) acc[i][j] = 0.f;
#pragma unroll 1
    for (int ky = 0; ky < 4; ++ky)
#pragma unroll 1
        for (int kx = 0; kx < 4; ++kx)
#pragma unroll
            for (int ci = 0; ci < 3; ++ci) {
                float4 b = *(const float4*)&Bs[((ky * 4 + kx) * 3 + ci) * 128 + co0];
                const float* trow = &Ts[(ci * 4 + ky) * 132 + kx];
#pragma unroll
                for (int q = 0; q < 8; ++q) {
                    float a = trow[2 * (px0 + q)];
                    acc[q][0] = fmaf(a, b.x, acc[q][0]);
                    acc[q][1] = fmaf(a, b.y, acc[q][1]);
                    acc[q][2] = fmaf(a, b.z, acc[q][2]);
                    acc[q][3] = fmaf(a, b.w, acc[q][3]);
                }
            }
    float4 bb = *(const float4*)&bias[co0];
#pragma unroll
    for (int q = 0; q < 8; ++q) {
        int ox = ox0 + px0 + q;
        float4 v;
        v.x = fmaxf(acc[q][0] + bb.x, 0.f);
        v.y = fmaxf(acc[q][1] + bb.y, 0.f);
        v.z = fmaxf(acc[q][2] + bb.z, 0.f);
        v.w = fmaxf(acc[q][3] + bb.w, 0.f);
        *(float4*)&out[(((long)n * OH + oy) * OW + ox) * 128 + co0] = v;
    }
}

// ---------------------------------------------------------------------------
// Generic fp32 tiled conv-as-GEMM (kept for wqt / wqb / wdt).
// MODE 1: convT gather (parity strips).  MODE 2: 1x1.
// ---------------------------------------------------------------------------
template<int MODE, int CIN, int COUT, int BM, int RELU, int IH, int IW, int OH, int OW>
__global__ __launch_bounds__(256) void conv_gemm(
    const float* __restrict__ in, const float* __restrict__ Wt,
    const float* __restrict__ bias, float* __restrict__ out) {
    constexpr int CHUNK  = 64;
    constexpr int NCH    = CIN / CHUNK;
    constexpr int CO_PER = (COUT == 128) ? 4 : 2;
    constexpr int PX_PER = BM / 8;
    constexpr int TAPS   = (MODE == 0) ? 16 : (MODE == 1 ? 4 : 1);
    __shared__ float As[CHUNK * BM];
    __shared__ float Bs[CHUNK * COUT];
    const int tid = threadIdx.x;
    const int bx  = blockIdx.x;
    int n, oy, ox0 = 0, par = 0;
    if (MODE == 1) {
        par = bx & 1;
        oy  = (bx >> 1) % OH;
        n   = bx / (2 * OH);
    } else {
        constexpr int SPR = OW / BM;
        int s = bx % SPR;
        oy = (bx / SPR) % OH;
        n  = bx / (SPR * OH);
        ox0 = s * BM;
    }
    const int cog = tid & 31;
    const int pxg = tid >> 5;
    const int co0 = cog * CO_PER, px0 = pxg * PX_PER;
    float acc[PX_PER][CO_PER];
#pragma unroll
    for (int q = 0; q < PX_PER; ++q)
#pragma unroll
        for (int j = 0; j < CO_PER; ++j) acc[q][j] = 0.f;
    constexpr int TPX  = 256 / BM;
    constexpr int CIPT = CHUNK / TPX;
    const int spx  = tid / TPX;
    const int sci0 = (tid % TPX) * CIPT;
    const int py   = oy & 1;

#pragma unroll 1
    for (int tap = 0; tap < TAPS; ++tap) {
        int iy, twi, sx;
        if (MODE == 0) {
            int ky = tap >> 2, kx = tap & 3;
            iy  = 2 * oy - 1 + ky;
            sx  = 2 * (ox0 + spx) - 1 + kx;
            twi = tap;
        } else if (MODE == 1) {
            int jj = tap >> 1, ii = tap & 1;
            iy  = ((oy + 1) >> 1) - jj;
            sx  = spx + par - ii;
            twi = ((1 - py) + 2 * jj) * 4 + ((1 - par) + 2 * ii);
        } else {
            iy = oy; sx = ox0 + spx; twi = 0;
        }
        const bool pxv = (iy >= 0) && (iy < IH) && (sx >= 0) && (sx < IW);
        const float* srcp = in + (((long)n * IH + iy) * IW + sx) * CIN + sci0;
#pragma unroll 1
        for (int cb = 0; cb < NCH; ++cb) {
            __syncthreads();
            float4 tmp[CIPT / 4];
#pragma unroll
            for (int t4 = 0; t4 < CIPT / 4; ++t4) {
                if (pxv) tmp[t4] = *(const float4*)(srcp + cb * CHUNK + 4 * t4);
                else { tmp[t4].x = 0.f; tmp[t4].y = 0.f; tmp[t4].z = 0.f; tmp[t4].w = 0.f; }
            }
#pragma unroll
            for (int t4 = 0; t4 < CIPT / 4; ++t4) {
                As[(sci0 + 4 * t4 + 0) * BM + spx] = tmp[t4].x;
                As[(sci0 + 4 * t4 + 1) * BM + spx] = tmp[t4].y;
                As[(sci0 + 4 * t4 + 2) * BM + spx] = tmp[t4].z;
                As[(sci0 + 4 * t4 + 3) * BM + spx] = tmp[t4].w;
            }
            {
                const float4* wsrc = (const float4*)(Wt + ((long)twi * CIN + cb * CHUNK) * COUT);
#pragma unroll
                for (int t4 = 0; t4 < (CHUNK * COUT) / 1024; ++t4)
                    ((float4*)Bs)[tid + 256 * t4] = wsrc[tid + 256 * t4];
            }
            __syncthreads();
#pragma unroll 4
            for (int k = 0; k < CHUNK; ++k) {
                float a[PX_PER];
#pragma unroll
                for (int t4 = 0; t4 < PX_PER / 4; ++t4)
                    *(float4*)&a[4 * t4] = *(const float4*)&As[k * BM + px0 + 4 * t4];
                if constexpr (CO_PER == 4) {
                    float4 b = *(const float4*)&Bs[k * COUT + co0];
#pragma unroll
                    for (int q = 0; q < PX_PER; ++q) {
                        acc[q][0] = fmaf(a[q], b.x, acc[q][0]);
                        acc[q][1] = fmaf(a[q], b.y, acc[q][1]);
                        acc[q][2] = fmaf(a[q], b.z, acc[q][2]);
                        acc[q][3] = fmaf(a[q], b.w, acc[q][3]);
                    }
                } else {
                    float2 b = *(const float2*)&Bs[k * COUT + co0];
#pragma unroll
                    for (int q = 0; q < PX_PER; ++q) {
                        acc[q][0] = fmaf(a[q], b.x, acc[q][0]);
                        acc[q][1] = fmaf(a[q], b.y, acc[q][1]);
                    }
                }
            }
        }
    }
    float bv[CO_PER];
#pragma unroll
    for (int j = 0; j < CO_PER; ++j) bv[j] = bias[co0 + j];
#pragma unroll
    for (int q = 0; q < PX_PER; ++q) {
        int ox = (MODE == 1) ? (par + 2 * (px0 + q)) : (ox0 + px0 + q);
        float* op = out + (((long)n * OH + oy) * OW + ox) * COUT + co0;
        if constexpr (CO_PER == 4) {
            float4 v;
            v.x = acc[q][0] + bv[0]; v.y = acc[q][1] + bv[1];
            v.z = acc[q][2] + bv[2]; v.w = acc[q][3] + bv[3];
            if (RELU) { v.x = fmaxf(v.x, 0.f); v.y = fmaxf(v.y, 0.f);
                        v.z = fmaxf(v.z, 0.f); v.w = fmaxf(v.w, 0.f); }
            *(float4*)op = v;
        } else {
            float2 v;
            v.x = acc[q][0] + bv[0]; v.y = acc[q][1] + bv[1];
            if (RELU) { v.x = fmaxf(v.x, 0.f); v.y = fmaxf(v.y, 0.f); }
            *(float2*)op = v;
        }
    }
}

// ---------------------------------------------------------------------------
__global__ void enorm_kernel(const float* __restrict__ et, const float* __restrict__ eb,
                             float* __restrict__ nt, float* __restrict__ nb) {
    int k = blockIdx.x * TPB + threadIdx.x;
    if (k >= 1024) return;
    const float* e = (k < 512) ? et : eb;
    float* o = (k < 512) ? nt : nb;
    int kk = k & 511;
    float s = 0.f;
#pragma unroll 8
    for (int d = 0; d < 64; ++d) { float v = e[d * 512 + kk]; s = fmaf(v, v, s); }
    o[kk] = s;
}

// ---------------------------------------------------------------------------
// Vector quantize.  One atomicAdd per block; NCHW out via LDS transpose.
// ---------------------------------------------------------------------------
__global__ __launch_bounds__(256) void quantize_kernel(
    const float* __restrict__ f, const float* __restrict__ embed,
    const float* __restrict__ enorm, float* __restrict__ qn,
    float* __restrict__ qc, float* __restrict__ ido, float* __restrict__ dsum,
    int M, int HW) {
    __shared__ float S[32][65];
    __shared__ float wsum[4];
    int lane = threadIdx.x & 63;
    int wave = threadIdx.x >> 6;
    int R0 = blockIdx.x * 32;
    int row0 = R0 + wave * 8;
    int c0 = lane * 8;
    const float* fr = f + (long)row0 * 64;
    float dot[8][8];
#pragma unroll
    for (int r = 0; r < 8; ++r)
#pragma unroll
        for (int j = 0; j < 8; ++j) dot[r][j] = 0.f;
#pragma unroll 2
    for (int d = 0; d < 64; ++d) {
        float4 e0 = *(const float4*)(embed + d * 512 + c0);
        float4 e1 = *(const float4*)(embed + d * 512 + c0 + 4);
#pragma unroll
        for (int r = 0; r < 8; ++r) {
            float fd = fr[r * 64 + d];
            dot[r][0] = fmaf(fd, e0.x, dot[r][0]);
            dot[r][1] = fmaf(fd, e0.y, dot[r][1]);
            dot[r][2] = fmaf(fd, e0.z, dot[r][2]);
            dot[r][3] = fmaf(fd, e0.w, dot[r][3]);
            dot[r][4] = fmaf(fd, e1.x, dot[r][4]);
            dot[r][5] = fmaf(fd, e1.y, dot[r][5]);
            dot[r][6] = fmaf(fd, e1.z, dot[r][6]);
            dot[r][7] = fmaf(fd, e1.w, dot[r][7]);
        }
    }
    float4 n0 = *(const float4*)(enorm + c0);
    float4 n1 = *(const float4*)(enorm + c0 + 4);
    float en[8] = { n0.x, n0.y, n0.z, n0.w, n1.x, n1.y, n1.z, n1.w };
    float ddacc = 0.f;
#pragma unroll 1
    for (int r = 0; r < 8; ++r) {
        float bvv = en[0] - 2.f * dot[r][0];
        int bi = c0;
#pragma unroll
        for (int j = 1; j < 8; ++j) {
            float s = en[j] - 2.f * dot[r][j];
            if (s < bvv) { bvv = s; bi = c0 + j; }
        }
#pragma unroll
        for (int off = 1; off < 64; off <<= 1) {
            float ov = __shfl_xor(bvv, off);
            int   oi = __shfl_xor(bi, off);
            if (ov < bvv || (ov == bvv && oi < bi)) { bvv = ov; bi = oi; }
        }
        int k = bi;
        int row = row0 + r;
        float ev = embed[lane * 512 + k];
        float fv = fr[r * 64 + lane];
        qn[(long)row * 64 + lane] = ev;
        S[wave * 8 + r][lane] = ev;
        float dq = ev - fv;
        ddacc = fmaf(dq, dq, ddacc);
        if (lane == 0) ido[row] = (float)k;
    }
#pragma unroll
    for (int off = 1; off < 64; off <<= 1) ddacc += __shfl_xor(ddacc, off);
    if (lane == 0) wsum[wave] = ddacc;
    __syncthreads();
    if (threadIdx.x == 0)
        atomicAdd(dsum, wsum[0] + wsum[1] + wsum[2] + wsum[3]);
    int nn = R0 / HW;
    int rem0 = R0 - nn * HW;
    int px = threadIdx.x & 31;
    int cg = threadIdx.x >> 5;
#pragma unroll
    for (int it = 0; it < 8; ++it) {
        int c = cg + 8 * it;
        qc[((long)nn * 64 + c) * HW + rem0 + px] = S[px][c];
    }
}

// ---------------------------------------------------------------------------
__global__ void concat_kernel(const float* __restrict__ a, const float* __restrict__ b,
                              float* __restrict__ o, int ca, int cb, int M) {
    int fpr = (ca + cb) >> 2;
    int idx = blockIdx.x * TPB + threadIdx.x;
    if (idx >= M * fpr) return;
    int row = idx / fpr;
    int c4  = (idx - row * fpr) * 4;
    float4 v;
    if (c4 < ca) v = *(const float4*)(a + (long)row * ca + c4);
    else         v = *(const float4*)(b + (long)row * cb + (c4 - ca));
    *(float4*)(o + (long)row * (ca + cb) + c4) = v;
}

// ---------------------------------------------------------------------------
__global__ void loss_kernel(const float* __restrict__ sums, float* __restrict__ out) {
    out[0] = sums[0] * (1.f / (16384.f * 64.f)) + sums[1] * (1.f / (65536.f * 64.f));
}

// ---------------------------------------------------------------------------
extern "C" void kernel_launch(void* const* d_in, const int* in_sizes, int n_in,
                              void* d_out, int out_size, void* d_ws, size_t ws_size,
                              hipStream_t stream) {
    const float* x   = (const float*)d_in[0];
    const float* wb1 = (const float*)d_in[1];  const float* bb1 = (const float*)d_in[2];
    const float* wb2 = (const float*)d_in[3];  const float* bb2 = (const float*)d_in[4];
    const float* wt1 = (const float*)d_in[5];  const float* bt1 = (const float*)d_in[6];
    const float* wqt = (const float*)d_in[7];  const float* bqt = (const float*)d_in[8];
    const float* embed_t = (const float*)d_in[9];
    const float* wdt = (const float*)d_in[10]; const float* bdt = (const float*)d_in[11];
    const float* wqb = (const float*)d_in[12]; const float* bqb = (const float*)d_in[13];
    const float* embed_b = (const float*)d_in[14];
    const float* wup = (const float*)d_in[15]; const float* bup = (const float*)d_in[16];
    const float* wd1 = (const float*)d_in[17]; const float* bd1 = (const float*)d_in[18];
    const float* wd2 = (const float*)d_in[19]; const float* bd2 = (const float*)d_in[20];
    float* out = (float*)d_out;
    float* ws  = (float*)d_ws;

    float* O_XHAT = out;
    float* O_QT   = out + 3145728;
    float* O_QB   = out + 4194304;
    float* O_LOSS = out + 8388608;
    float* O_IDT  = out + 8388609;
    float* O_IDB  = out + 8404993;

    // ws layout (floats)
    float* W_WB1 = ws + 0;        // 6144   (fp32, conv1)
    short* WB_WD2 = (short*)(ws + 16384);     // 16384 shorts (wd2 bf16 cls layout)
    float* W_WQT = ws + 532480;   // 8192   (fp32 1x1)
    float* W_WDT = ws + 540672;   // 65536  (fp32 convT, id-critical)
    float* W_WQB = ws + 606208;   // 12288  (fp32 1x1)
    float* EN_T  = ws + 818176;   // 512
    float* EN_B  = ws + 818688;   // 512
    float* SUMS  = ws + 819200;   // 2
    float* T1    = ws + 1048576;          // enc_b NHWC [16,64,64,128] fp32
    const long BIG = 9437184;
    float* T0   = ws + BIG;               // enc_b1 NHWC [16,128,128,128] fp32
    float* T2   = ws + BIG;               // enc_t NHWC (reuses T0 after conv2)
    float* QT   = ws + BIG + 2097152;
    float* QTN  = ws + BIG + 3145728;
    float* DECT = ws + BIG + 4194304;
    float* ECAT = ws + BIG + 8388608;
    float* QB   = ws + BIG + 20971520;
    float* QBN  = ws + BIG + 25165824;
    float* UPT  = ws + BIG + 4194304;     // reuses DECT
    float* QCAT = ws + BIG + 8388608;     // reuses ECAT
    float* HBUF = ws + BIG + 16777216;
    // bf16 split weight planes (shorts), after T0's end @ 42,991,616 floats
    short* WB_BF2 = (short*)(ws + 42991616);  // [2][16][128][128] = 524288 sh
    short* WB_BT1 = (short*)(ws + 43253760);  // [2][16][128][128]
    short* WB_BD1 = (short*)(ws + 43515904);  // [2][16][64][128]  = 262144 sh
    short* WB_BUP = (short*)(ws + 43646976);  // [2][16][64][64]   = 131072 sh

    auto wt_launch = [&](const float* src, float* dst, int cin, int cout, int taps, int iohw) {
        int tot = cin * cout * taps;
        wtrans_kernel<<<(tot + TPB - 1) / TPB, TPB, 0, stream>>>(src, dst, cin, cout, taps, iohw);
    };
    auto wtb_launch = [&](const float* src, short* dst, int cin, int cout, int taps, int iohw) {
        int tot = cin * cout * taps;
        wtrans_bf16_kernel<<<(tot + TPB - 1) / TPB, TPB, 0, stream>>>(src, dst, cin, cout, taps, iohw, tot);
    };
    wt_launch(wb1, W_WB1, 3, 128, 16, 0);
    wt_launch(wqt, W_WQT, 128, 64, 1, 0);
    wt_launch(wdt, W_WDT, 64, 64, 16, 1);
    wt_launch(wqb, W_WQB, 192, 64, 1, 0);
    wtrans_wd2_kernel<<<64, TPB, 0, stream>>>(wd2, WB_WD2);
    wtb_launch(wb2, WB_BF2, 128, 128, 16, 0);
    wtb_launch(wt1, WB_BT1, 128, 128, 16, 0);
    wtb_launch(wd1, WB_BD1, 128, 64, 16, 1);
    wtb_launch(wup, WB_BUP, 64, 64, 16, 1);
    enorm_kernel<<<4, TPB, 0, stream>>>(embed_t, embed_b, EN_T, EN_B);
    hipError_t e0 = hipMemsetAsync((void*)SUMS, 0, 2 * sizeof(float), stream);
    (void)e0;

    // ----- encode -----
    conv1_kernel<<<4096, TPB, 0, stream>>>(x, W_WB1, bb1, T0);
    mfma_conv<0, 128, 128, 1, 1, 128, 128, 64, 64, 2><<<512, TPB, 0, stream>>>(T0, WB_BF2, bb2, T1);
    mfma_conv<0, 128, 128, 1, 1, 64, 64, 32, 32, 4><<<128, TPB, 0, stream>>>(T1, WB_BT1, bt1, T2);
    conv_gemm<2, 128, 64, 32, 0, 32, 32, 32, 32><<<512, TPB, 0, stream>>>(T2, W_WQT, bqt, QT);
    quantize_kernel<<<512, TPB, 0, stream>>>(QT, embed_t, EN_T, QTN, O_QT, O_IDT, SUMS,
                                             16384, 1024);
    conv_gemm<1, 64, 64, 32, 0, 32, 32, 64, 64><<<2048, TPB, 0, stream>>>(QTN, W_WDT, bdt, DECT);
    concat_kernel<<<12288, TPB, 0, stream>>>(DECT, T1, ECAT, 64, 128, 65536);
    conv_gemm<2, 192, 64, 64, 0, 64, 64, 64, 64><<<1024, TPB, 0, stream>>>(ECAT, W_WQB, bqb, QB);
    quantize_kernel<<<2048, TPB, 0, stream>>>(QB, embed_b, EN_B, QBN, O_QB, O_IDB, SUMS + 1,
                                              65536, 4096);
    // ----- decode -----
    mfma_conv<1, 64, 64, 0, 0, 32, 32, 64, 64, 4><<<512, TPB, 0, stream>>>(QTN, WB_BUP, bup, UPT);
    concat_kernel<<<8192, TPB, 0, stream>>>(UPT, QBN, QCAT, 64, 64, 65536);
    mfma_conv<1, 128, 64, 0, 1, 64, 64, 128, 128, 2><<<2048, TPB, 0, stream>>>(QCAT, WB_BD1, bd1, HBUF);
    convt_final_mfma<<<2048, TPB, 0, stream>>>(HBUF, WB_WD2, bd2, O_XHAT);
    loss_kernel<<<1, 1, 0, stream>>>(SUMS, O_LOSS);

    (void)in_sizes; (void)n_in; (void)out_size; (void)ws_size;
}

// Round 6
// 802.083 us; speedup vs baseline: 3.0506x; 1.1139x over previous
//
#include <hip/hip_runtime.h>

#define TPB 256

typedef __attribute__((ext_vector_type(4))) float f32x4;
typedef __attribute__((ext_vector_type(8))) short bf16x8;

// ---------------------------------------------------------------------------
// Weight transform fp32: src OIHW (iohw=0) or IOHW (iohw=1) -> [tap][ci][co]
// ---------------------------------------------------------------------------
__global__ void wtrans_kernel(const float* __restrict__ src, float* __restrict__ dst,
                              int CIN, int COUT, int taps, int iohw) {
    int idx = blockIdx.x * TPB + threadIdx.x;
    int tot = CIN * COUT * taps;
    if (idx >= tot) return;
    int co = idx % COUT;
    int ci = (idx / COUT) % CIN;
    int tap = idx / (COUT * CIN);
    float v = iohw ? src[(ci * COUT + co) * taps + tap]
                   : src[(co * CIN + ci) * taps + tap];
    dst[idx] = v;
}

// ---------------------------------------------------------------------------
// RNE fp32 -> bf16 (finite inputs), returns 16-bit pattern in low bits.
// ---------------------------------------------------------------------------
__device__ __forceinline__ unsigned bf16_rne(float v) {
    unsigned u = __float_as_uint(v);
    return (u + 0x7FFFu + ((u >> 16) & 1u)) >> 16;
}

// ---------------------------------------------------------------------------
// Weight transform bf16-split: src OIHW/IOHW fp32 -> hi plane [tap][co][ci],
// lo plane at +PL.  hi = RNE-bf16(v), lo = RNE-bf16(v - hi).
// ---------------------------------------------------------------------------
__global__ void wtrans_bf16_kernel(const float* __restrict__ src, short* __restrict__ dst,
                                   int CIN, int COUT, int taps, int iohw, int PL) {
    int idx = blockIdx.x * TPB + threadIdx.x;
    int tot = CIN * COUT * taps;
    if (idx >= tot) return;
    int ci = idx % CIN;
    int co = (idx / CIN) % COUT;
    int tap = idx / (CIN * COUT);
    float v = iohw ? src[(ci * COUT + co) * taps + tap]
                   : src[(co * CIN + ci) * taps + tap];
    unsigned h = bf16_rne(v);
    float rem = v - __uint_as_float(h << 16);
    unsigned l = bf16_rne(rem);
    dst[idx] = (short)h;
    dst[idx + PL] = (short)l;
}

// ---------------------------------------------------------------------------
// wd2 weights -> bf16 [cls(4)][tap(4)][co(16 pad from 3)][ci(64)]
// ---------------------------------------------------------------------------
__global__ void wtrans_wd2_kernel(const float* __restrict__ src, short* __restrict__ dst) {
    int idx = blockIdx.x * TPB + threadIdx.x;
    if (idx >= 16384) return;
    int ci  = idx & 63;
    int co  = (idx >> 6) & 15;
    int tap = (idx >> 10) & 3;
    int cls = idx >> 12;
    int py = cls >> 1, px = cls & 1;
    int jj = tap >> 1, ii = tap & 1;
    int ky = (1 - py) + 2 * jj;
    int kx = (1 - px) + 2 * ii;
    float v = (co < 3) ? src[(ci * 3 + co) * 16 + ky * 4 + kx] : 0.f;
    dst[idx] = (short)bf16_rne(v);
}

// ---------------------------------------------------------------------------
// embed [64,512] fp32 -> transposed split bf16 [n=512][k=64], hi | lo planes.
// Handles both codebooks (idx < 32768 -> top table).
// ---------------------------------------------------------------------------
__global__ void etrans_kernel(const float* __restrict__ et, const float* __restrict__ eb,
                              short* __restrict__ ETt, short* __restrict__ ETb) {
    int idx = blockIdx.x * TPB + threadIdx.x;
    if (idx >= 65536) return;
    const float* src = (idx < 32768) ? et : eb;
    short* dst = (idx < 32768) ? ETt : ETb;
    int i = idx & 32767;
    int k = i & 63;
    int n = i >> 6;
    float v = src[k * 512 + n];
    unsigned h = bf16_rne(v);
    float rem = v - __uint_as_float(h << 16);
    dst[i] = (short)h;
    dst[i + 32768] = (short)bf16_rne(rem);
}

// ---------------------------------------------------------------------------
// fp32 pair -> packed bf16x2 helpers (RNE, integer path)
// ---------------------------------------------------------------------------
__device__ __forceinline__ void cvt_split2(float a, float b, unsigned& hw, unsigned& lw) {
    unsigned ha = bf16_rne(a), hb = bf16_rne(b);
    float ra = a - __uint_as_float(ha << 16);
    float rb = b - __uint_as_float(hb << 16);
    hw = ha | (hb << 16);
    lw = bf16_rne(ra) | (bf16_rne(rb) << 16);
}
__device__ __forceinline__ unsigned cvt_pk(float a, float b) {
    return bf16_rne(a) | (bf16_rne(b) << 16);
}

// ---------------------------------------------------------------------------
// MFMA implicit-GEMM conv.  NHWC fp32 in/out, bf16(-split) compute.
// (unchanged from round 4/5 — verified)
// ---------------------------------------------------------------------------
template<int MODE, int CIN, int COUT, int SPLIT, int RELU,
         int IH, int IW, int OH, int OW, int R>
__global__ __launch_bounds__(256) void mfma_conv(
    const float* __restrict__ in, const short* __restrict__ Wb,
    const float* __restrict__ bias, float* __restrict__ outp) {
    constexpr int TAPS = (MODE == 0) ? 16 : 4;
    constexpr int CW = (MODE == 0) ? OW : OW / 2;
    constexpr int CH = (MODE == 0) ? OH : OH / 2;
    constexpr int NCH = CIN / 32;
    constexpr int MTc = (COUT == 128) ? 4 : 2;
    constexpr long PL = (long)TAPS * COUT * CIN;

    __shared__ short Ah[128 * 40];
    __shared__ short Al[SPLIT ? 128 * 40 : 8];
    __shared__ short Bh[COUT * 40];
    __shared__ short Bl[SPLIT ? COUT * 40 : 8];

    int bx = blockIdx.x;
    int ry = 0, rx = 0;
    if (MODE == 1) { int c = bx & 3; ry = c >> 1; rx = c & 1; bx >>= 2; }
    const int y0 = (bx % (CH / R)) * R;
    const int n  = bx / (CH / R);

    const int tid = threadIdx.x;
    const int p  = tid >> 1;
    const int ak = (tid & 1) * 16;
    const int rr = p / CW, xx = p % CW;
    constexpr int BPT = (COUT * 32) / 256;
    constexpr int TPRB = 32 / BPT;
    const int bco = tid / TPRB;
    const int bk  = (tid % TPRB) * BPT;
    const int lane = tid & 63, wv = tid >> 6;
    const int quad = lane >> 4, l16 = lane & 15;
    const int mbase = (COUT == 128) ? (wv & 1) * 64 : wv * 32;
    const int nbase = (COUT == 128) ? (wv >> 1) * 64 : 0;

    f32x4 acc[MTc][4];
#pragma unroll
    for (int mt = 0; mt < MTc; ++mt)
#pragma unroll
        for (int nt = 0; nt < 4; ++nt) acc[mt][nt] = f32x4{0.f, 0.f, 0.f, 0.f};

#pragma unroll 1
    for (int tap = 0; tap < TAPS; ++tap) {
        int iy, ix, wt;
        if (MODE == 0) {
            int ky = tap >> 2, kx = tap & 3;
            iy = 2 * (y0 + rr) - 1 + ky;
            ix = 2 * xx - 1 + kx;
            wt = tap;
        } else {
            int jj = tap >> 1, ii = tap & 1;
            iy = (y0 + rr) + ry - jj;
            ix = xx + rx - ii;
            wt = ((1 - ry) + 2 * jj) * 4 + ((1 - rx) + 2 * ii);
        }
        const bool av = (iy >= 0) && (iy < IH) && (ix >= 0) && (ix < IW);
        const long abase = ((long)(n * IH + iy) * IW + ix) * CIN + ak;
        const short* wrh = Wb + ((long)wt * COUT + bco) * CIN + bk;

#pragma unroll 1
        for (int cb = 0; cb < NCH; ++cb) {
            __syncthreads();
            float4 f[4];
            if (av) {
                const float* sp = in + abase + cb * 32;
#pragma unroll
                for (int i = 0; i < 4; ++i) f[i] = *(const float4*)(sp + 4 * i);
            } else {
#pragma unroll
                for (int i = 0; i < 4; ++i) { f[i].x = 0.f; f[i].y = 0.f; f[i].z = 0.f; f[i].w = 0.f; }
            }
            if constexpr (SPLIT) {
                unsigned hw[8], lw[8];
#pragma unroll
                for (int i = 0; i < 4; ++i) {
                    cvt_split2(f[i].x, f[i].y, hw[2 * i], lw[2 * i]);
                    cvt_split2(f[i].z, f[i].w, hw[2 * i + 1], lw[2 * i + 1]);
                }
                *(uint4*)&Ah[p * 40 + ak]     = make_uint4(hw[0], hw[1], hw[2], hw[3]);
                *(uint4*)&Ah[p * 40 + ak + 8] = make_uint4(hw[4], hw[5], hw[6], hw[7]);
                *(uint4*)&Al[p * 40 + ak]     = make_uint4(lw[0], lw[1], lw[2], lw[3]);
                *(uint4*)&Al[p * 40 + ak + 8] = make_uint4(lw[4], lw[5], lw[6], lw[7]);
            } else {
                unsigned hw[8];
#pragma unroll
                for (int i = 0; i < 4; ++i) {
                    hw[2 * i]     = cvt_pk(f[i].x, f[i].y);
                    hw[2 * i + 1] = cvt_pk(f[i].z, f[i].w);
                }
                *(uint4*)&Ah[p * 40 + ak]     = make_uint4(hw[0], hw[1], hw[2], hw[3]);
                *(uint4*)&Ah[p * 40 + ak + 8] = make_uint4(hw[4], hw[5], hw[6], hw[7]);
            }
#pragma unroll
            for (int i = 0; i < BPT / 8; ++i) {
                *(uint4*)&Bh[bco * 40 + bk + 8 * i] = *(const uint4*)(wrh + cb * 32 + 8 * i);
                if constexpr (SPLIT)
                    *(uint4*)&Bl[bco * 40 + bk + 8 * i] = *(const uint4*)(wrh + PL + cb * 32 + 8 * i);
            }
            __syncthreads();
            bf16x8 ahf[MTc], alf[SPLIT ? MTc : 1];
#pragma unroll
            for (int mt = 0; mt < MTc; ++mt) {
                ahf[mt] = *(const bf16x8*)&Ah[(mbase + mt * 16 + l16) * 40 + quad * 8];
                if constexpr (SPLIT)
                    alf[mt] = *(const bf16x8*)&Al[(mbase + mt * 16 + l16) * 40 + quad * 8];
            }
#pragma unroll
            for (int nt = 0; nt < 4; ++nt) {
                bf16x8 bhf = *(const bf16x8*)&Bh[(nbase + nt * 16 + l16) * 40 + quad * 8];
#pragma unroll
                for (int mt = 0; mt < MTc; ++mt)
                    acc[mt][nt] = __builtin_amdgcn_mfma_f32_16x16x32_bf16(ahf[mt], bhf, acc[mt][nt], 0, 0, 0);
                if constexpr (SPLIT) {
                    bf16x8 blf = *(const bf16x8*)&Bl[(nbase + nt * 16 + l16) * 40 + quad * 8];
#pragma unroll
                    for (int mt = 0; mt < MTc; ++mt) {
                        acc[mt][nt] = __builtin_amdgcn_mfma_f32_16x16x32_bf16(alf[mt], bhf, acc[mt][nt], 0, 0, 0);
                        acc[mt][nt] = __builtin_amdgcn_mfma_f32_16x16x32_bf16(ahf[mt], blf, acc[mt][nt], 0, 0, 0);
                    }
                }
            }
        }
    }
#pragma unroll
    for (int mt = 0; mt < MTc; ++mt)
#pragma unroll
        for (int nt = 0; nt < 4; ++nt) {
            int co = nbase + nt * 16 + l16;
            float bv = bias[co];
#pragma unroll
            for (int r = 0; r < 4; ++r) {
                int pl = mbase + mt * 16 + quad * 4 + r;
                int rr2 = pl / CW, x2 = pl % CW;
                int oy, ox;
                if (MODE == 0) { oy = y0 + rr2; ox = x2; }
                else           { oy = 2 * (y0 + rr2) + ry; ox = 2 * x2 + rx; }
                float vv = acc[mt][nt][r] + bv;
                if (RELU) vv = fmaxf(vv, 0.f);
                outp[((long)(n * OH + oy) * OW + ox) * COUT + co] = vv;
            }
        }
}

// ---------------------------------------------------------------------------
// wd2 convT 64->3 via MFMA (unchanged from round 5 — verified)
// ---------------------------------------------------------------------------
__global__ __launch_bounds__(256) void convt_final_mfma(
    const float* __restrict__ h, const short* __restrict__ Wc,
    const float* __restrict__ bias, float* __restrict__ out) {
    const int HW = 128;
    __shared__ short HB[3 * 130 * 72];
    __shared__ float Sout[6 * 260];

    const int tid = threadIdx.x;
    const int y = blockIdx.x & 127;
    const int n = blockIdx.x >> 7;
    const int lane = tid & 63, wv = tid >> 6;
    const int quad = lane >> 4, l16 = lane & 15;

    for (int u = tid; u < 780; u += TPB) {
        int row = u >> 1, half = u & 1;
        int hr = row / 130, xc = row % 130;
        int hy = y - 1 + hr, hx = xc - 1;
        unsigned ww[16];
        bool ok = (hy >= 0 && hy < HW && hx >= 0 && hx < HW);
        const float* sp = h + ((long)(n * HW + hy) * HW + hx) * 64 + half * 32;
#pragma unroll
        for (int i = 0; i < 16; ++i) {
            float a = 0.f, b = 0.f;
            if (ok) { float2 p2 = *(const float2*)(sp + 2 * i); a = p2.x; b = p2.y; }
            ww[i] = cvt_pk(a, b);
        }
        short* dp = &HB[row * 72 + half * 32];
#pragma unroll
        for (int i = 0; i < 4; ++i)
            *(uint4*)(dp + 8 * i) = make_uint4(ww[4 * i], ww[4 * i + 1], ww[4 * i + 2], ww[4 * i + 3]);
    }
    __syncthreads();

#pragma unroll 1
    for (int cls = 0; cls < 4; ++cls) {
        const int py = cls >> 1, px = cls & 1;
        bf16x8 Bf[4][2];
#pragma unroll
        for (int tap = 0; tap < 4; ++tap)
#pragma unroll
            for (int cb = 0; cb < 2; ++cb)
                Bf[tap][cb] = *(const bf16x8*)&Wc[((cls * 4 + tap) * 16 + l16) * 64 + cb * 32 + quad * 8];

        f32x4 acc2[2] = { f32x4{0.f,0.f,0.f,0.f}, f32x4{0.f,0.f,0.f,0.f} };
#pragma unroll
        for (int mt = 0; mt < 2; ++mt) {
            const int xp0 = wv * 32 + mt * 16;
#pragma unroll
            for (int tap = 0; tap < 4; ++tap) {
                const int jj = tap >> 1, ii = tap & 1;
                const int hr = py - jj + 1;
                const int rbase = (hr * 130 + xp0 + l16 + px - ii + 1) * 72;
#pragma unroll
                for (int cb = 0; cb < 2; ++cb) {
                    bf16x8 Af = *(const bf16x8*)&HB[rbase + cb * 32 + quad * 8];
                    acc2[mt] = __builtin_amdgcn_mfma_f32_16x16x32_bf16(Af, Bf[tap][cb], acc2[mt], 0, 0, 0);
                }
            }
        }
        if (l16 < 3) {
#pragma unroll
            for (int mt = 0; mt < 2; ++mt)
#pragma unroll
                for (int r = 0; r < 4; ++r) {
                    int xp = wv * 32 + mt * 16 + quad * 4 + r;
                    Sout[(py * 3 + l16) * 260 + 2 * xp + px] = acc2[mt][r];
                }
        }
    }
    __syncthreads();

    for (int u = tid; u < 384; u += TPB) {
        int idx = u * 4;
        int rowi = idx >> 8;
        int xq   = idx & 255;
        int py = rowi / 3, co = rowi % 3;
        float bv = bias[co];
        float4 v = *(const float4*)&Sout[rowi * 260 + xq];
        v.x += bv; v.y += bv; v.z += bv; v.w += bv;
        *(float4*)&out[(((long)(n * 3 + co) * 256) + 2 * y + py) * 256 + xq] = v;
    }
}

// ---------------------------------------------------------------------------
// conv1: x NCHW [16,3,256,256] -> out NHWC [16,128,128,128] (unchanged)
// ---------------------------------------------------------------------------
__global__ __launch_bounds__(256) void conv1_kernel(
    const float* __restrict__ x, const float* __restrict__ Wt,
    const float* __restrict__ bias, float* __restrict__ out) {
    const int IH = 256, IW = 256, OH = 128, OW = 128, BM = 64;
    int bx = blockIdx.x;
    int sx = bx & 1;
    int oy = (bx >> 1) & 127;
    int n  = bx >> 8;
    int ox0 = sx * BM;
    __shared__ float Bs[16 * 3 * 128];
    __shared__ float Ts[3 * 4 * 132];
    int tid = threadIdx.x;
    for (int i = tid; i < 6144 / 4; i += TPB)
        ((float4*)Bs)[i] = ((const float4*)Wt)[i];
    int iy0 = 2 * oy - 1;
    for (int idx = tid; idx < 3 * 4 * 130; idx += TPB) {
        int ci = idx / 520; int r = idx % 520;
        int ky = r / 130;   int xx = r % 130;
        int iy = iy0 + ky;  int ix = 2 * ox0 - 1 + xx;
        float v = 0.f;
        if (iy >= 0 && iy < IH && ix >= 0 && ix < IW)
            v = x[((n * 3 + ci) * IH + iy) * IW + ix];
        Ts[(ci * 4 + ky) * 132 + xx] = v;
    }
    __syncthreads();
    int cog = tid & 31, pxg = tid >> 5;
    int co0 = cog * 4, px0 = pxg * 8;
    float acc[8][4];
#pragma unroll
    for (int i = 0; i < 8; ++i)
#pragma unroll
        for (int j = 0; j < 4; ++j) acc[i][j] = 0.f;
#pragma unroll 1
    for (int ky = 0; ky < 4; ++ky)
#pragma unroll 1
        for (int kx = 0; kx < 4; ++kx)
#pragma unroll
            for (int ci = 0; ci < 3; ++ci) {
                float4 b = *(const float4*)&Bs[((ky * 4 + kx) * 3 + ci) * 128 + co0];
                const float* trow = &Ts[(ci * 4 + ky) * 132 + kx];
#pragma unroll
                for (int q = 0; q < 8; ++q) {
                    float a = trow[2 * (px0 + q)];
                    acc[q][0] = fmaf(a, b.x, acc[q][0]);
                    acc[q][1] = fmaf(a, b.y, acc[q][1]);
                    acc[q][2] = fmaf(a, b.z, acc[q][2]);
                    acc[q][3] = fmaf(a, b.w, acc[q][3]);
                }
            }
    float4 bb = *(const float4*)&bias[co0];
#pragma unroll
    for (int q = 0; q < 8; ++q) {
        int ox = ox0 + px0 + q;
        float4 v;
        v.x = fmaxf(acc[q][0] + bb.x, 0.f);
        v.y = fmaxf(acc[q][1] + bb.y, 0.f);
        v.z = fmaxf(acc[q][2] + bb.z, 0.f);
        v.w = fmaxf(acc[q][3] + bb.w, 0.f);
        *(float4*)&out[(((long)n * OH + oy) * OW + ox) * 128 + co0] = v;
    }
}

// ---------------------------------------------------------------------------
// Generic fp32 tiled conv-as-GEMM (wqt / wqb / wdt) — unchanged
// ---------------------------------------------------------------------------
template<int MODE, int CIN, int COUT, int BM, int RELU, int IH, int IW, int OH, int OW>
__global__ __launch_bounds__(256) void conv_gemm(
    const float* __restrict__ in, const float* __restrict__ Wt,
    const float* __restrict__ bias, float* __restrict__ out) {
    constexpr int CHUNK  = 64;
    constexpr int NCH    = CIN / CHUNK;
    constexpr int CO_PER = (COUT == 128) ? 4 : 2;
    constexpr int PX_PER = BM / 8;
    constexpr int TAPS   = (MODE == 0) ? 16 : (MODE == 1 ? 4 : 1);
    __shared__ float As[CHUNK * BM];
    __shared__ float Bs[CHUNK * COUT];
    const int tid = threadIdx.x;
    const int bx  = blockIdx.x;
    int n, oy, ox0 = 0, par = 0;
    if (MODE == 1) {
        par = bx & 1;
        oy  = (bx >> 1) % OH;
        n   = bx / (2 * OH);
    } else {
        constexpr int SPR = OW / BM;
        int s = bx % SPR;
        oy = (bx / SPR) % OH;
        n  = bx / (SPR * OH);
        ox0 = s * BM;
    }
    const int cog = tid & 31;
    const int pxg = tid >> 5;
    const int co0 = cog * CO_PER, px0 = pxg * PX_PER;
    float acc[PX_PER][CO_PER];
#pragma unroll
    for (int q = 0; q < PX_PER; ++q)
#pragma unroll
        for (int j = 0; j < CO_PER; ++j) acc[q][j] = 0.f;
    constexpr int TPX  = 256 / BM;
    constexpr int CIPT = CHUNK / TPX;
    const int spx  = tid / TPX;
    const int sci0 = (tid % TPX) * CIPT;
    const int py   = oy & 1;

#pragma unroll 1
    for (int tap = 0; tap < TAPS; ++tap) {
        int iy, twi, sx;
        if (MODE == 0) {
            int ky = tap >> 2, kx = tap & 3;
            iy  = 2 * oy - 1 + ky;
            sx  = 2 * (ox0 + spx) - 1 + kx;
            twi = tap;
        } else if (MODE == 1) {
            int jj = tap >> 1, ii = tap & 1;
            iy  = ((oy + 1) >> 1) - jj;
            sx  = spx + par - ii;
            twi = ((1 - py) + 2 * jj) * 4 + ((1 - par) + 2 * ii);
        } else {
            iy = oy; sx = ox0 + spx; twi = 0;
        }
        const bool pxv = (iy >= 0) && (iy < IH) && (sx >= 0) && (sx < IW);
        const float* srcp = in + (((long)n * IH + iy) * IW + sx) * CIN + sci0;
#pragma unroll 1
        for (int cb = 0; cb < NCH; ++cb) {
            __syncthreads();
            float4 tmp[CIPT / 4];
#pragma unroll
            for (int t4 = 0; t4 < CIPT / 4; ++t4) {
                if (pxv) tmp[t4] = *(const float4*)(srcp + cb * CHUNK + 4 * t4);
                else { tmp[t4].x = 0.f; tmp[t4].y = 0.f; tmp[t4].z = 0.f; tmp[t4].w = 0.f; }
            }
#pragma unroll
            for (int t4 = 0; t4 < CIPT / 4; ++t4) {
                As[(sci0 + 4 * t4 + 0) * BM + spx] = tmp[t4].x;
                As[(sci0 + 4 * t4 + 1) * BM + spx] = tmp[t4].y;
                As[(sci0 + 4 * t4 + 2) * BM + spx] = tmp[t4].z;
                As[(sci0 + 4 * t4 + 3) * BM + spx] = tmp[t4].w;
            }
            {
                const float4* wsrc = (const float4*)(Wt + ((long)twi * CIN + cb * CHUNK) * COUT);
#pragma unroll
                for (int t4 = 0; t4 < (CHUNK * COUT) / 1024; ++t4)
                    ((float4*)Bs)[tid + 256 * t4] = wsrc[tid + 256 * t4];
            }
            __syncthreads();
#pragma unroll 4
            for (int k = 0; k < CHUNK; ++k) {
                float a[PX_PER];
#pragma unroll
                for (int t4 = 0; t4 < PX_PER / 4; ++t4)
                    *(float4*)&a[4 * t4] = *(const float4*)&As[k * BM + px0 + 4 * t4];
                if constexpr (CO_PER == 4) {
                    float4 b = *(const float4*)&Bs[k * COUT + co0];
#pragma unroll
                    for (int q = 0; q < PX_PER; ++q) {
                        acc[q][0] = fmaf(a[q], b.x, acc[q][0]);
                        acc[q][1] = fmaf(a[q], b.y, acc[q][1]);
                        acc[q][2] = fmaf(a[q], b.z, acc[q][2]);
                        acc[q][3] = fmaf(a[q], b.w, acc[q][3]);
                    }
                } else {
                    float2 b = *(const float2*)&Bs[k * COUT + co0];
#pragma unroll
                    for (int q = 0; q < PX_PER; ++q) {
                        acc[q][0] = fmaf(a[q], b.x, acc[q][0]);
                        acc[q][1] = fmaf(a[q], b.y, acc[q][1]);
                    }
                }
            }
        }
    }
    float bv[CO_PER];
#pragma unroll
    for (int j = 0; j < CO_PER; ++j) bv[j] = bias[co0 + j];
#pragma unroll
    for (int q = 0; q < PX_PER; ++q) {
        int ox = (MODE == 1) ? (par + 2 * (px0 + q)) : (ox0 + px0 + q);
        float* op = out + (((long)n * OH + oy) * OW + ox) * COUT + co0;
        if constexpr (CO_PER == 4) {
            float4 v;
            v.x = acc[q][0] + bv[0]; v.y = acc[q][1] + bv[1];
            v.z = acc[q][2] + bv[2]; v.w = acc[q][3] + bv[3];
            if (RELU) { v.x = fmaxf(v.x, 0.f); v.y = fmaxf(v.y, 0.f);
                        v.z = fmaxf(v.z, 0.f); v.w = fmaxf(v.w, 0.f); }
            *(float4*)op = v;
        } else {
            float2 v;
            v.x = acc[q][0] + bv[0]; v.y = acc[q][1] + bv[1];
            if (RELU) { v.x = fmaxf(v.x, 0.f); v.y = fmaxf(v.y, 0.f); }
            *(float2*)op = v;
        }
    }
}

// ---------------------------------------------------------------------------
__global__ void enorm_kernel(const float* __restrict__ et, const float* __restrict__ eb,
                             float* __restrict__ nt, float* __restrict__ nb) {
    int k = blockIdx.x * TPB + threadIdx.x;
    if (k >= 1024) return;
    const float* e = (k < 512) ? et : eb;
    float* o = (k < 512) ? nt : nb;
    int kk = k & 511;
    float s = 0.f;
#pragma unroll 8
    for (int d = 0; d < 64; ++d) { float v = e[d * 512 + kk]; s = fmaf(v, v, s); }
    o[kk] = s;
}

// ---------------------------------------------------------------------------
// MFMA vector quantize.  scores = |e|^2 - 2 f@embed via split-bf16 MFMA
// (3-term, fp32-faithful), fused argmin on MFMA C-layout.
// Block = 64 rows, 4 waves (16 rows/wave).  A fragments persist in regs;
// B streams from transposed split codebook ET [hi|lo][n=512][k=64] (L2-hot).
// Outputs: qn NHWC, qc NCHW (64-px strips via LDS transpose), ido, dsum
// (one atomicAdd per block).  Requires 64 | HW and 64 | M.
// ---------------------------------------------------------------------------
__global__ __launch_bounds__(256) void quantize_mfma(
    const float* __restrict__ f, const short* __restrict__ ET,
    const float* __restrict__ embed, const float* __restrict__ enorm,
    float* __restrict__ qn, float* __restrict__ qc, float* __restrict__ ido,
    float* __restrict__ dsum, int M, int HW) {
    __shared__ short Fh[64 * 72];
    __shared__ short Fl[64 * 72];
    __shared__ float S[64 * 65];
    __shared__ int   KI[64];
    __shared__ float wsum[4];

    const int tid = threadIdx.x;
    const int lane = tid & 63, wv = tid >> 6;
    const int quad = lane >> 4, l16 = lane & 15;
    const int R0 = blockIdx.x * 64;

    // ---- stage f rows (fp32 -> split bf16) ----
    {
        int row = tid >> 2;
        int k0 = (tid & 3) * 16;
        const float* sp = f + (long)(R0 + row) * 64 + k0;
        unsigned hw[8], lw[8];
#pragma unroll
        for (int i = 0; i < 4; ++i) {
            float4 p = *(const float4*)(sp + 4 * i);
            cvt_split2(p.x, p.y, hw[2 * i], lw[2 * i]);
            cvt_split2(p.z, p.w, hw[2 * i + 1], lw[2 * i + 1]);
        }
        short* dh = &Fh[row * 72 + k0];
        short* dl = &Fl[row * 72 + k0];
        *(uint4*)(dh)     = make_uint4(hw[0], hw[1], hw[2], hw[3]);
        *(uint4*)(dh + 8) = make_uint4(hw[4], hw[5], hw[6], hw[7]);
        *(uint4*)(dl)     = make_uint4(lw[0], lw[1], lw[2], lw[3]);
        *(uint4*)(dl + 8) = make_uint4(lw[4], lw[5], lw[6], lw[7]);
    }
    __syncthreads();

    // ---- persistent A fragments: rows m = wv*16 + l16, k chunks 0/1 ----
    const int arow = (wv * 16 + l16) * 72;
    bf16x8 Ah0 = *(const bf16x8*)&Fh[arow + quad * 8];
    bf16x8 Ah1 = *(const bf16x8*)&Fh[arow + 32 + quad * 8];
    bf16x8 Al0 = *(const bf16x8*)&Fl[arow + quad * 8];
    bf16x8 Al1 = *(const bf16x8*)&Fl[arow + 32 + quad * 8];

    float bestv[4];
    int   besti[4];
#pragma unroll
    for (int r = 0; r < 4; ++r) { bestv[r] = 3.4e38f; besti[r] = 0; }

    const short* ETlo = ET + 32768;
#pragma unroll 2
    for (int j = 0; j < 32; ++j) {
        const int nb = (j * 16 + l16) * 64 + quad * 8;
        bf16x8 Bh0 = *(const bf16x8*)(ET + nb);
        bf16x8 Bh1 = *(const bf16x8*)(ET + nb + 32);
        bf16x8 Bl0 = *(const bf16x8*)(ETlo + nb);
        bf16x8 Bl1 = *(const bf16x8*)(ETlo + nb + 32);
        f32x4 acc = f32x4{0.f, 0.f, 0.f, 0.f};
        acc = __builtin_amdgcn_mfma_f32_16x16x32_bf16(Ah0, Bh0, acc, 0, 0, 0);
        acc = __builtin_amdgcn_mfma_f32_16x16x32_bf16(Ah1, Bh1, acc, 0, 0, 0);
        acc = __builtin_amdgcn_mfma_f32_16x16x32_bf16(Al0, Bh0, acc, 0, 0, 0);
        acc = __builtin_amdgcn_mfma_f32_16x16x32_bf16(Al1, Bh1, acc, 0, 0, 0);
        acc = __builtin_amdgcn_mfma_f32_16x16x32_bf16(Ah0, Bl0, acc, 0, 0, 0);
        acc = __builtin_amdgcn_mfma_f32_16x16x32_bf16(Ah1, Bl1, acc, 0, 0, 0);
        float en = enorm[j * 16 + l16];
        int   ni = j * 16 + l16;
#pragma unroll
        for (int r = 0; r < 4; ++r) {
            float s = fmaf(-2.f, acc[r], en);
            if (s < bestv[r]) { bestv[r] = s; besti[r] = ni; }
        }
    }
    // reduce across the 16 n-lanes (xor 1,2,4,8 stays within quad group)
#pragma unroll
    for (int m = 1; m < 16; m <<= 1) {
#pragma unroll
        for (int r = 0; r < 4; ++r) {
            float ov = __shfl_xor(bestv[r], m);
            int   oi = __shfl_xor(besti[r], m);
            if (ov < bestv[r] || (ov == bestv[r] && oi < besti[r])) {
                bestv[r] = ov; besti[r] = oi;
            }
        }
    }
    if (l16 == 0) {
#pragma unroll
        for (int r = 0; r < 4; ++r) KI[wv * 16 + quad * 4 + r] = besti[r];
    }
    __syncthreads();

    // ---- outputs ----
    float ddacc = 0.f;
#pragma unroll 1
    for (int r16 = 0; r16 < 16; ++r16) {
        int row = wv * 16 + r16;
        int k = KI[row];
        float ev = embed[lane * 512 + k];
        float fv = f[(long)(R0 + row) * 64 + lane];
        qn[(long)(R0 + row) * 64 + lane] = ev;
        S[row * 65 + lane] = ev;
        float dq = ev - fv;
        ddacc = fmaf(dq, dq, ddacc);
        if (lane == 0) ido[R0 + row] = (float)k;
    }
#pragma unroll
    for (int off = 1; off < 64; off <<= 1) ddacc += __shfl_xor(ddacc, off);
    if (lane == 0) wsum[wv] = ddacc;
    __syncthreads();
    if (tid == 0)
        atomicAdd(dsum, wsum[0] + wsum[1] + wsum[2] + wsum[3]);

    // ---- NCHW transpose store: 64-px (256 B) strips per channel ----
    int nn = R0 / HW;
    int rem0 = R0 - nn * HW;
    int px = tid & 63;
    int cg = tid >> 6;
#pragma unroll
    for (int it = 0; it < 16; ++it) {
        int c = cg + 4 * it;
        qc[((long)nn * 64 + c) * HW + rem0 + px] = S[px * 65 + c];
    }
}

// ---------------------------------------------------------------------------
__global__ void concat_kernel(const float* __restrict__ a, const float* __restrict__ b,
                              float* __restrict__ o, int ca, int cb, int M) {
    int fpr = (ca + cb) >> 2;
    int idx = blockIdx.x * TPB + threadIdx.x;
    if (idx >= M * fpr) return;
    int row = idx / fpr;
    int c4  = (idx - row * fpr) * 4;
    float4 v;
    if (c4 < ca) v = *(const float4*)(a + (long)row * ca + c4);
    else         v = *(const float4*)(b + (long)row * cb + (c4 - ca));
    *(float4*)(o + (long)row * (ca + cb) + c4) = v;
}

// ---------------------------------------------------------------------------
__global__ void loss_kernel(const float* __restrict__ sums, float* __restrict__ out) {
    out[0] = sums[0] * (1.f / (16384.f * 64.f)) + sums[1] * (1.f / (65536.f * 64.f));
}

// ---------------------------------------------------------------------------
extern "C" void kernel_launch(void* const* d_in, const int* in_sizes, int n_in,
                              void* d_out, int out_size, void* d_ws, size_t ws_size,
                              hipStream_t stream) {
    const float* x   = (const float*)d_in[0];
    const float* wb1 = (const float*)d_in[1];  const float* bb1 = (const float*)d_in[2];
    const float* wb2 = (const float*)d_in[3];  const float* bb2 = (const float*)d_in[4];
    const float* wt1 = (const float*)d_in[5];  const float* bt1 = (const float*)d_in[6];
    const float* wqt = (const float*)d_in[7];  const float* bqt = (const float*)d_in[8];
    const float* embed_t = (const float*)d_in[9];
    const float* wdt = (const float*)d_in[10]; const float* bdt = (const float*)d_in[11];
    const float* wqb = (const float*)d_in[12]; const float* bqb = (const float*)d_in[13];
    const float* embed_b = (const float*)d_in[14];
    const float* wup = (const float*)d_in[15]; const float* bup = (const float*)d_in[16];
    const float* wd1 = (const float*)d_in[17]; const float* bd1 = (const float*)d_in[18];
    const float* wd2 = (const float*)d_in[19]; const float* bd2 = (const float*)d_in[20];
    float* out = (float*)d_out;
    float* ws  = (float*)d_ws;

    float* O_XHAT = out;
    float* O_QT   = out + 3145728;
    float* O_QB   = out + 4194304;
    float* O_LOSS = out + 8388608;
    float* O_IDT  = out + 8388609;
    float* O_IDB  = out + 8404993;

    // ws layout (floats)
    float* W_WB1 = ws + 0;        // 6144   (fp32, conv1)
    short* WB_WD2 = (short*)(ws + 16384);     // 16384 shorts (wd2 bf16 cls layout)
    short* ET_T  = (short*)(ws + 32768);      // 65536 shorts (hi|lo [512][64])
    short* ET_B  = (short*)(ws + 65536);      // 65536 shorts
    float* W_WQT = ws + 532480;   // 8192   (fp32 1x1)
    float* W_WDT = ws + 540672;   // 65536  (fp32 convT, id-critical)
    float* W_WQB = ws + 606208;   // 12288  (fp32 1x1)
    float* EN_T  = ws + 818176;   // 512
    float* EN_B  = ws + 818688;   // 512
    float* SUMS  = ws + 819200;   // 2
    float* T1    = ws + 1048576;          // enc_b NHWC [16,64,64,128] fp32
    const long BIG = 9437184;
    float* T0   = ws + BIG;               // enc_b1 NHWC [16,128,128,128] fp32
    float* T2   = ws + BIG;               // enc_t NHWC (reuses T0 after conv2)
    float* QT   = ws + BIG + 2097152;
    float* QTN  = ws + BIG + 3145728;
    float* DECT = ws + BIG + 4194304;
    float* ECAT = ws + BIG + 8388608;
    float* QB   = ws + BIG + 20971520;
    float* QBN  = ws + BIG + 25165824;
    float* UPT  = ws + BIG + 4194304;     // reuses DECT
    float* QCAT = ws + BIG + 8388608;     // reuses ECAT
    float* HBUF = ws + BIG + 16777216;
    short* WB_BF2 = (short*)(ws + 42991616);  // [2][16][128][128] = 524288 sh
    short* WB_BT1 = (short*)(ws + 43253760);
    short* WB_BD1 = (short*)(ws + 43515904);  // [2][16][64][128]
    short* WB_BUP = (short*)(ws + 43646976);  // [2][16][64][64]

    auto wt_launch = [&](const float* src, float* dst, int cin, int cout, int taps, int iohw) {
        int tot = cin * cout * taps;
        wtrans_kernel<<<(tot + TPB - 1) / TPB, TPB, 0, stream>>>(src, dst, cin, cout, taps, iohw);
    };
    auto wtb_launch = [&](const float* src, short* dst, int cin, int cout, int taps, int iohw) {
        int tot = cin * cout * taps;
        wtrans_bf16_kernel<<<(tot + TPB - 1) / TPB, TPB, 0, stream>>>(src, dst, cin, cout, taps, iohw, tot);
    };
    wt_launch(wb1, W_WB1, 3, 128, 16, 0);
    wt_launch(wqt, W_WQT, 128, 64, 1, 0);
    wt_launch(wdt, W_WDT, 64, 64, 16, 1);
    wt_launch(wqb, W_WQB, 192, 64, 1, 0);
    wtrans_wd2_kernel<<<64, TPB, 0, stream>>>(wd2, WB_WD2);
    wtb_launch(wb2, WB_BF2, 128, 128, 16, 0);
    wtb_launch(wt1, WB_BT1, 128, 128, 16, 0);
    wtb_launch(wd1, WB_BD1, 128, 64, 16, 1);
    wtb_launch(wup, WB_BUP, 64, 64, 16, 1);
    enorm_kernel<<<4, TPB, 0, stream>>>(embed_t, embed_b, EN_T, EN_B);
    etrans_kernel<<<256, TPB, 0, stream>>>(embed_t, embed_b, ET_T, ET_B);
    hipError_t e0 = hipMemsetAsync((void*)SUMS, 0, 2 * sizeof(float), stream);
    (void)e0;

    // ----- encode -----
    conv1_kernel<<<4096, TPB, 0, stream>>>(x, W_WB1, bb1, T0);
    mfma_conv<0, 128, 128, 1, 1, 128, 128, 64, 64, 2><<<512, TPB, 0, stream>>>(T0, WB_BF2, bb2, T1);
    mfma_conv<0, 128, 128, 1, 1, 64, 64, 32, 32, 4><<<128, TPB, 0, stream>>>(T1, WB_BT1, bt1, T2);
    conv_gemm<2, 128, 64, 32, 0, 32, 32, 32, 32><<<512, TPB, 0, stream>>>(T2, W_WQT, bqt, QT);
    quantize_mfma<<<256, TPB, 0, stream>>>(QT, ET_T, embed_t, EN_T, QTN, O_QT, O_IDT, SUMS,
                                           16384, 1024);
    conv_gemm<1, 64, 64, 32, 0, 32, 32, 64, 64><<<2048, TPB, 0, stream>>>(QTN, W_WDT, bdt, DECT);
    concat_kernel<<<12288, TPB, 0, stream>>>(DECT, T1, ECAT, 64, 128, 65536);
    conv_gemm<2, 192, 64, 64, 0, 64, 64, 64, 64><<<1024, TPB, 0, stream>>>(ECAT, W_WQB, bqb, QB);
    quantize_mfma<<<1024, TPB, 0, stream>>>(QB, ET_B, embed_b, EN_B, QBN, O_QB, O_IDB, SUMS + 1,
                                            65536, 4096);
    // ----- decode -----
    mfma_conv<1, 64, 64, 0, 0, 32, 32, 64, 64, 4><<<512, TPB, 0, stream>>>(QTN, WB_BUP, bup, UPT);
    concat_kernel<<<8192, TPB, 0, stream>>>(UPT, QBN, QCAT, 64, 64, 65536);
    mfma_conv<1, 128, 64, 0, 1, 64, 64, 128, 128, 2><<<2048, TPB, 0, stream>>>(QCAT, WB_BD1, bd1, HBUF);
    convt_final_mfma<<<2048, TPB, 0, stream>>>(HBUF, WB_WD2, bd2, O_XHAT);
    loss_kernel<<<1, 1, 0, stream>>>(SUMS, O_LOSS);

    (void)in_sizes; (void)n_in; (void)out_size; (void)ws_size;
}

// Round 7
// 707.499 us; speedup vs baseline: 3.4584x; 1.1337x over previous
//
#include <hip/hip_runtime.h>

#define TPB 256

typedef __attribute__((ext_vector_type(4))) float f32x4;
typedef __attribute__((ext_vector_type(8))) short bf16x8;

// ---------------------------------------------------------------------------
// Weight transform fp32: src OIHW (iohw=0) or IOHW (iohw=1) -> [tap][ci][co]
// ---------------------------------------------------------------------------
__global__ void wtrans_kernel(const float* __restrict__ src, float* __restrict__ dst,
                              int CIN, int COUT, int taps, int iohw) {
    int idx = blockIdx.x * TPB + threadIdx.x;
    int tot = CIN * COUT * taps;
    if (idx >= tot) return;
    int co = idx % COUT;
    int ci = (idx / COUT) % CIN;
    int tap = idx / (COUT * CIN);
    float v = iohw ? src[(ci * COUT + co) * taps + tap]
                   : src[(co * CIN + ci) * taps + tap];
    dst[idx] = v;
}

// ---------------------------------------------------------------------------
// RNE fp32 -> bf16 (finite inputs), returns 16-bit pattern in low bits.
// ---------------------------------------------------------------------------
__device__ __forceinline__ unsigned bf16_rne(float v) {
    unsigned u = __float_as_uint(v);
    return (u + 0x7FFFu + ((u >> 16) & 1u)) >> 16;
}

// ---------------------------------------------------------------------------
// Weight transform bf16-split: fp32 -> hi plane [tap][co][ci], lo at +PL.
// ---------------------------------------------------------------------------
__global__ void wtrans_bf16_kernel(const float* __restrict__ src, short* __restrict__ dst,
                                   int CIN, int COUT, int taps, int iohw, int PL) {
    int idx = blockIdx.x * TPB + threadIdx.x;
    int tot = CIN * COUT * taps;
    if (idx >= tot) return;
    int ci = idx % CIN;
    int co = (idx / CIN) % COUT;
    int tap = idx / (CIN * COUT);
    float v = iohw ? src[(ci * COUT + co) * taps + tap]
                   : src[(co * CIN + ci) * taps + tap];
    unsigned h = bf16_rne(v);
    float rem = v - __uint_as_float(h << 16);
    unsigned l = bf16_rne(rem);
    dst[idx] = (short)h;
    dst[idx + PL] = (short)l;
}

// ---------------------------------------------------------------------------
// wd2 weights -> bf16 [cls(4)][tap(4)][co(16 pad from 3)][ci(64)]
// ---------------------------------------------------------------------------
__global__ void wtrans_wd2_kernel(const float* __restrict__ src, short* __restrict__ dst) {
    int idx = blockIdx.x * TPB + threadIdx.x;
    if (idx >= 16384) return;
    int ci  = idx & 63;
    int co  = (idx >> 6) & 15;
    int tap = (idx >> 10) & 3;
    int cls = idx >> 12;
    int py = cls >> 1, px = cls & 1;
    int jj = tap >> 1, ii = tap & 1;
    int ky = (1 - py) + 2 * jj;
    int kx = (1 - px) + 2 * ii;
    float v = (co < 3) ? src[(ci * 3 + co) * 16 + ky * 4 + kx] : 0.f;
    dst[idx] = (short)bf16_rne(v);
}

// ---------------------------------------------------------------------------
// embed [64,512] fp32 -> transposed split bf16 [n=512][k=64], hi | lo planes.
// ---------------------------------------------------------------------------
__global__ void etrans_kernel(const float* __restrict__ et, const float* __restrict__ eb,
                              short* __restrict__ ETt, short* __restrict__ ETb) {
    int idx = blockIdx.x * TPB + threadIdx.x;
    if (idx >= 65536) return;
    const float* src = (idx < 32768) ? et : eb;
    short* dst = (idx < 32768) ? ETt : ETb;
    int i = idx & 32767;
    int k = i & 63;
    int n = i >> 6;
    float v = src[k * 512 + n];
    unsigned h = bf16_rne(v);
    float rem = v - __uint_as_float(h << 16);
    dst[i] = (short)h;
    dst[i + 32768] = (short)bf16_rne(rem);
}

// ---------------------------------------------------------------------------
// fp32 pair -> packed bf16x2 helpers (RNE, integer path)
// ---------------------------------------------------------------------------
__device__ __forceinline__ void cvt_split2(float a, float b, unsigned& hw, unsigned& lw) {
    unsigned ha = bf16_rne(a), hb = bf16_rne(b);
    float ra = a - __uint_as_float(ha << 16);
    float rb = b - __uint_as_float(hb << 16);
    hw = ha | (hb << 16);
    lw = bf16_rne(ra) | (bf16_rne(rb) << 16);
}
__device__ __forceinline__ unsigned cvt_pk(float a, float b) {
    return bf16_rne(a) | (bf16_rne(b) << 16);
}

// ---------------------------------------------------------------------------
// MFMA implicit-GEMM conv.  bf16(-split) compute.
// MODE 0: 4x4 s2 p1 conv.  MODE 1: convT via 4 parity classes.
// INBF: 0 = fp32 input (cvt in staging); 1 = pre-packed bf16 input
//       (split planes hi|lo at +APL_IN if SPLIT, plain single plane if !SPLIT)
// OUTB: 0 = fp32 only; 1 = fp32 + split bf16; 2 = plain bf16 only;
//       3 = split bf16 only.
// ---------------------------------------------------------------------------
template<int MODE, int CIN, int COUT, int SPLIT, int RELU,
         int IH, int IW, int OH, int OW, int R, int INBF, int OUTB>
__global__ __launch_bounds__(256) void mfma_conv(
    const void* __restrict__ inv, const short* __restrict__ Wb,
    const float* __restrict__ bias, float* __restrict__ outp,
    short* __restrict__ outb) {
    constexpr int TAPS = (MODE == 0) ? 16 : 4;
    constexpr int CW = (MODE == 0) ? OW : OW / 2;
    constexpr int CH = (MODE == 0) ? OH : OH / 2;
    constexpr int NCH = CIN / 32;
    constexpr int MTc = (COUT == 128) ? 4 : 2;
    constexpr long PL = (long)TAPS * COUT * CIN;        // weight plane (shorts)
    constexpr long APL_IN  = 16L * IH * IW * CIN;       // activation plane (elems)
    constexpr long APL_OUT = 16L * OH * OW * COUT;

    __shared__ short Ah[128 * 40];
    __shared__ short Al[SPLIT ? 128 * 40 : 8];
    __shared__ short Bh[COUT * 40];
    __shared__ short Bl[SPLIT ? COUT * 40 : 8];

    int bx = blockIdx.x;
    int ry = 0, rx = 0;
    if (MODE == 1) { int c = bx & 3; ry = c >> 1; rx = c & 1; bx >>= 2; }
    const int y0 = (bx % (CH / R)) * R;
    const int n  = bx / (CH / R);

    const int tid = threadIdx.x;
    const int p  = tid >> 1;
    const int ak = (tid & 1) * 16;
    const int rr = p / CW, xx = p % CW;
    constexpr int BPT = (COUT * 32) / 256;
    constexpr int TPRB = 32 / BPT;
    const int bco = tid / TPRB;
    const int bk  = (tid % TPRB) * BPT;
    const int lane = tid & 63, wv = tid >> 6;
    const int quad = lane >> 4, l16 = lane & 15;
    const int mbase = (COUT == 128) ? (wv & 1) * 64 : wv * 32;
    const int nbase = (COUT == 128) ? (wv >> 1) * 64 : 0;

    f32x4 acc[MTc][4];
#pragma unroll
    for (int mt = 0; mt < MTc; ++mt)
#pragma unroll
        for (int nt = 0; nt < 4; ++nt) acc[mt][nt] = f32x4{0.f, 0.f, 0.f, 0.f};

#pragma unroll 1
    for (int tap = 0; tap < TAPS; ++tap) {
        int iy, ix, wt;
        if (MODE == 0) {
            int ky = tap >> 2, kx = tap & 3;
            iy = 2 * (y0 + rr) - 1 + ky;
            ix = 2 * xx - 1 + kx;
            wt = tap;
        } else {
            int jj = tap >> 1, ii = tap & 1;
            iy = (y0 + rr) + ry - jj;
            ix = xx + rx - ii;
            wt = ((1 - ry) + 2 * jj) * 4 + ((1 - rx) + 2 * ii);
        }
        const bool av = (iy >= 0) && (iy < IH) && (ix >= 0) && (ix < IW);
        const long abase = ((long)(n * IH + iy) * IW + ix) * CIN + ak;
        const short* wrh = Wb + ((long)wt * COUT + bco) * CIN + bk;

#pragma unroll 1
        for (int cb = 0; cb < NCH; ++cb) {
            __syncthreads();
            // ---- stage A ----
            if constexpr (INBF) {
                const short* sb = (const short*)inv + abase + cb * 32;
                uint4 h0, h1;
                if (av) { h0 = *(const uint4*)sb; h1 = *(const uint4*)(sb + 8); }
                else { h0 = make_uint4(0,0,0,0); h1 = h0; }
                *(uint4*)&Ah[p * 40 + ak]     = h0;
                *(uint4*)&Ah[p * 40 + ak + 8] = h1;
                if constexpr (SPLIT) {
                    uint4 l0, l1;
                    if (av) { l0 = *(const uint4*)(sb + APL_IN); l1 = *(const uint4*)(sb + APL_IN + 8); }
                    else { l0 = make_uint4(0,0,0,0); l1 = l0; }
                    *(uint4*)&Al[p * 40 + ak]     = l0;
                    *(uint4*)&Al[p * 40 + ak + 8] = l1;
                }
            } else {
                const float* sp = (const float*)inv + abase + cb * 32;
                float4 f[4];
                if (av) {
#pragma unroll
                    for (int i = 0; i < 4; ++i) f[i] = *(const float4*)(sp + 4 * i);
                } else {
#pragma unroll
                    for (int i = 0; i < 4; ++i) { f[i].x = 0.f; f[i].y = 0.f; f[i].z = 0.f; f[i].w = 0.f; }
                }
                if constexpr (SPLIT) {
                    unsigned hw[8], lw[8];
#pragma unroll
                    for (int i = 0; i < 4; ++i) {
                        cvt_split2(f[i].x, f[i].y, hw[2 * i], lw[2 * i]);
                        cvt_split2(f[i].z, f[i].w, hw[2 * i + 1], lw[2 * i + 1]);
                    }
                    *(uint4*)&Ah[p * 40 + ak]     = make_uint4(hw[0], hw[1], hw[2], hw[3]);
                    *(uint4*)&Ah[p * 40 + ak + 8] = make_uint4(hw[4], hw[5], hw[6], hw[7]);
                    *(uint4*)&Al[p * 40 + ak]     = make_uint4(lw[0], lw[1], lw[2], lw[3]);
                    *(uint4*)&Al[p * 40 + ak + 8] = make_uint4(lw[4], lw[5], lw[6], lw[7]);
                } else {
                    unsigned hw[8];
#pragma unroll
                    for (int i = 0; i < 4; ++i) {
                        hw[2 * i]     = cvt_pk(f[i].x, f[i].y);
                        hw[2 * i + 1] = cvt_pk(f[i].z, f[i].w);
                    }
                    *(uint4*)&Ah[p * 40 + ak]     = make_uint4(hw[0], hw[1], hw[2], hw[3]);
                    *(uint4*)&Ah[p * 40 + ak + 8] = make_uint4(hw[4], hw[5], hw[6], hw[7]);
                }
            }
            // ---- stage B (bf16 in global) ----
#pragma unroll
            for (int i = 0; i < BPT / 8; ++i) {
                *(uint4*)&Bh[bco * 40 + bk + 8 * i] = *(const uint4*)(wrh + cb * 32 + 8 * i);
                if constexpr (SPLIT)
                    *(uint4*)&Bl[bco * 40 + bk + 8 * i] = *(const uint4*)(wrh + PL + cb * 32 + 8 * i);
            }
            __syncthreads();
            // ---- MFMA ----
            bf16x8 ahf[MTc], alf[SPLIT ? MTc : 1];
#pragma unroll
            for (int mt = 0; mt < MTc; ++mt) {
                ahf[mt] = *(const bf16x8*)&Ah[(mbase + mt * 16 + l16) * 40 + quad * 8];
                if constexpr (SPLIT)
                    alf[mt] = *(const bf16x8*)&Al[(mbase + mt * 16 + l16) * 40 + quad * 8];
            }
#pragma unroll
            for (int nt = 0; nt < 4; ++nt) {
                bf16x8 bhf = *(const bf16x8*)&Bh[(nbase + nt * 16 + l16) * 40 + quad * 8];
#pragma unroll
                for (int mt = 0; mt < MTc; ++mt)
                    acc[mt][nt] = __builtin_amdgcn_mfma_f32_16x16x32_bf16(ahf[mt], bhf, acc[mt][nt], 0, 0, 0);
                if constexpr (SPLIT) {
                    bf16x8 blf = *(const bf16x8*)&Bl[(nbase + nt * 16 + l16) * 40 + quad * 8];
#pragma unroll
                    for (int mt = 0; mt < MTc; ++mt) {
                        acc[mt][nt] = __builtin_amdgcn_mfma_f32_16x16x32_bf16(alf[mt], bhf, acc[mt][nt], 0, 0, 0);
                        acc[mt][nt] = __builtin_amdgcn_mfma_f32_16x16x32_bf16(ahf[mt], blf, acc[mt][nt], 0, 0, 0);
                    }
                }
            }
        }
    }
    // ---- epilogue ----
#pragma unroll
    for (int mt = 0; mt < MTc; ++mt)
#pragma unroll
        for (int nt = 0; nt < 4; ++nt) {
            int co = nbase + nt * 16 + l16;
            float bv = bias[co];
#pragma unroll
            for (int r = 0; r < 4; ++r) {
                int pl = mbase + mt * 16 + quad * 4 + r;
                int rr2 = pl / CW, x2 = pl % CW;
                int oy, ox;
                if (MODE == 0) { oy = y0 + rr2; ox = x2; }
                else           { oy = 2 * (y0 + rr2) + ry; ox = 2 * x2 + rx; }
                float vv = acc[mt][nt][r] + bv;
                if (RELU) vv = fmaxf(vv, 0.f);
                long oidx = ((long)(n * OH + oy) * OW + ox) * COUT + co;
                if constexpr (OUTB == 0 || OUTB == 1) outp[oidx] = vv;
                if constexpr (OUTB == 1 || OUTB == 3) {
                    unsigned hh = bf16_rne(vv);
                    outb[oidx] = (short)hh;
                    outb[oidx + APL_OUT] = (short)bf16_rne(vv - __uint_as_float(hh << 16));
                }
                if constexpr (OUTB == 2) outb[oidx] = (short)bf16_rne(vv);
            }
        }
}

// ---------------------------------------------------------------------------
// wd2 convT 64->3 via MFMA.  h is plain bf16 [16,128,128,64] (copy staging).
// ---------------------------------------------------------------------------
__global__ __launch_bounds__(256) void convt_final_mfma(
    const short* __restrict__ h, const short* __restrict__ Wc,
    const float* __restrict__ bias, float* __restrict__ out) {
    const int HW = 128;
    __shared__ short HB[3 * 130 * 72];
    __shared__ float Sout[6 * 260];

    const int tid = threadIdx.x;
    const int y = blockIdx.x & 127;
    const int n = blockIdx.x >> 7;
    const int lane = tid & 63, wv = tid >> 6;
    const int quad = lane >> 4, l16 = lane & 15;

    for (int u = tid; u < 780; u += TPB) {
        int row = u >> 1, half = u & 1;
        int hr = row / 130, xc = row % 130;
        int hy = y - 1 + hr, hx = xc - 1;
        bool ok = (hy >= 0 && hy < HW && hx >= 0 && hx < HW);
        const short* sp = h + ((long)(n * HW + hy) * HW + hx) * 64 + half * 32;
        uint4 a0, a1, a2, a3;
        if (ok) {
            a0 = *(const uint4*)sp;       a1 = *(const uint4*)(sp + 8);
            a2 = *(const uint4*)(sp + 16); a3 = *(const uint4*)(sp + 24);
        } else {
            a0 = make_uint4(0,0,0,0); a1 = a0; a2 = a0; a3 = a0;
        }
        short* dp = &HB[row * 72 + half * 32];
        *(uint4*)dp = a0; *(uint4*)(dp + 8) = a1;
        *(uint4*)(dp + 16) = a2; *(uint4*)(dp + 24) = a3;
    }
    __syncthreads();

#pragma unroll 1
    for (int cls = 0; cls < 4; ++cls) {
        const int py = cls >> 1, px = cls & 1;
        bf16x8 Bf[4][2];
#pragma unroll
        for (int tap = 0; tap < 4; ++tap)
#pragma unroll
            for (int cb = 0; cb < 2; ++cb)
                Bf[tap][cb] = *(const bf16x8*)&Wc[((cls * 4 + tap) * 16 + l16) * 64 + cb * 32 + quad * 8];

        f32x4 acc2[2] = { f32x4{0.f,0.f,0.f,0.f}, f32x4{0.f,0.f,0.f,0.f} };
#pragma unroll
        for (int mt = 0; mt < 2; ++mt) {
            const int xp0 = wv * 32 + mt * 16;
#pragma unroll
            for (int tap = 0; tap < 4; ++tap) {
                const int jj = tap >> 1, ii = tap & 1;
                const int hr = py - jj + 1;
                const int rbase = (hr * 130 + xp0 + l16 + px - ii + 1) * 72;
#pragma unroll
                for (int cb = 0; cb < 2; ++cb) {
                    bf16x8 Af = *(const bf16x8*)&HB[rbase + cb * 32 + quad * 8];
                    acc2[mt] = __builtin_amdgcn_mfma_f32_16x16x32_bf16(Af, Bf[tap][cb], acc2[mt], 0, 0, 0);
                }
            }
        }
        if (l16 < 3) {
#pragma unroll
            for (int mt = 0; mt < 2; ++mt)
#pragma unroll
                for (int r = 0; r < 4; ++r) {
                    int xp = wv * 32 + mt * 16 + quad * 4 + r;
                    Sout[(py * 3 + l16) * 260 + 2 * xp + px] = acc2[mt][r];
                }
        }
    }
    __syncthreads();

    for (int u = tid; u < 384; u += TPB) {
        int idx = u * 4;
        int rowi = idx >> 8;
        int xq   = idx & 255;
        int py = rowi / 3, co = rowi % 3;
        float bv = bias[co];
        float4 v = *(const float4*)&Sout[rowi * 260 + xq];
        v.x += bv; v.y += bv; v.z += bv; v.w += bv;
        *(float4*)&out[(((long)(n * 3 + co) * 256) + 2 * y + py) * 256 + xq] = v;
    }
}

// ---------------------------------------------------------------------------
// conv1: x NCHW [16,3,256,256] -> split-bf16 NHWC [16,128,128,128] + ReLU
// ---------------------------------------------------------------------------
__global__ __launch_bounds__(256) void conv1_kernel(
    const float* __restrict__ x, const float* __restrict__ Wt,
    const float* __restrict__ bias, short* __restrict__ outb) {
    const int IH = 256, IW = 256, OH = 128, OW = 128, BM = 64;
    const long APL0 = 16L * 128 * 128 * 128;
    int bx = blockIdx.x;
    int sx = bx & 1;
    int oy = (bx >> 1) & 127;
    int n  = bx >> 8;
    int ox0 = sx * BM;
    __shared__ float Bs[16 * 3 * 128];
    __shared__ float Ts[3 * 4 * 132];
    int tid = threadIdx.x;
    for (int i = tid; i < 6144 / 4; i += TPB)
        ((float4*)Bs)[i] = ((const float4*)Wt)[i];
    int iy0 = 2 * oy - 1;
    for (int idx = tid; idx < 3 * 4 * 130; idx += TPB) {
        int ci = idx / 520; int r = idx % 520;
        int ky = r / 130;   int xx = r % 130;
        int iy = iy0 + ky;  int ix = 2 * ox0 - 1 + xx;
        float v = 0.f;
        if (iy >= 0 && iy < IH && ix >= 0 && ix < IW)
            v = x[((n * 3 + ci) * IH + iy) * IW + ix];
        Ts[(ci * 4 + ky) * 132 + xx] = v;
    }
    __syncthreads();
    int cog = tid & 31, pxg = tid >> 5;
    int co0 = cog * 4, px0 = pxg * 8;
    float acc[8][4];
#pragma unroll
    for (int i = 0; i < 8; ++i)
#pragma unroll
        for (int j = 0; j < 4; ++j) acc[i][j] = 0.f;
#pragma unroll 1
    for (int ky = 0; ky < 4; ++ky)
#pragma unroll 1
        for (int kx = 0; kx < 4; ++kx)
#pragma unroll
            for (int ci = 0; ci < 3; ++ci) {
                float4 b = *(const float4*)&Bs[((ky * 4 + kx) * 3 + ci) * 128 + co0];
                const float* trow = &Ts[(ci * 4 + ky) * 132 + kx];
#pragma unroll
                for (int q = 0; q < 8; ++q) {
                    float a = trow[2 * (px0 + q)];
                    acc[q][0] = fmaf(a, b.x, acc[q][0]);
                    acc[q][1] = fmaf(a, b.y, acc[q][1]);
                    acc[q][2] = fmaf(a, b.z, acc[q][2]);
                    acc[q][3] = fmaf(a, b.w, acc[q][3]);
                }
            }
    float4 bb = *(const float4*)&bias[co0];
#pragma unroll
    for (int q = 0; q < 8; ++q) {
        int ox = ox0 + px0 + q;
        float v0 = fmaxf(acc[q][0] + bb.x, 0.f);
        float v1 = fmaxf(acc[q][1] + bb.y, 0.f);
        float v2 = fmaxf(acc[q][2] + bb.z, 0.f);
        float v3 = fmaxf(acc[q][3] + bb.w, 0.f);
        unsigned h0, l0, h1, l1;
        cvt_split2(v0, v1, h0, l0);
        cvt_split2(v2, v3, h1, l1);
        long pix = ((long)n * OH + oy) * OW + ox;
        *(uint2*)&outb[pix * 128 + co0]        = make_uint2(h0, h1);
        *(uint2*)&outb[APL0 + pix * 128 + co0] = make_uint2(l0, l1);
    }
}

// ---------------------------------------------------------------------------
// Generic fp32 tiled conv-as-GEMM (wqt / wqb / wdt) — unchanged
// ---------------------------------------------------------------------------
template<int MODE, int CIN, int COUT, int BM, int RELU, int IH, int IW, int OH, int OW>
__global__ __launch_bounds__(256) void conv_gemm(
    const float* __restrict__ in, const float* __restrict__ Wt,
    const float* __restrict__ bias, float* __restrict__ out) {
    constexpr int CHUNK  = 64;
    constexpr int NCH    = CIN / CHUNK;
    constexpr int CO_PER = (COUT == 128) ? 4 : 2;
    constexpr int PX_PER = BM / 8;
    constexpr int TAPS   = (MODE == 0) ? 16 : (MODE == 1 ? 4 : 1);
    __shared__ float As[CHUNK * BM];
    __shared__ float Bs[CHUNK * COUT];
    const int tid = threadIdx.x;
    const int bx  = blockIdx.x;
    int n, oy, ox0 = 0, par = 0;
    if (MODE == 1) {
        par = bx & 1;
        oy  = (bx >> 1) % OH;
        n   = bx / (2 * OH);
    } else {
        constexpr int SPR = OW / BM;
        int s = bx % SPR;
        oy = (bx / SPR) % OH;
        n  = bx / (SPR * OH);
        ox0 = s * BM;
    }
    const int cog = tid & 31;
    const int pxg = tid >> 5;
    const int co0 = cog * CO_PER, px0 = pxg * PX_PER;
    float acc[PX_PER][CO_PER];
#pragma unroll
    for (int q = 0; q < PX_PER; ++q)
#pragma unroll
        for (int j = 0; j < CO_PER; ++j) acc[q][j] = 0.f;
    constexpr int TPX  = 256 / BM;
    constexpr int CIPT = CHUNK / TPX;
    const int spx  = tid / TPX;
    const int sci0 = (tid % TPX) * CIPT;
    const int py   = oy & 1;

#pragma unroll 1
    for (int tap = 0; tap < TAPS; ++tap) {
        int iy, twi, sx;
        if (MODE == 0) {
            int ky = tap >> 2, kx = tap & 3;
            iy  = 2 * oy - 1 + ky;
            sx  = 2 * (ox0 + spx) - 1 + kx;
            twi = tap;
        } else if (MODE == 1) {
            int jj = tap >> 1, ii = tap & 1;
            iy  = ((oy + 1) >> 1) - jj;
            sx  = spx + par - ii;
            twi = ((1 - py) + 2 * jj) * 4 + ((1 - par) + 2 * ii);
        } else {
            iy = oy; sx = ox0 + spx; twi = 0;
        }
        const bool pxv = (iy >= 0) && (iy < IH) && (sx >= 0) && (sx < IW);
        const float* srcp = in + (((long)n * IH + iy) * IW + sx) * CIN + sci0;
#pragma unroll 1
        for (int cb = 0; cb < NCH; ++cb) {
            __syncthreads();
            float4 tmp[CIPT / 4];
#pragma unroll
            for (int t4 = 0; t4 < CIPT / 4; ++t4) {
                if (pxv) tmp[t4] = *(const float4*)(srcp + cb * CHUNK + 4 * t4);
                else { tmp[t4].x = 0.f; tmp[t4].y = 0.f; tmp[t4].z = 0.f; tmp[t4].w = 0.f; }
            }
#pragma unroll
            for (int t4 = 0; t4 < CIPT / 4; ++t4) {
                As[(sci0 + 4 * t4 + 0) * BM + spx] = tmp[t4].x;
                As[(sci0 + 4 * t4 + 1) * BM + spx] = tmp[t4].y;
                As[(sci0 + 4 * t4 + 2) * BM + spx] = tmp[t4].z;
                As[(sci0 + 4 * t4 + 3) * BM + spx] = tmp[t4].w;
            }
            {
                const float4* wsrc = (const float4*)(Wt + ((long)twi * CIN + cb * CHUNK) * COUT);
#pragma unroll
                for (int t4 = 0; t4 < (CHUNK * COUT) / 1024; ++t4)
                    ((float4*)Bs)[tid + 256 * t4] = wsrc[tid + 256 * t4];
            }
            __syncthreads();
#pragma unroll 4
            for (int k = 0; k < CHUNK; ++k) {
                float a[PX_PER];
#pragma unroll
                for (int t4 = 0; t4 < PX_PER / 4; ++t4)
                    *(float4*)&a[4 * t4] = *(const float4*)&As[k * BM + px0 + 4 * t4];
                if constexpr (CO_PER == 4) {
                    float4 b = *(const float4*)&Bs[k * COUT + co0];
#pragma unroll
                    for (int q = 0; q < PX_PER; ++q) {
                        acc[q][0] = fmaf(a[q], b.x, acc[q][0]);
                        acc[q][1] = fmaf(a[q], b.y, acc[q][1]);
                        acc[q][2] = fmaf(a[q], b.z, acc[q][2]);
                        acc[q][3] = fmaf(a[q], b.w, acc[q][3]);
                    }
                } else {
                    float2 b = *(const float2*)&Bs[k * COUT + co0];
#pragma unroll
                    for (int q = 0; q < PX_PER; ++q) {
                        acc[q][0] = fmaf(a[q], b.x, acc[q][0]);
                        acc[q][1] = fmaf(a[q], b.y, acc[q][1]);
                    }
                }
            }
        }
    }
    float bv[CO_PER];
#pragma unroll
    for (int j = 0; j < CO_PER; ++j) bv[j] = bias[co0 + j];
#pragma unroll
    for (int q = 0; q < PX_PER; ++q) {
        int ox = (MODE == 1) ? (par + 2 * (px0 + q)) : (ox0 + px0 + q);
        float* op = out + (((long)n * OH + oy) * OW + ox) * COUT + co0;
        if constexpr (CO_PER == 4) {
            float4 v;
            v.x = acc[q][0] + bv[0]; v.y = acc[q][1] + bv[1];
            v.z = acc[q][2] + bv[2]; v.w = acc[q][3] + bv[3];
            if (RELU) { v.x = fmaxf(v.x, 0.f); v.y = fmaxf(v.y, 0.f);
                        v.z = fmaxf(v.z, 0.f); v.w = fmaxf(v.w, 0.f); }
            *(float4*)op = v;
        } else {
            float2 v;
            v.x = acc[q][0] + bv[0]; v.y = acc[q][1] + bv[1];
            if (RELU) { v.x = fmaxf(v.x, 0.f); v.y = fmaxf(v.y, 0.f); }
            *(float2*)op = v;
        }
    }
}

// ---------------------------------------------------------------------------
__global__ void enorm_kernel(const float* __restrict__ et, const float* __restrict__ eb,
                             float* __restrict__ nt, float* __restrict__ nb) {
    int k = blockIdx.x * TPB + threadIdx.x;
    if (k >= 1024) return;
    const float* e = (k < 512) ? et : eb;
    float* o = (k < 512) ? nt : nb;
    int kk = k & 511;
    float s = 0.f;
#pragma unroll 8
    for (int d = 0; d < 64; ++d) { float v = e[d * 512 + kk]; s = fmaf(v, v, s); }
    o[kk] = s;
}

// ---------------------------------------------------------------------------
// MFMA vector quantize (unchanged from round 6 — verified)
// ---------------------------------------------------------------------------
__global__ __launch_bounds__(256) void quantize_mfma(
    const float* __restrict__ f, const short* __restrict__ ET,
    const float* __restrict__ embed, const float* __restrict__ enorm,
    float* __restrict__ qn, float* __restrict__ qc, float* __restrict__ ido,
    float* __restrict__ dsum, int M, int HW) {
    __shared__ short Fh[64 * 72];
    __shared__ short Fl[64 * 72];
    __shared__ float S[64 * 65];
    __shared__ int   KI[64];
    __shared__ float wsum[4];

    const int tid = threadIdx.x;
    const int lane = tid & 63, wv = tid >> 6;
    const int quad = lane >> 4, l16 = lane & 15;
    const int R0 = blockIdx.x * 64;

    {
        int row = tid >> 2;
        int k0 = (tid & 3) * 16;
        const float* sp = f + (long)(R0 + row) * 64 + k0;
        unsigned hw[8], lw[8];
#pragma unroll
        for (int i = 0; i < 4; ++i) {
            float4 p = *(const float4*)(sp + 4 * i);
            cvt_split2(p.x, p.y, hw[2 * i], lw[2 * i]);
            cvt_split2(p.z, p.w, hw[2 * i + 1], lw[2 * i + 1]);
        }
        short* dh = &Fh[row * 72 + k0];
        short* dl = &Fl[row * 72 + k0];
        *(uint4*)(dh)     = make_uint4(hw[0], hw[1], hw[2], hw[3]);
        *(uint4*)(dh + 8) = make_uint4(hw[4], hw[5], hw[6], hw[7]);
        *(uint4*)(dl)     = make_uint4(lw[0], lw[1], lw[2], lw[3]);
        *(uint4*)(dl + 8) = make_uint4(lw[4], lw[5], lw[6], lw[7]);
    }
    __syncthreads();

    const int arow = (wv * 16 + l16) * 72;
    bf16x8 Ah0 = *(const bf16x8*)&Fh[arow + quad * 8];
    bf16x8 Ah1 = *(const bf16x8*)&Fh[arow + 32 + quad * 8];
    bf16x8 Al0 = *(const bf16x8*)&Fl[arow + quad * 8];
    bf16x8 Al1 = *(const bf16x8*)&Fl[arow + 32 + quad * 8];

    float bestv[4];
    int   besti[4];
#pragma unroll
    for (int r = 0; r < 4; ++r) { bestv[r] = 3.4e38f; besti[r] = 0; }

    const short* ETlo = ET + 32768;
#pragma unroll 2
    for (int j = 0; j < 32; ++j) {
        const int nb = (j * 16 + l16) * 64 + quad * 8;
        bf16x8 Bh0 = *(const bf16x8*)(ET + nb);
        bf16x8 Bh1 = *(const bf16x8*)(ET + nb + 32);
        bf16x8 Bl0 = *(const bf16x8*)(ETlo + nb);
        bf16x8 Bl1 = *(const bf16x8*)(ETlo + nb + 32);
        f32x4 acc = f32x4{0.f, 0.f, 0.f, 0.f};
        acc = __builtin_amdgcn_mfma_f32_16x16x32_bf16(Ah0, Bh0, acc, 0, 0, 0);
        acc = __builtin_amdgcn_mfma_f32_16x16x32_bf16(Ah1, Bh1, acc, 0, 0, 0);
        acc = __builtin_amdgcn_mfma_f32_16x16x32_bf16(Al0, Bh0, acc, 0, 0, 0);
        acc = __builtin_amdgcn_mfma_f32_16x16x32_bf16(Al1, Bh1, acc, 0, 0, 0);
        acc = __builtin_amdgcn_mfma_f32_16x16x32_bf16(Ah0, Bl0, acc, 0, 0, 0);
        acc = __builtin_amdgcn_mfma_f32_16x16x32_bf16(Ah1, Bl1, acc, 0, 0, 0);
        float en = enorm[j * 16 + l16];
        int   ni = j * 16 + l16;
#pragma unroll
        for (int r = 0; r < 4; ++r) {
            float s = fmaf(-2.f, acc[r], en);
            if (s < bestv[r]) { bestv[r] = s; besti[r] = ni; }
        }
    }
#pragma unroll
    for (int m = 1; m < 16; m <<= 1) {
#pragma unroll
        for (int r = 0; r < 4; ++r) {
            float ov = __shfl_xor(bestv[r], m);
            int   oi = __shfl_xor(besti[r], m);
            if (ov < bestv[r] || (ov == bestv[r] && oi < besti[r])) {
                bestv[r] = ov; besti[r] = oi;
            }
        }
    }
    if (l16 == 0) {
#pragma unroll
        for (int r = 0; r < 4; ++r) KI[wv * 16 + quad * 4 + r] = besti[r];
    }
    __syncthreads();

    float ddacc = 0.f;
#pragma unroll 1
    for (int r16 = 0; r16 < 16; ++r16) {
        int row = wv * 16 + r16;
        int k = KI[row];
        float ev = embed[lane * 512 + k];
        float fv = f[(long)(R0 + row) * 64 + lane];
        qn[(long)(R0 + row) * 64 + lane] = ev;
        S[row * 65 + lane] = ev;
        float dq = ev - fv;
        ddacc = fmaf(dq, dq, ddacc);
        if (lane == 0) ido[R0 + row] = (float)k;
    }
#pragma unroll
    for (int off = 1; off < 64; off <<= 1) ddacc += __shfl_xor(ddacc, off);
    if (lane == 0) wsum[wv] = ddacc;
    __syncthreads();
    if (tid == 0)
        atomicAdd(dsum, wsum[0] + wsum[1] + wsum[2] + wsum[3]);

    int nn = R0 / HW;
    int rem0 = R0 - nn * HW;
    int px = tid & 63;
    int cg = tid >> 6;
#pragma unroll
    for (int it = 0; it < 16; ++it) {
        int c = cg + 4 * it;
        qc[((long)nn * 64 + c) * HW + rem0 + px] = S[px * 65 + c];
    }
}

// ---------------------------------------------------------------------------
// ECAT concat: [DECT fp32 64ch | T1b split-bf16 reconstructed 128ch] -> fp32
// ---------------------------------------------------------------------------
__global__ void concat_rec_kernel(const float* __restrict__ a, const short* __restrict__ bh,
                                  float* __restrict__ o, int M) {
    const long PLB = 8388608L;   // 16*64*64*128
    int idx = blockIdx.x * TPB + threadIdx.x;
    if (idx >= M * 48) return;
    int row = idx / 48;
    int c4  = (idx - row * 48) * 4;
    float4 v;
    if (c4 < 64) v = *(const float4*)(a + (long)row * 64 + c4);
    else {
        int cc = c4 - 64;
        uint2 h = *(const uint2*)(bh + (long)row * 128 + cc);
        uint2 l = *(const uint2*)(bh + PLB + (long)row * 128 + cc);
        v.x = __uint_as_float(h.x << 16)        + __uint_as_float(l.x << 16);
        v.y = __uint_as_float(h.x & 0xFFFF0000u) + __uint_as_float(l.x & 0xFFFF0000u);
        v.z = __uint_as_float(h.y << 16)        + __uint_as_float(l.y << 16);
        v.w = __uint_as_float(h.y & 0xFFFF0000u) + __uint_as_float(l.y & 0xFFFF0000u);
    }
    *(float4*)(o + (long)row * 192 + c4) = v;
}

// ---------------------------------------------------------------------------
// decoder concat: [UPT fp32 64 | QBN fp32 64] -> plain bf16 128ch
// ---------------------------------------------------------------------------
__global__ void concat_bf16_kernel(const float* __restrict__ a, const float* __restrict__ b,
                                   short* __restrict__ o, int M) {
    int idx = blockIdx.x * TPB + threadIdx.x;
    if (idx >= M * 32) return;
    int row = idx / 32;
    int c4  = (idx - row * 32) * 4;
    float4 v;
    if (c4 < 64) v = *(const float4*)(a + (long)row * 64 + c4);
    else         v = *(const float4*)(b + (long)row * 64 + (c4 - 64));
    *(uint2*)(o + (long)row * 128 + c4) = make_uint2(cvt_pk(v.x, v.y), cvt_pk(v.z, v.w));
}

// ---------------------------------------------------------------------------
__global__ void loss_kernel(const float* __restrict__ sums, float* __restrict__ out) {
    out[0] = sums[0] * (1.f / (16384.f * 64.f)) + sums[1] * (1.f / (65536.f * 64.f));
}

// ---------------------------------------------------------------------------
extern "C" void kernel_launch(void* const* d_in, const int* in_sizes, int n_in,
                              void* d_out, int out_size, void* d_ws, size_t ws_size,
                              hipStream_t stream) {
    const float* x   = (const float*)d_in[0];
    const float* wb1 = (const float*)d_in[1];  const float* bb1 = (const float*)d_in[2];
    const float* wb2 = (const float*)d_in[3];  const float* bb2 = (const float*)d_in[4];
    const float* wt1 = (const float*)d_in[5];  const float* bt1 = (const float*)d_in[6];
    const float* wqt = (const float*)d_in[7];  const float* bqt = (const float*)d_in[8];
    const float* embed_t = (const float*)d_in[9];
    const float* wdt = (const float*)d_in[10]; const float* bdt = (const float*)d_in[11];
    const float* wqb = (const float*)d_in[12]; const float* bqb = (const float*)d_in[13];
    const float* embed_b = (const float*)d_in[14];
    const float* wup = (const float*)d_in[15]; const float* bup = (const float*)d_in[16];
    const float* wd1 = (const float*)d_in[17]; const float* bd1 = (const float*)d_in[18];
    const float* wd2 = (const float*)d_in[19]; const float* bd2 = (const float*)d_in[20];
    float* out = (float*)d_out;
    float* ws  = (float*)d_ws;

    float* O_XHAT = out;
    float* O_QT   = out + 3145728;
    float* O_QB   = out + 4194304;
    float* O_LOSS = out + 8388608;
    float* O_IDT  = out + 8388609;
    float* O_IDB  = out + 8404993;

    // ws layout (float-slot offsets; peak 43,712,512 floats ≈ 175 MB)
    float* W_WB1 = ws + 0;                    // 6144
    short* WB_WD2 = (short*)(ws + 16384);     // 16384 shorts
    short* ET_T  = (short*)(ws + 32768);      // 65536 shorts (hi|lo [512][64])
    short* ET_B  = (short*)(ws + 65536);      // 65536 shorts
    float* W_WQT = ws + 532480;   // 8192
    float* W_WDT = ws + 540672;   // 65536 (fp32, id-critical)
    float* W_WQB = ws + 606208;   // 12288
    float* EN_T  = ws + 818176;   // 512
    float* EN_B  = ws + 818688;   // 512
    float* SUMS  = ws + 819200;   // 2
    // T1b: split bf16 [2][16,64,64,128] = 16,777,216 shorts (8.4M float-slots)
    short* T1B  = (short*)(ws + 1048576);     // ends exactly at BIG
    const long BIG = 9437184;
    // T0b: split bf16 [2][16,128,128,128] = 67,108,864 shorts (33.5M slots)
    short* T0B  = (short*)(ws + BIG);
    float* T2   = ws + BIG;                   // fp32, overlays dead T0b
    float* QT   = ws + BIG + 2097152;
    float* QTN  = ws + BIG + 3145728;
    float* DECT = ws + BIG + 4194304;
    float* ECAT = ws + BIG + 8388608;         // [16,64,64,192] fp32, 12.6M
    float* QB   = ws + BIG + 20971520;
    float* QBN  = ws + BIG + 25165824;
    float* UPT  = ws + BIG + 4194304;         // reuses DECT (dead after ECAT)
    short* QCATB = (short*)(ws + BIG + 8388608);   // plain bf16, reuses ECAT
    short* HBUFB = (short*)(ws + BIG + 16777216);  // plain bf16 [16,128,128,64]
    short* WB_BF2 = (short*)(ws + 42991616);  // conv2 weights split bf16
    short* WB_BT1 = (short*)(ws + 43253760);
    short* WB_BD1 = (short*)(ws + 43515904);
    short* WB_BUP = (short*)(ws + 43646976);

    auto wt_launch = [&](const float* src, float* dst, int cin, int cout, int taps, int iohw) {
        int tot = cin * cout * taps;
        wtrans_kernel<<<(tot + TPB - 1) / TPB, TPB, 0, stream>>>(src, dst, cin, cout, taps, iohw);
    };
    auto wtb_launch = [&](const float* src, short* dst, int cin, int cout, int taps, int iohw) {
        int tot = cin * cout * taps;
        wtrans_bf16_kernel<<<(tot + TPB - 1) / TPB, TPB, 0, stream>>>(src, dst, cin, cout, taps, iohw, tot);
    };
    wt_launch(wb1, W_WB1, 3, 128, 16, 0);
    wt_launch(wqt, W_WQT, 128, 64, 1, 0);
    wt_launch(wdt, W_WDT, 64, 64, 16, 1);
    wt_launch(wqb, W_WQB, 192, 64, 1, 0);
    wtrans_wd2_kernel<<<64, TPB, 0, stream>>>(wd2, WB_WD2);
    wtb_launch(wb2, WB_BF2, 128, 128, 16, 0);
    wtb_launch(wt1, WB_BT1, 128, 128, 16, 0);
    wtb_launch(wd1, WB_BD1, 128, 64, 16, 1);
    wtb_launch(wup, WB_BUP, 64, 64, 16, 1);
    enorm_kernel<<<4, TPB, 0, stream>>>(embed_t, embed_b, EN_T, EN_B);
    etrans_kernel<<<256, TPB, 0, stream>>>(embed_t, embed_b, ET_T, ET_B);
    hipError_t e0 = hipMemsetAsync((void*)SUMS, 0, 2 * sizeof(float), stream);
    (void)e0;

    // ----- encode -----
    conv1_kernel<<<4096, TPB, 0, stream>>>(x, W_WB1, bb1, T0B);
    // conv2: split bf16 in (copy staging), split bf16 out
    mfma_conv<0, 128, 128, 1, 1, 128, 128, 64, 64, 2, 1, 3>
        <<<512, TPB, 0, stream>>>(T0B, WB_BF2, bb2, nullptr, T1B);
    // conv3: split bf16 in, fp32 out
    mfma_conv<0, 128, 128, 1, 1, 64, 64, 32, 32, 4, 1, 0>
        <<<128, TPB, 0, stream>>>(T1B, WB_BT1, bt1, T2, nullptr);
    conv_gemm<2, 128, 64, 32, 0, 32, 32, 32, 32><<<512, TPB, 0, stream>>>(T2, W_WQT, bqt, QT);
    quantize_mfma<<<256, TPB, 0, stream>>>(QT, ET_T, embed_t, EN_T, QTN, O_QT, O_IDT, SUMS,
                                           16384, 1024);
    conv_gemm<1, 64, 64, 32, 0, 32, 32, 64, 64><<<2048, TPB, 0, stream>>>(QTN, W_WDT, bdt, DECT);
    concat_rec_kernel<<<12288, TPB, 0, stream>>>(DECT, T1B, ECAT, 65536);
    conv_gemm<2, 192, 64, 64, 0, 64, 64, 64, 64><<<1024, TPB, 0, stream>>>(ECAT, W_WQB, bqb, QB);
    quantize_mfma<<<1024, TPB, 0, stream>>>(QB, ET_B, embed_b, EN_B, QBN, O_QB, O_IDB, SUMS + 1,
                                            65536, 4096);
    // ----- decode -----
    mfma_conv<1, 64, 64, 0, 0, 32, 32, 64, 64, 4, 0, 0>
        <<<512, TPB, 0, stream>>>(QTN, WB_BUP, bup, UPT, nullptr);
    concat_bf16_kernel<<<8192, TPB, 0, stream>>>(UPT, QBN, QCATB, 65536);
    mfma_conv<1, 128, 64, 0, 1, 64, 64, 128, 128, 2, 1, 2>
        <<<2048, TPB, 0, stream>>>(QCATB, WB_BD1, bd1, nullptr, HBUFB);
    convt_final_mfma<<<2048, TPB, 0, stream>>>(HBUFB, WB_WD2, bd2, O_XHAT);
    loss_kernel<<<1, 1, 0, stream>>>(SUMS, O_LOSS);

    (void)in_sizes; (void)n_in; (void)out_size; (void)ws_size;
}